// Round 7
// baseline (2715.456 us; speedup 1.0000x reference)
//
#include <hip/hip_runtime.h>
#include <math.h>

#define DD 1024
#define NP 5120   // padded sample pitch (class offsets padded to 64)
#define PT_TILES 80
#define TS 65     // fp32 LDS tile stride (bank-step 4 for 4-row column reads => 2-way/free)

typedef _Float16 half8 __attribute__((ext_vector_type(8)));
typedef _Float16 half4 __attribute__((ext_vector_type(4)));
typedef float floatx4 __attribute__((ext_vector_type(4)));
typedef short s16x8 __attribute__((ext_vector_type(8)));

// ---------------- workspace layout (float offsets) ----------------
#define OFF_XTH   ((size_t)0)
#define OFF_XTL   ((size_t)2621440)
#define OFF_BASE  ((size_t)5242880)
#define OFF_SIGMA ((size_t)6291456)    // 16*1024*1024 fp32 (lower: Schur, upper: R panels then V)
#define OFF_DINV  ((size_t)23068672)
#define OFF_SUMS  ((size_t)24117248)
#define OFF_MU    ((size_t)24133632)
#define OFF_U     ((size_t)24150016)
#define OFF_MU2   ((size_t)24166400)
#define OFF_XQ2   ((size_t)24166416)
#define OFF_XQMU  ((size_t)24170512)
#define OFF_KAPNU ((size_t)24236048)
#define OFF_CF    ((size_t)24236056)
#define OFF_BETA  ((size_t)24236072)
#define OFF_INVS  ((size_t)24236088)
#define OFF_INTS  ((size_t)24236104)

#define UT_CLS_STRIDE ((size_t)557056) // 136 tiles * 4096 halves

__device__ __forceinline__ void tri_decode(int b, int& ti, int& tj) {
  int t = 0;
  while ((t + 1) * (t + 2) / 2 <= b) t++;
  ti = t;
  tj = b - t * (t + 1) / 2;
}

__device__ __forceinline__ short f2bf(float f) {
  union { float f; unsigned u; } v; v.f = f;
  unsigned r = v.u + 0x7FFF + ((v.u >> 16) & 1);
  return (short)(r >> 16);
}
__device__ __forceinline__ float bf2f(short b) {
  union { unsigned u; float f; } v; v.u = ((unsigned)(unsigned short)b) << 16; return v.f;
}

__device__ __forceinline__ float reduce256(float v, float* scratch) {
  for (int o = 32; o > 0; o >>= 1) v += __shfl_down(v, o, 64);
  int lane = threadIdx.x & 63, w = threadIdx.x >> 6;
  __syncthreads();
  if (lane == 0) scratch[w] = v;
  __syncthreads();
  return scratch[0] + scratch[1] + scratch[2] + scratch[3];
}

// ---------------- stats ----------------
__global__ void k_scalars(const int* y, const float* kappa, const float* nu,
                          float* kapnu, float* cf, float* beta, float* invs,
                          int* counts, int* offsets, int* cls_of_pt, int* order,
                          float* sums, float* uarr, float* dout) {
  __shared__ int h[16];
  __shared__ int cur[16];
  int t = threadIdx.x;
  if (t < 16) h[t] = 0;
  __syncthreads();
  for (int n = t; n < 4096; n += 256) atomicAdd(&h[y[n]], 1);
  __syncthreads();
  if (t == 0) {
    float kap = fabsf(kappa[0]) + 1e-6f;
    float nu_ = fmaxf(nu[0], 1024.0f - 1.0f + 1e-6f);
    kapnu[0] = kap; kapnu[1] = nu_;
    int off = 0, tile = 0;
    for (int c = 0; c < 16; c++) {
      counts[c] = h[c]; offsets[c] = off; cur[c] = off;
      cf[c] = (float)h[c];
      beta[c] = kap + (float)h[c];
      invs[c] = 1.0f / (nu_ + (float)h[c] + 1024.0f + 2.0f);
      int ntile = ((h[c] + 63) & ~63) >> 6;
      for (int q = 0; q < ntile && tile < PT_TILES; q++) cls_of_pt[tile++] = c;
      off += (h[c] + 63) & ~63;
    }
    while (tile < PT_TILES) cls_of_pt[tile++] = -1;
  }
  for (int i = t; i < NP; i += 256) order[i] = -1;
  for (int i = t; i < 16 * 1024; i += 256) { sums[i] = 0.f; uarr[i] = 0.f; }
  for (int i = t; i < 4096 * 16; i += 256) dout[i] = 0.f;
  __syncthreads();
  for (int n = t; n < 4096; n += 256) {
    int c = y[n];
    int p = atomicAdd(&cur[c], 1);
    order[p] = n;
  }
}

__global__ void k_gatherT(const float* X, const int* order, const int* cls_of_pt,
                          short* XTh, short* XTl, float* sums) {
  int pt = blockIdx.x, dt = blockIdx.y, t = threadIdx.x;
  __shared__ float T[64 * TS];
  __shared__ float CS[4 * 64];
  __shared__ int src[64];
  if (t < 64) src[t] = order[pt * 64 + t];
  __syncthreads();
  for (int i = 0; i < 4; i++) {
    int idx4 = i * 256 + t;
    int r = idx4 >> 4, c4 = (idx4 & 15) << 2;
    int s = src[r];
    float4 v = (s >= 0) ? *(const float4*)&X[(size_t)s * DD + dt * 64 + c4]
                        : make_float4(0.f, 0.f, 0.f, 0.f);
    T[r * TS + c4] = v.x; T[r * TS + c4 + 1] = v.y;
    T[r * TS + c4 + 2] = v.z; T[r * TS + c4 + 3] = v.w;
  }
  __syncthreads();
  for (int i = 0; i < 16; i++) {
    int lin = i * 256 + t;
    int d = lin >> 6, p = lin & 63;
    float v = T[p * TS + d];
    short hi = f2bf(v);
    float lov = v - bf2f(hi);
    size_t addr = (size_t)(dt * 64 + d) * NP + pt * 64 + p;
    XTh[addr] = hi;
    XTl[addr] = f2bf(lov);
  }
  int cls = cls_of_pt[pt];
  if (cls < 0) return;
  int g = t >> 6, d = t & 63;
  float s = 0.f;
  for (int p = g * 16; p < g * 16 + 16; p++) s += T[p * TS + d];
  CS[g * 64 + d] = s;
  __syncthreads();
  if (g == 0)
    atomicAdd(&sums[(size_t)cls * DD + dt * 64 + d],
              CS[d] + CS[64 + d] + CS[128 + d] + CS[192 + d]);
}

__global__ void k_mumu2(const float* sums, const float* m, const float* kapnu,
                        const float* cf, float* mu, float* mu2) {
  __shared__ float scratch[4];
  int c = blockIdx.x, t = threadIdx.x;
  float kap = kapnu[0];
  float denom = 1.0f / (kap + cf[c]);
  float s2 = 0.f;
  for (int j = t; j < DD; j += 256) {
    float v = (kap * m[j] + sums[(size_t)c * DD + j]) * denom;
    mu[(size_t)c * DD + j] = v;
    s2 += v * v;
  }
  float tot = reduce256(s2, scratch);
  if (t == 0) mu2[c] = tot;
}

__device__ __forceinline__ float lval(const float* td, const float* tl, int i, int j) {
  if (i == j) return fabsf(td[i]);
  if (i > j) return tl[(size_t)i * DD + j];
  return 0.f;
}

__global__ void k_base(const float* td, const float* tl, const float* m,
                       const float* kapnu, float* base) {
  int ti, tj; tri_decode(blockIdx.x, ti, tj);
  __shared__ float Ta[16][65], Tb[16][65];
  int t = threadIdx.x, tx = t & 15, ty = t >> 4;
  int r0 = ty * 4, c0 = tx * 4;
  float acc[4][4] = {};
  int kmax = (tj + 1) * 64;
  for (int kk = 0; kk < kmax; kk += 16) {
    __syncthreads();
    for (int idx = t; idx < 64 * 16; idx += 256) {
      int r = idx >> 4, p = idx & 15;
      Ta[p][r] = lval(td, tl, ti * 64 + r, kk + p);
      Tb[p][r] = lval(td, tl, tj * 64 + r, kk + p);
    }
    __syncthreads();
#pragma unroll
    for (int p = 0; p < 16; p++) {
      float av[4], bv[4];
#pragma unroll
      for (int a = 0; a < 4; a++) av[a] = Ta[p][r0 + a];
#pragma unroll
      for (int b = 0; b < 4; b++) bv[b] = Tb[p][c0 + b];
#pragma unroll
      for (int a = 0; a < 4; a++)
#pragma unroll
        for (int b = 0; b < 4; b++) acc[a][b] += av[a] * bv[b];
    }
  }
  float kap = kapnu[0];
#pragma unroll
  for (int a = 0; a < 4; a++)
#pragma unroll
    for (int b = 0; b < 4; b++) {
      int gi = ti * 64 + r0 + a, gj = tj * 64 + c0 + b;
      base[(size_t)gi * DD + gj] = acc[a][b] + kap * m[gi] * m[gj];
    }
}

__global__ __launch_bounds__(256) void k_syrk_mfma(const short* XTh, const short* XTl,
                                                   const float* base, const float* mu,
                                                   const float* beta, const float* invs,
                                                   const int* counts, const int* offsets,
                                                   float* sigma) {
  int bb = blockIdx.x;
  int cls = bb / 36, tr = bb % 36;
  int ti, tj; tri_decode(tr, ti, tj);
  int cnt = counts[cls], off = offsets[cls];
  float* Sg = sigma + ((size_t)cls << 20);
  const float* muc = mu + (size_t)cls * DD;
  __shared__ short Ah[128 * 40], Al[128 * 40], Bh[128 * 40], Bl[128 * 40];
  int t = threadIdx.x;
  int wave = t >> 6, lane = t & 63;
  int wr = wave >> 1, wc = wave & 1;
  int quad = lane >> 4, l15 = lane & 15;
  int i0 = ti * 128, j0 = tj * 128;
  bool same = (ti == tj);
  floatx4 acc[4][4];
#pragma unroll
  for (int a = 0; a < 4; a++)
#pragma unroll
    for (int b = 0; b < 4; b++) acc[a][b] = (floatx4){0.f, 0.f, 0.f, 0.f};
  for (int nn = 0; nn < cnt; nn += 32) {
    __syncthreads();
#pragma unroll
    for (int r = 0; r < 2; r++) {
      int lin = r * 256 + t;
      int row = lin >> 2, kg = (lin & 3) << 3;
      size_t sA = (size_t)(i0 + row) * NP + off + nn + kg;
      *(s16x8*)&Ah[row * 40 + kg] = *(const s16x8*)&XTh[sA];
      *(s16x8*)&Al[row * 40 + kg] = *(const s16x8*)&XTl[sA];
      if (!same) {
        size_t sB = (size_t)(j0 + row) * NP + off + nn + kg;
        *(s16x8*)&Bh[row * 40 + kg] = *(const s16x8*)&XTh[sB];
        *(s16x8*)&Bl[row * 40 + kg] = *(const s16x8*)&XTl[sB];
      }
    }
    __syncthreads();
    const short* PBh = same ? Ah : Bh;
    const short* PBl = same ? Al : Bl;
    s16x8 ah[4], al[4], bh[4], bl[4];
#pragma unroll
    for (int f = 0; f < 4; f++) {
      ah[f] = *(const s16x8*)&Ah[(wr * 64 + f * 16 + l15) * 40 + quad * 8];
      al[f] = *(const s16x8*)&Al[(wr * 64 + f * 16 + l15) * 40 + quad * 8];
      bh[f] = *(const s16x8*)&PBh[(wc * 64 + f * 16 + l15) * 40 + quad * 8];
      bl[f] = *(const s16x8*)&PBl[(wc * 64 + f * 16 + l15) * 40 + quad * 8];
    }
#pragma unroll
    for (int fi = 0; fi < 4; fi++)
#pragma unroll
      for (int fj = 0; fj < 4; fj++) {
        acc[fi][fj] = __builtin_amdgcn_mfma_f32_16x16x32_bf16(ah[fi], bh[fj], acc[fi][fj], 0, 0, 0);
        acc[fi][fj] = __builtin_amdgcn_mfma_f32_16x16x32_bf16(ah[fi], bl[fj], acc[fi][fj], 0, 0, 0);
        acc[fi][fj] = __builtin_amdgcn_mfma_f32_16x16x32_bf16(al[fi], bh[fj], acc[fi][fj], 0, 0, 0);
      }
  }
  float bet = beta[cls], isc = invs[cls];
#pragma unroll
  for (int fi = 0; fi < 4; fi++)
#pragma unroll
    for (int fj = 0; fj < 4; fj++)
#pragma unroll
      for (int reg = 0; reg < 4; reg++) {
        int gi = i0 + wr * 64 + fi * 16 + quad * 4 + reg;
        int gj = j0 + wc * 64 + fj * 16 + l15;
        float v = acc[fi][fj][reg] + base[(size_t)gi * DD + gj] - bet * muc[gi] * muc[gj];
        Sg[(size_t)gi * DD + gj] = v * isc;
      }
}

// ---------------- factorization ----------------
// R7: BARRIER-FREE wave-local elimination. One wave (lane = column, 64
// regs/lane) does the 63-round column sweep with __shfl broadcasts —
// no __syncthreads inside (vs R1's 63 barrier-rounds ~16us on a near-idle
// GPU). Ascending-i single pass captures rd (at i==j, wave-uniform branch)
// and se = A[c][j]*rd (at i==c, cndmask) so all register indices stay
// compile-time (rule #20). No redundant work, no divergent serial chol
// (the R2/R4 failure modes). Waves 1-3 zero Wsc concurrently.
// Inversion: level-doubling (R1-proven), unchanged.
// areg[i][b] = A[4ty+i][4tx+b]. Asc/Wsc: 64*TS LDS scratch (clobbered).
// Tsc: >=1024 floats scratch for the T = L21*W11 panels.
__device__ void chol_inv_reg(float areg[4][4], float* Dinv, int cls, int k, int t,
                             float* Asc, float* Wsc, float* Tsc) {
  int tx = t & 15, ty = t >> 4;
  int r0 = ty * 4, c0 = tx * 4;
  // raw tile -> Asc (all 256 threads)
#pragma unroll
  for (int i = 0; i < 4; i++)
#pragma unroll
    for (int b = 0; b < 4; b++)
      Asc[(r0 + i) * TS + c0 + b] = areg[i][b];
  __syncthreads();
  if (t < 64) {
    // wave 0: lane c owns column c
    int c = t;
    float a[64];
#pragma unroll
    for (int i = 0; i < 64; i++) a[i] = Asc[i * TS + c];
    float rd = 0.f;
#pragma unroll
    for (int jb = 0; jb < 8; jb++) {
      for (int jo = 0; jo < 8; jo++) {      // runtime: keeps code icache-sized
        int j = jb * 8 + jo;
        float se = 0.f;
#pragma unroll
        for (int i = jb * 8; i < 64; i++) { // compile-time start; i<=j lanes auto-masked
          float u = __shfl(a[i], j, 64);    // column j, row i (uniform value)
          if (i == j) rd = 1.0f / u;        // wave-uniform branch (j scalar)
          se = (i == c && c > j) ? u * rd : se;
          a[i] -= u * se;                   // se==0 until i reaches c (ascending)
        }
      }
    }
    // column scale by 1/sqrt(diag); write true scaled L (0 above diag)
    float dval = 1.f;
#pragma unroll
    for (int i = 0; i < 64; i++) dval = (i == c) ? a[i] : dval;
    float sd = 1.0f / sqrtf(dval);
#pragma unroll
    for (int i = 0; i < 64; i++)
      Asc[i * TS + c] = (i >= c) ? a[i] * sd : 0.f;
  } else {
    // waves 1-3: zero Wsc concurrently
    for (int idx = t - 64; idx < 4096; idx += 192) {
      int r = idx >> 6, cz = idx & 63;
      Wsc[r * TS + cz] = 0.f;
    }
  }
  __syncthreads();
  // --- level-doubling inversion of L (in Asc) into Wsc ---
  // base: invert the 16 diagonal 4x4 blocks (forward substitution, local)
  if (t < 16) {
    int c = t * 4;
    float l[4][4], w[4][4];
#pragma unroll
    for (int i = 0; i < 4; i++)
#pragma unroll
      for (int j = 0; j <= i; j++) l[i][j] = Asc[(c + i) * TS + c + j];
#pragma unroll
    for (int j = 0; j < 4; j++) {
      w[j][j] = 1.0f / l[j][j];
#pragma unroll
      for (int i = j + 1; i < 4; i++) {
        float s = 0.f;
#pragma unroll
        for (int kk = j; kk < i; kk++) s += l[i][kk] * w[kk][j];
        w[i][j] = -s / l[i][i];
      }
    }
#pragma unroll
    for (int i = 0; i < 4; i++)
#pragma unroll
      for (int j = 0; j <= i; j++) Wsc[(c + i) * TS + c + j] = w[i][j];
  }
  __syncthreads();
  // combine levels: for each pair [c,c+h) x [c+h,c+2h):
  //   T = L_BA * W_AA   (W_AA lower-tri)
  //   W_BA = -W_BB * T  (W_BB lower-tri)
#pragma unroll 4
  for (int h = 4; h <= 32; h <<= 1) {
    int hh = h * h;
    int total = 32 * h;  // (64/(2h)) pairs * h*h elements
    for (int idx = t; idx < total; idx += 256) {
      int pr = idx / hh;
      int rem = idx - pr * hh;
      int i = rem / h, j = rem - (rem / h) * h;
      int c = pr * 2 * h;
      float s = 0.f;
      for (int kk = j; kk < h; kk++)
        s += Asc[(c + h + i) * TS + c + kk] * Wsc[(c + kk) * TS + c + j];
      Tsc[idx] = s;
    }
    __syncthreads();
    for (int idx = t; idx < total; idx += 256) {
      int pr = idx / hh;
      int rem = idx - pr * hh;
      int i = rem / h, j = rem - (rem / h) * h;
      int c = pr * 2 * h;
      int tb = pr * hh;
      float s = 0.f;
      for (int kk = 0; kk <= i; kk++)
        s += Wsc[(c + h + i) * TS + c + h + kk] * Tsc[tb + kk * h + j];
      Wsc[(c + h + i) * TS + c + j] = -s;
    }
    __syncthreads();
  }
  float* Dv = Dinv + ((size_t)(cls * 16 + k)) * 4096;
  for (int idx4 = t; idx4 < 1024; idx4 += 256) {
    int r = idx4 >> 4, c4 = (idx4 & 15) << 2;
    float4 v = make_float4(Wsc[r * TS + c4], Wsc[r * TS + c4 + 1],
                           Wsc[r * TS + c4 + 2], Wsc[r * TS + c4 + 3]);
    *(float4*)&Dv[r * 64 + c4] = v;
  }
}

__global__ void k_diag0(float* sigma, float* Dinv) {
  __shared__ float A[64 * TS], W[64 * TS];
  __shared__ float Tq[1024];
  int cls = blockIdx.x, t = threadIdx.x;
  int tx = t & 15, ty = t >> 4;
  int r0 = ty * 4, c0 = tx * 4;
  float* Sg = sigma + ((size_t)cls << 20);
  float areg[4][4];
#pragma unroll
  for (int i = 0; i < 4; i++) {
    float4 s = *(const float4*)&Sg[(size_t)(r0 + i) * DD + c0];
    areg[i][0] = s.x; areg[i][1] = s.y; areg[i][2] = s.z; areg[i][3] = s.w;
  }
  chol_inv_reg(areg, Dinv, cls, 0, t, A, W, Tq);
}

// R3: split early steps (k<=7, trailing-work-dominated) into
// panel launch + update launch. Panels P_i = A(i,k)*W_k^T computed ONCE
// (16*nb blocks) and persisted to the upper mirror; update blocks READ the
// persisted panels and do a single 64^3 a3 matmul each.
__global__ void k_panel(float* sigma, const float* Dinv, int k) {
  __shared__ float B0[64 * TS], B1[64 * TS];
  int i_ = blockIdx.x, cls = blockIdx.y, t = threadIdx.x;
  int tx = t & 15, ty = t >> 4;
  int r0 = ty * 4, c0 = tx * 4;
  int it = k + 1 + i_;
  float* Sg = sigma + ((size_t)cls << 20);
  const float* Dv = Dinv + ((size_t)(cls * 16 + k)) * 4096;
  for (int i = 0; i < 4; i++) {
    int idx4 = i * 256 + t;
    int r = idx4 >> 4, c4 = (idx4 & 15) << 2;
    float4 v0 = *(const float4*)&Dv[r * 64 + c4];
    B0[r * TS + c4] = v0.x; B0[r * TS + c4 + 1] = v0.y;
    B0[r * TS + c4 + 2] = v0.z; B0[r * TS + c4 + 3] = v0.w;
    float4 v1 = *(const float4*)&Sg[(size_t)(it * 64 + r) * DD + k * 64 + c4];
    B1[r * TS + c4] = v1.x; B1[r * TS + c4 + 1] = v1.y;
    B1[r * TS + c4 + 2] = v1.z; B1[r * TS + c4 + 3] = v1.w;
  }
  __syncthreads();
  float a1[4][4] = {};
#pragma unroll 8
  for (int p = 0; p < 64; p++) {
    float bv[4], av1[4];
#pragma unroll
    for (int bq = 0; bq < 4; bq++) bv[bq] = B0[(c0 + bq) * TS + p];
#pragma unroll
    for (int a = 0; a < 4; a++) av1[a] = B1[(r0 + a) * TS + p];
#pragma unroll
    for (int a = 0; a < 4; a++)
#pragma unroll
      for (int bq = 0; bq < 4; bq++) a1[a][bq] += av1[a] * bv[bq];
  }
#pragma unroll
  for (int a = 0; a < 4; a++) {
    float4 v = make_float4(a1[a][0], a1[a][1], a1[a][2], a1[a][3]);
    *(float4*)&Sg[(size_t)(k * 64 + r0 + a) * DD + it * 64 + c0] = v;
  }
}

__global__ void k_update(float* sigma, float* Dinv, int k) {
  __shared__ float B0[64 * TS], B1[64 * TS], B2[64 * TS];
  int b = blockIdx.x, t = threadIdx.x;
  int tx = t & 15, ty = t >> 4;
  int r0 = ty * 4, c0 = tx * 4;
  int nb = 15 - k;
  int nt = nb * (nb + 1) / 2;
  int cls, a_, b_;
  bool special = (b < 16);
  if (special) { cls = b; a_ = 0; b_ = 0; }
  else {
    int jp = b - 16;
    cls = jp / (nt - 1);
    int s = jp % (nt - 1) + 1;
    tri_decode(s, a_, b_);
  }
  int it = k + 1 + a_, jt = k + 1 + b_;
  bool same = (it == jt);
  float* Sg = sigma + ((size_t)cls << 20);
  // load persisted panels P_it (B1) and P_jt (B2) from the upper mirror
  for (int i = 0; i < 4; i++) {
    int idx4 = i * 256 + t;
    int r = idx4 >> 4, c4 = (idx4 & 15) << 2;
    float4 v1 = *(const float4*)&Sg[(size_t)(k * 64 + r) * DD + it * 64 + c4];
    B1[r * TS + c4] = v1.x; B1[r * TS + c4 + 1] = v1.y;
    B1[r * TS + c4 + 2] = v1.z; B1[r * TS + c4 + 3] = v1.w;
    if (!same) {
      float4 v2 = *(const float4*)&Sg[(size_t)(k * 64 + r) * DD + jt * 64 + c4];
      B2[r * TS + c4] = v2.x; B2[r * TS + c4 + 1] = v2.y;
      B2[r * TS + c4 + 2] = v2.z; B2[r * TS + c4 + 3] = v2.w;
    }
  }
  __syncthreads();
  float* PB = same ? B1 : B2;
  float a3[4][4] = {};
#pragma unroll 8
  for (int p = 0; p < 64; p++) {
    float av[4], bv[4];
#pragma unroll
    for (int a = 0; a < 4; a++) av[a] = B1[(r0 + a) * TS + p];
#pragma unroll
    for (int bq = 0; bq < 4; bq++) bv[bq] = PB[(c0 + bq) * TS + p];
#pragma unroll
    for (int a = 0; a < 4; a++)
#pragma unroll
      for (int bq = 0; bq < 4; bq++) a3[a][bq] += av[a] * bv[bq];
  }
  if (!special) {
#pragma unroll
    for (int a = 0; a < 4; a++) {
      size_t addr = (size_t)(it * 64 + r0 + a) * DD + jt * 64 + c0;
      float4 s = *(const float4*)&Sg[addr];
      s.x -= a3[a][0]; s.y -= a3[a][1]; s.z -= a3[a][2]; s.w -= a3[a][3];
      *(float4*)&Sg[addr] = s;
    }
    return;
  }
  // special: updated (k+1,k+1) tile straight into registers, then factor
  float areg[4][4];
#pragma unroll
  for (int i = 0; i < 4; i++) {
    size_t addr = (size_t)(it * 64 + r0 + i) * DD + jt * 64 + c0;
    float4 s = *(const float4*)&Sg[addr];
    areg[i][0] = s.x - a3[i][0]; areg[i][1] = s.y - a3[i][1];
    areg[i][2] = s.z - a3[i][2]; areg[i][3] = s.w - a3[i][3];
  }
  __syncthreads();
  chol_inv_reg(areg, Dinv, cls, k + 1, t, B1, B2, B0);
}

// merged step k (used for k>7 where work is small / latency-dominated)
__global__ void k_cholstep(float* sigma, float* Dinv, int k) {
  __shared__ float B0[64 * TS], B1[64 * TS], B2[64 * TS];
  int b = blockIdx.x, t = threadIdx.x;
  int tx = t & 15, ty = t >> 4;
  int r0 = ty * 4, c0 = tx * 4;
  int nb = 15 - k;
  int nt = nb * (nb + 1) / 2;
  int cls, a_, b_;
  bool special = (b < 16);
  if (special) { cls = b; a_ = 0; b_ = 0; }
  else {
    int jp = b - 16;
    cls = jp / (nt - 1);
    int s = jp % (nt - 1) + 1;
    tri_decode(s, a_, b_);
  }
  int it = k + 1 + a_, jt = k + 1 + b_;
  bool same = (it == jt);
  float* Sg = sigma + ((size_t)cls << 20);
  const float* Dv = Dinv + ((size_t)(cls * 16 + k)) * 4096;
  for (int i = 0; i < 4; i++) {
    int idx4 = i * 256 + t;
    int r = idx4 >> 4, c4 = (idx4 & 15) << 2;
    float4 v0 = *(const float4*)&Dv[r * 64 + c4];
    B0[r * TS + c4] = v0.x; B0[r * TS + c4 + 1] = v0.y;
    B0[r * TS + c4 + 2] = v0.z; B0[r * TS + c4 + 3] = v0.w;
    float4 v1 = *(const float4*)&Sg[(size_t)(it * 64 + r) * DD + k * 64 + c4];
    B1[r * TS + c4] = v1.x; B1[r * TS + c4 + 1] = v1.y;
    B1[r * TS + c4 + 2] = v1.z; B1[r * TS + c4 + 3] = v1.w;
    if (!same) {
      float4 v2 = *(const float4*)&Sg[(size_t)(jt * 64 + r) * DD + k * 64 + c4];
      B2[r * TS + c4] = v2.x; B2[r * TS + c4 + 1] = v2.y;
      B2[r * TS + c4 + 2] = v2.z; B2[r * TS + c4 + 3] = v2.w;
    }
  }
  __syncthreads();
  // fused: a1 = B1*B0^T, a2 = B2*B0^T (shared bv)
  float a1[4][4] = {}, a2[4][4] = {};
#pragma unroll 8
  for (int p = 0; p < 64; p++) {
    float bv[4], av1[4];
#pragma unroll
    for (int bq = 0; bq < 4; bq++) bv[bq] = B0[(c0 + bq) * TS + p];
#pragma unroll
    for (int a = 0; a < 4; a++) av1[a] = B1[(r0 + a) * TS + p];
#pragma unroll
    for (int a = 0; a < 4; a++)
#pragma unroll
      for (int bq = 0; bq < 4; bq++) a1[a][bq] += av1[a] * bv[bq];
    if (!same) {
      float av2[4];
#pragma unroll
      for (int a = 0; a < 4; a++) av2[a] = B2[(r0 + a) * TS + p];
#pragma unroll
      for (int a = 0; a < 4; a++)
#pragma unroll
        for (int bq = 0; bq < 4; bq++) a2[a][bq] += av2[a] * bv[bq];
    }
  }
  __syncthreads();
#pragma unroll
  for (int a = 0; a < 4; a++)
#pragma unroll
    for (int bq = 0; bq < 4; bq++) {
      B1[(r0 + a) * TS + c0 + bq] = a1[a][bq];
      if (!same) B2[(r0 + a) * TS + c0 + bq] = a2[a][bq];
    }
  if (b_ == 0) {
#pragma unroll
    for (int a = 0; a < 4; a++) {
      float4 v = make_float4(a1[a][0], a1[a][1], a1[a][2], a1[a][3]);
      *(float4*)&Sg[(size_t)(k * 64 + r0 + a) * DD + it * 64 + c0] = v;
    }
  }
  __syncthreads();
  float* PB = same ? B1 : B2;
  float a3[4][4] = {};
#pragma unroll 8
  for (int p = 0; p < 64; p++) {
    float av[4], bv[4];
#pragma unroll
    for (int a = 0; a < 4; a++) av[a] = B1[(r0 + a) * TS + p];
#pragma unroll
    for (int bq = 0; bq < 4; bq++) bv[bq] = PB[(c0 + bq) * TS + p];
#pragma unroll
    for (int a = 0; a < 4; a++)
#pragma unroll
      for (int bq = 0; bq < 4; bq++) a3[a][bq] += av[a] * bv[bq];
  }
  if (!special) {
#pragma unroll
    for (int a = 0; a < 4; a++) {
      size_t addr = (size_t)(it * 64 + r0 + a) * DD + jt * 64 + c0;
      float4 s = *(const float4*)&Sg[addr];
      s.x -= a3[a][0]; s.y -= a3[a][1]; s.z -= a3[a][2]; s.w -= a3[a][3];
      *(float4*)&Sg[addr] = s;
    }
    return;
  }
  // special: updated (k+1,k+1) tile straight into registers, then factor
  float areg[4][4];
#pragma unroll
  for (int i = 0; i < 4; i++) {
    size_t addr = (size_t)(it * 64 + r0 + i) * DD + jt * 64 + c0;
    float4 s = *(const float4*)&Sg[addr];
    areg[i][0] = s.x - a3[i][0]; areg[i][1] = s.y - a3[i][1];
    areg[i][2] = s.z - a3[i][2]; areg[i][3] = s.w - a3[i][3];
  }
  __syncthreads();
  // B0 (held W_k) is dead here -> reuse as the level-doubling T scratch
  chol_inv_reg(areg, Dinv, cls, k + 1, t, B1, B2, B0);
}

// level-1 V combine (width 64->128), fully in-LDS: V21 = -W1 * R * W0
__global__ void k_vl1(float* sigma, const float* Dinv) {
  __shared__ float Rl[64 * TS], W0s[64 * TS], W1s[64 * TS], Ts[64 * TS];
  int b = blockIdx.x, t = threadIdx.x;
  int cls = b >> 3, i = b & 7;
  int t0 = 2 * i, t1 = 2 * i + 1;
  float* Sg = sigma + ((size_t)cls << 20);
  int tx = t & 15, ty = t >> 4;
  int r0 = ty * 4, c0 = tx * 4;
  const float* Dv0 = Dinv + ((size_t)(cls * 16 + t0)) * 4096;
  const float* Dv1 = Dinv + ((size_t)(cls * 16 + t1)) * 4096;
  for (int idx4 = t; idx4 < 1024; idx4 += 256) {
    int r = idx4 >> 4, c4 = (idx4 & 15) << 2;
    float4 vr = *(const float4*)&Sg[(size_t)(t0 * 64 + r) * DD + t1 * 64 + c4];
    Rl[r * TS + c4] = vr.x; Rl[r * TS + c4 + 1] = vr.y;
    Rl[r * TS + c4 + 2] = vr.z; Rl[r * TS + c4 + 3] = vr.w;
    float4 v0 = *(const float4*)&Dv0[r * 64 + c4];
    W0s[r * TS + c4] = v0.x; W0s[r * TS + c4 + 1] = v0.y;
    W0s[r * TS + c4 + 2] = v0.z; W0s[r * TS + c4 + 3] = v0.w;
    float4 v1 = *(const float4*)&Dv1[r * 64 + c4];
    W1s[r * TS + c4] = v1.x; W1s[r * TS + c4 + 1] = v1.y;
    W1s[r * TS + c4 + 2] = v1.z; W1s[r * TS + c4 + 3] = v1.w;
  }
  __syncthreads();
  float aT[4][4] = {};
#pragma unroll 8
  for (int p = 0; p < 64; p++) {
    float av[4], bv[4];
#pragma unroll
    for (int a = 0; a < 4; a++) av[a] = Rl[(r0 + a) * TS + p];
#pragma unroll
    for (int bq = 0; bq < 4; bq++) bv[bq] = W0s[p * TS + c0 + bq];
#pragma unroll
    for (int a = 0; a < 4; a++)
#pragma unroll
      for (int bq = 0; bq < 4; bq++) aT[a][bq] += av[a] * bv[bq];
  }
  __syncthreads();
#pragma unroll
  for (int a = 0; a < 4; a++)
#pragma unroll
    for (int bq = 0; bq < 4; bq++) Ts[(r0 + a) * TS + c0 + bq] = aT[a][bq];
  __syncthreads();
  float aV[4][4] = {};
#pragma unroll 8
  for (int p = 0; p < 64; p++) {
    float av[4], bv[4];
#pragma unroll
    for (int a = 0; a < 4; a++) av[a] = W1s[(r0 + a) * TS + p];
#pragma unroll
    for (int bq = 0; bq < 4; bq++) bv[bq] = Ts[p * TS + c0 + bq];
#pragma unroll
    for (int a = 0; a < 4; a++)
#pragma unroll
      for (int bq = 0; bq < 4; bq++) aV[a][bq] += av[a] * bv[bq];
  }
#pragma unroll
  for (int a = 0; a < 4; a++)
    *(float4*)&Sg[(size_t)(t0 * 64 + r0 + a) * DD + t1 * 64 + c0] =
        make_float4(-aV[a][0], -aV[a][1], -aV[a][2], -aV[a][3]);
}

// level-L launch A: T(a,b) = sum_m R21(a,m) * V11(m,b); T -> lower scratch
__global__ void k_vlA(float* sigma, const float* Dinv, int w) {
  __shared__ float Xs[64 * TS], Ys[64 * TS];
  int aa = blockIdx.x / w, bb = blockIdx.x % w;
  int base = blockIdx.y * 2 * w, cls = blockIdx.z;
  float* Sg = sigma + ((size_t)cls << 20);
  int t = threadIdx.x, tx = t & 15, ty = t >> 4;
  int r0 = ty * 4, c0 = tx * 4;
  float acc[4][4] = {};
  for (int m = bb; m < w; m++) {
    __syncthreads();
    for (int idx4 = t; idx4 < 1024; idx4 += 256) {
      int r = idx4 >> 4, c4 = (idx4 & 15) << 2;
      float4 v = *(const float4*)&Sg[(size_t)((base + m) * 64 + r) * DD + (base + w + aa) * 64 + c4];
      Xs[r * TS + c4] = v.x; Xs[r * TS + c4 + 1] = v.y;
      Xs[r * TS + c4 + 2] = v.z; Xs[r * TS + c4 + 3] = v.w;
    }
    if (m == bb) {
      const float* Dv = Dinv + ((size_t)(cls * 16 + base + bb)) * 4096;
      for (int idx4 = t; idx4 < 1024; idx4 += 256) {
        int r = idx4 >> 4, c4 = (idx4 & 15) << 2;
        float4 v = *(const float4*)&Dv[r * 64 + c4];
        Ys[r * TS + c4] = v.x; Ys[r * TS + c4 + 1] = v.y;
        Ys[r * TS + c4 + 2] = v.z; Ys[r * TS + c4 + 3] = v.w;
      }
    } else {
      for (int idx4 = t; idx4 < 1024; idx4 += 256) {
        int p = idx4 >> 4, c4 = (idx4 & 15) << 2;
        float4 v = *(const float4*)&Sg[(size_t)((base + bb) * 64 + p) * DD + (base + m) * 64 + c4];
        Ys[p * TS + c4] = v.x; Ys[p * TS + c4 + 1] = v.y;
        Ys[p * TS + c4 + 2] = v.z; Ys[p * TS + c4 + 3] = v.w;
      }
    }
    __syncthreads();
#pragma unroll 8
    for (int p = 0; p < 64; p++) {
      float av[4], bv[4];
#pragma unroll
      for (int a = 0; a < 4; a++) av[a] = Xs[(r0 + a) * TS + p];
#pragma unroll
      for (int bq = 0; bq < 4; bq++) bv[bq] = Ys[p * TS + c0 + bq];
#pragma unroll
      for (int a = 0; a < 4; a++)
#pragma unroll
        for (int bq = 0; bq < 4; bq++) acc[a][bq] += av[a] * bv[bq];
    }
  }
#pragma unroll
  for (int a = 0; a < 4; a++)
    *(float4*)&Sg[(size_t)((base + w + aa) * 64 + r0 + a) * DD + (base + bb) * 64 + c0] =
        make_float4(acc[a][0], acc[a][1], acc[a][2], acc[a][3]);
}

// level-L launch B: V21(a,b) = -sum_{m<=a} V22(a,m) * T(m,b); -> upper mirror
__global__ void k_vlB(float* sigma, const float* Dinv, int w) {
  __shared__ float Xs[64 * TS], Ys[64 * TS];
  int aa = blockIdx.x / w, bb = blockIdx.x % w;
  int base = blockIdx.y * 2 * w, cls = blockIdx.z;
  float* Sg = sigma + ((size_t)cls << 20);
  int t = threadIdx.x, tx = t & 15, ty = t >> 4;
  int r0 = ty * 4, c0 = tx * 4;
  float acc[4][4] = {};
  for (int m = 0; m <= aa; m++) {
    __syncthreads();
    if (m == aa) {
      const float* Dv = Dinv + ((size_t)(cls * 16 + base + w + aa)) * 4096;
      for (int idx4 = t; idx4 < 1024; idx4 += 256) {
        int r = idx4 >> 4, c4 = (idx4 & 15) << 2;
        float4 v = *(const float4*)&Dv[r * 64 + c4];
        Xs[r * TS + c4] = v.x; Xs[r * TS + c4 + 1] = v.y;
        Xs[r * TS + c4 + 2] = v.z; Xs[r * TS + c4 + 3] = v.w;
      }
    } else {
      for (int idx4 = t; idx4 < 1024; idx4 += 256) {
        int r = idx4 >> 4, c4 = (idx4 & 15) << 2;
        float4 v = *(const float4*)&Sg[(size_t)((base + w + m) * 64 + r) * DD + (base + w + aa) * 64 + c4];
        Xs[r * TS + c4] = v.x; Xs[r * TS + c4 + 1] = v.y;
        Xs[r * TS + c4 + 2] = v.z; Xs[r * TS + c4 + 3] = v.w;
      }
    }
    for (int idx4 = t; idx4 < 1024; idx4 += 256) {
      int p = idx4 >> 4, c4 = (idx4 & 15) << 2;
      float4 v = *(const float4*)&Sg[(size_t)((base + w + m) * 64 + p) * DD + (base + bb) * 64 + c4];
      Ys[p * TS + c4] = v.x; Ys[p * TS + c4 + 1] = v.y;
      Ys[p * TS + c4 + 2] = v.z; Ys[p * TS + c4 + 3] = v.w;
    }
    __syncthreads();
#pragma unroll 8
    for (int p = 0; p < 64; p++) {
      float av[4], bv[4];
#pragma unroll
      for (int a = 0; a < 4; a++) av[a] = Xs[(r0 + a) * TS + p];
#pragma unroll
      for (int bq = 0; bq < 4; bq++) bv[bq] = Ys[p * TS + c0 + bq];
#pragma unroll
      for (int a = 0; a < 4; a++)
#pragma unroll
        for (int bq = 0; bq < 4; bq++) acc[a][bq] += av[a] * bv[bq];
    }
  }
#pragma unroll
  for (int a = 0; a < 4; a++)
    *(float4*)&Sg[(size_t)((base + bb) * 64 + r0 + a) * DD + (base + w + aa) * 64 + c0] =
        make_float4(-acc[a][0], -acc[a][1], -acc[a][2], -acc[a][3]);
}

// 2176 blocks: packed-fp16 V-tile copy (half8 writes) + fused u-partial
__global__ void k_finalize(const float* sigma, const float* Dinv, const float* mu,
                           float* uarr, _Float16* UT) {
  __shared__ float U0[64 * TS];
  __shared__ float CS[4 * 64];
  int jp = blockIdx.x, t = threadIdx.x;
  int cls = jp / 136, tr = jp % 136;
  int nt_, kt_; tri_decode(tr, nt_, kt_);   // nt_ >= kt_
  const float* muc = mu + (size_t)cls * DD;
  _Float16* outp = UT + (size_t)cls * UT_CLS_STRIDE + (size_t)tr * 4096;
  const float* srcp;
  size_t row_stride;
  if (kt_ == nt_) {
    srcp = Dinv + ((size_t)(cls * 16 + nt_)) * 4096;
    row_stride = 64;
  } else {
    srcp = sigma + ((size_t)cls << 20) + (size_t)(kt_ * 64) * DD + nt_ * 64;
    row_stride = DD;
  }
  for (int i = 0; i < 2; i++) {
    int g8 = i * 256 + t;            // 512 groups of 8 halves
    int rr = g8 >> 3, c8 = (g8 & 7) << 3;
    float4 v0 = *(const float4*)&srcp[(size_t)rr * row_stride + c8];
    float4 v1 = *(const float4*)&srcp[(size_t)rr * row_stride + c8 + 4];
    half8 h;
    h[0] = (_Float16)v0.x; h[1] = (_Float16)v0.y; h[2] = (_Float16)v0.z; h[3] = (_Float16)v0.w;
    h[4] = (_Float16)v1.x; h[5] = (_Float16)v1.y; h[6] = (_Float16)v1.z; h[7] = (_Float16)v1.w;
    *(half8*)&outp[rr * 64 + c8] = h;
    U0[rr * TS + c8] = v0.x; U0[rr * TS + c8 + 1] = v0.y;
    U0[rr * TS + c8 + 2] = v0.z; U0[rr * TS + c8 + 3] = v0.w;
    U0[rr * TS + c8 + 4] = v1.x; U0[rr * TS + c8 + 5] = v1.y;
    U0[rr * TS + c8 + 6] = v1.z; U0[rr * TS + c8 + 7] = v1.w;
  }
  __syncthreads();
  int g = t >> 6, r = t & 63;
  float s = 0.f;
  for (int c = g * 16; c < g * 16 + 16; c++)
    s += U0[r * TS + c] * muc[kt_ * 64 + c];
  CS[g * 64 + r] = s;
  __syncthreads();
  if (g == 0)
    atomicAdd(&uarr[(size_t)cls * DD + nt_ * 64 + r],
              CS[r] + CS[64 + r] + CS[128 + r] + CS[192 + r]);
}

// ---------------- predict side ----------------
__global__ void k_xqdots(const float* Xq, const float* mu, float* xq2, float* xqmu,
                         _Float16* XqH) {
  __shared__ float xrow[DD];
  int m = blockIdx.x, t = threadIdx.x;
  for (int i = t; i < 256; i += 256)
    ((float4*)xrow)[i] = ((const float4*)(Xq + (size_t)m * DD))[i];
  __syncthreads();
  for (int i = t; i < 256; i += 256) {
    float4 v = ((const float4*)xrow)[i];
    half4 h = {(_Float16)v.x, (_Float16)v.y, (_Float16)v.z, (_Float16)v.w};
    *(half4*)&XqH[(size_t)m * DD + i * 4] = h;
  }
  int wave = t >> 6, lane = t & 63;
  for (int cc = 0; cc < 4; cc++) {
    int c = wave * 4 + cc;
    const float* muc = mu + (size_t)c * DD;
    float s = 0.f;
    for (int j = lane; j < DD; j += 64) s += xrow[j] * muc[j];
    for (int o = 32; o > 0; o >>= 1) s += __shfl_down(s, o, 64);
    if (lane == 0) xqmu[(size_t)m * 16 + c] = s;
  }
  if (wave == 0) {
    float s = 0.f;
    for (int j = lane; j < DD; j += 64) s += xrow[j] * xrow[j];
    for (int o = 32; o > 0; o >>= 1) s += __shfl_down(s, o, 64);
    if (lane == 0) xq2[m] = s;
  }
}

// R3-proven gemmG (160us). R6's global_load_lds rewrite REGRESSED
// (VALUBusy 21->55%: per-iter 64-bit addr calc for 4 gload_lds calls) —
// staging is NOT the binding constraint at this 2-barrier structure.
__global__ __launch_bounds__(256) void k_gemmG_mfma(const _Float16* XqH, const _Float16* UT,
                                                    const float* u, float* dout) {
  int mt = blockIdx.x, ct = blockIdx.y, cls = blockIdx.z;
  const _Float16* Uc = UT + (size_t)cls * UT_CLS_STRIDE;
  __shared__ _Float16 As[128 * 40];
  __shared__ _Float16 Bs[128 * 40];
  int t = threadIdx.x;
  int wave = t >> 6, lane = t & 63;
  int wr = wave >> 1, wc = wave & 1;
  int quad = lane >> 4, l15 = lane & 15;
  int m0 = mt * 128, n0 = ct * 128, NT0 = ct * 2;
  floatx4 acc[4][4];
#pragma unroll
  for (int a = 0; a < 4; a++)
#pragma unroll
    for (int b = 0; b < 4; b++) acc[a][b] = (floatx4){0.f, 0.f, 0.f, 0.f};
  int kmax = (ct + 1) * 128;
  for (int kk = 0; kk < kmax; kk += 32) {
    __syncthreads();
#pragma unroll
    for (int i = 0; i < 2; i++) {
      int lin = i * 256 + t;
      int r = lin >> 2, kg = (lin & 3) * 8;
      *(half8*)&As[r * 40 + kg] = *(const half8*)&XqH[(size_t)(m0 + r) * DD + kk + kg];
    }
    int kt = kk >> 6, k0 = kk & 63;
#pragma unroll
    for (int i = 0; i < 2; i++) {
      int lin = i * 256 + t;
      int nl = lin >> 2, kg = (lin & 3) * 8;
      int s = nl >> 6, np = nl & 63;
      int nt = NT0 + s;
      half8 v = {};
      if (kt <= nt)
        v = *(const half8*)&Uc[(size_t)(nt * (nt + 1) / 2 + kt) * 4096 + np * 64 + k0 + kg];
      *(half8*)&Bs[nl * 40 + kg] = v;
    }
    __syncthreads();
    half8 af[4], bf[4];
#pragma unroll
    for (int f = 0; f < 4; f++) {
      af[f] = *(const half8*)&As[(wr * 64 + f * 16 + l15) * 40 + quad * 8];
      bf[f] = *(const half8*)&Bs[(wc * 64 + f * 16 + l15) * 40 + quad * 8];
    }
#pragma unroll
    for (int fi = 0; fi < 4; fi++)
#pragma unroll
      for (int fj = 0; fj < 4; fj++)
        acc[fi][fj] = __builtin_amdgcn_mfma_f32_16x16x32_f16(af[fi], bf[fj], acc[fi][fj], 0, 0, 0);
  }
  float uv[4];
#pragma unroll
  for (int fj = 0; fj < 4; fj++)
    uv[fj] = u[(size_t)cls * DD + n0 + wc * 64 + fj * 16 + l15];
#pragma unroll
  for (int fi = 0; fi < 4; fi++) {
#pragma unroll
    for (int r = 0; r < 4; r++) {
      float p = 0.f;
#pragma unroll
      for (int fj = 0; fj < 4; fj++) {
        float e = acc[fi][fj][r] - uv[fj];
        p += e * e;
      }
      p += __shfl_xor(p, 1, 64);
      p += __shfl_xor(p, 2, 64);
      p += __shfl_xor(p, 4, 64);
      p += __shfl_xor(p, 8, 64);
      if (l15 == 0) {
        int m = m0 + wr * 64 + fi * 16 + quad * 4 + r;
        atomicAdd(&dout[(size_t)m * 16 + cls], p);
      }
    }
  }
}

__global__ void k_logits(const float* xq2, const float* xqmu, const float* mu2,
                         float* dout) {
  size_t idx = (size_t)blockIdx.x * 256 + threadIdx.x;
  int m = (int)(idx >> 4), c = (int)(idx & 15);
  float q1 = dout[idx];
  float q2 = xq2[m] - 2.0f * xqmu[idx] + mu2[c];
  dout[idx] = -(0.9f * q1 + 0.1f * q2);
}

extern "C" void kernel_launch(void* const* d_in, const int* in_sizes, int n_in,
                              void* d_out, int out_size, void* d_ws, size_t ws_size,
                              hipStream_t stream) {
  (void)in_sizes; (void)n_in; (void)out_size; (void)ws_size;
  const float* X  = (const float*)d_in[0];
  const int*   y  = (const int*)d_in[1];
  const float* Xq = (const float*)d_in[2];
  const float* m  = (const float*)d_in[3];
  const float* kappa = (const float*)d_in[4];
  const float* nu = (const float*)d_in[5];
  const float* td = (const float*)d_in[6];
  const float* tl = (const float*)d_in[7];
  float* out = (float*)d_out;
  float* ws = (float*)d_ws;

  short* XTh   = (short*)(ws + OFF_XTH);
  short* XTl   = (short*)(ws + OFF_XTL);
  _Float16* UT = (_Float16*)ws;              // overlays XT planes (dead after syrk)
  float* baseb = ws + OFF_BASE;
  float* sigma = ws + OFF_SIGMA;
  _Float16* XqH = (_Float16*)sigma;          // overlays sigma (dead after finalize)
  float* Dinv  = ws + OFF_DINV;
  float* sums  = ws + OFF_SUMS;
  float* mu    = ws + OFF_MU;
  float* uarr  = ws + OFF_U;
  float* mu2   = ws + OFF_MU2;
  float* xq2   = ws + OFF_XQ2;
  float* xqmu  = ws + OFF_XQMU;
  float* kapnu = ws + OFF_KAPNU;
  float* cf    = ws + OFF_CF;
  float* beta  = ws + OFF_BETA;
  float* invs  = ws + OFF_INVS;
  int* ints      = (int*)(ws + OFF_INTS);
  int* counts    = ints;
  int* offsets   = ints + 16;
  int* cls_of_pt = ints + 32;
  int* order     = ints + 32 + PT_TILES;

  k_scalars<<<1, 256, 0, stream>>>(y, kappa, nu, kapnu, cf, beta, invs,
                                   counts, offsets, cls_of_pt, order,
                                   sums, uarr, out);
  k_gatherT<<<dim3(PT_TILES, 16), 256, 0, stream>>>(X, order, cls_of_pt, XTh, XTl, sums);
  k_mumu2<<<16, 256, 0, stream>>>(sums, m, kapnu, cf, mu, mu2);
  k_base<<<136, 256, 0, stream>>>(td, tl, m, kapnu, baseb);
  k_syrk_mfma<<<16 * 36, 256, 0, stream>>>(XTh, XTl, baseb, mu, beta, invs,
                                           counts, offsets, sigma);
  k_diag0<<<16, 256, 0, stream>>>(sigma, Dinv);
  for (int k = 0; k < 15; k++) {
    int nb = 15 - k;
    int nt = nb * (nb + 1) / 2;
    if (k <= 7) {
      k_panel<<<dim3(nb, 16), 256, 0, stream>>>(sigma, Dinv, k);
      k_update<<<16 * nt, 256, 0, stream>>>(sigma, Dinv, k);
    } else {
      k_cholstep<<<16 * nt, 256, 0, stream>>>(sigma, Dinv, k);
    }
  }
  k_vl1<<<128, 256, 0, stream>>>(sigma, Dinv);
  for (int L = 2; L <= 4; L++) {
    int w = 1 << (L - 1);
    int ncomb = 8 >> (L - 1);
    k_vlA<<<dim3(w * w, ncomb, 16), 256, 0, stream>>>(sigma, Dinv, w);
    k_vlB<<<dim3(w * w, ncomb, 16), 256, 0, stream>>>(sigma, Dinv, w);
  }
  k_finalize<<<16 * 136, 256, 0, stream>>>(sigma, Dinv, mu, uarr, UT);
  k_xqdots<<<4096, 256, 0, stream>>>(Xq, mu, xq2, xqmu, XqH);
  k_gemmG_mfma<<<dim3(32, 8, 16), 256, 0, stream>>>(XqH, UT, uarr, out);
  k_logits<<<256, 256, 0, stream>>>(xq2, xqmu, mu2, out);
}

// Round 8
// 1480.672 us; speedup vs baseline: 1.8339x; 1.8339x over previous
//
#include <hip/hip_runtime.h>
#include <math.h>

#define DD 1024
#define NP 5120   // padded sample pitch (class offsets padded to 64)
#define PT_TILES 80
#define TS 65     // fp32 LDS tile stride (bank-step 4 for 4-row column reads => 2-way/free)

typedef _Float16 half8 __attribute__((ext_vector_type(8)));
typedef _Float16 half4 __attribute__((ext_vector_type(4)));
typedef float floatx4 __attribute__((ext_vector_type(4)));
typedef short s16x8 __attribute__((ext_vector_type(8)));

// ---------------- workspace layout (float offsets) ----------------
#define OFF_XTH   ((size_t)0)
#define OFF_XTL   ((size_t)2621440)
#define OFF_BASE  ((size_t)5242880)
#define OFF_SIGMA ((size_t)6291456)    // 16*1024*1024 fp32 (lower: Schur, upper: R panels then V)
#define OFF_DINV  ((size_t)23068672)
#define OFF_SUMS  ((size_t)24117248)
#define OFF_MU    ((size_t)24133632)
#define OFF_U     ((size_t)24150016)
#define OFF_MU2   ((size_t)24166400)
#define OFF_XQ2   ((size_t)24166416)
#define OFF_XQMU  ((size_t)24170512)
#define OFF_KAPNU ((size_t)24236048)
#define OFF_CF    ((size_t)24236056)
#define OFF_BETA  ((size_t)24236072)
#define OFF_INVS  ((size_t)24236088)
#define OFF_INTS  ((size_t)24236104)

#define UT_CLS_STRIDE ((size_t)557056) // 136 tiles * 4096 halves

__device__ __forceinline__ void tri_decode(int b, int& ti, int& tj) {
  int t = 0;
  while ((t + 1) * (t + 2) / 2 <= b) t++;
  ti = t;
  tj = b - t * (t + 1) / 2;
}

__device__ __forceinline__ short f2bf(float f) {
  union { float f; unsigned u; } v; v.f = f;
  unsigned r = v.u + 0x7FFF + ((v.u >> 16) & 1);
  return (short)(r >> 16);
}
__device__ __forceinline__ float bf2f(short b) {
  union { unsigned u; float f; } v; v.u = ((unsigned)(unsigned short)b) << 16; return v.f;
}

__device__ __forceinline__ float reduce256(float v, float* scratch) {
  for (int o = 32; o > 0; o >>= 1) v += __shfl_down(v, o, 64);
  int lane = threadIdx.x & 63, w = threadIdx.x >> 6;
  __syncthreads();
  if (lane == 0) scratch[w] = v;
  __syncthreads();
  return scratch[0] + scratch[1] + scratch[2] + scratch[3];
}

// ---------------- stats ----------------
__global__ void k_scalars(const int* y, const float* kappa, const float* nu,
                          float* kapnu, float* cf, float* beta, float* invs,
                          int* counts, int* offsets, int* cls_of_pt, int* order,
                          float* sums, float* uarr, float* dout) {
  __shared__ int h[16];
  __shared__ int cur[16];
  int t = threadIdx.x;
  if (t < 16) h[t] = 0;
  __syncthreads();
  for (int n = t; n < 4096; n += 256) atomicAdd(&h[y[n]], 1);
  __syncthreads();
  if (t == 0) {
    float kap = fabsf(kappa[0]) + 1e-6f;
    float nu_ = fmaxf(nu[0], 1024.0f - 1.0f + 1e-6f);
    kapnu[0] = kap; kapnu[1] = nu_;
    int off = 0, tile = 0;
    for (int c = 0; c < 16; c++) {
      counts[c] = h[c]; offsets[c] = off; cur[c] = off;
      cf[c] = (float)h[c];
      beta[c] = kap + (float)h[c];
      invs[c] = 1.0f / (nu_ + (float)h[c] + 1024.0f + 2.0f);
      int ntile = ((h[c] + 63) & ~63) >> 6;
      for (int q = 0; q < ntile && tile < PT_TILES; q++) cls_of_pt[tile++] = c;
      off += (h[c] + 63) & ~63;
    }
    while (tile < PT_TILES) cls_of_pt[tile++] = -1;
  }
  for (int i = t; i < NP; i += 256) order[i] = -1;
  for (int i = t; i < 16 * 1024; i += 256) { sums[i] = 0.f; uarr[i] = 0.f; }
  for (int i = t; i < 4096 * 16; i += 256) dout[i] = 0.f;
  __syncthreads();
  for (int n = t; n < 4096; n += 256) {
    int c = y[n];
    int p = atomicAdd(&cur[c], 1);
    order[p] = n;
  }
}

__global__ void k_gatherT(const float* X, const int* order, const int* cls_of_pt,
                          short* XTh, short* XTl, float* sums) {
  int pt = blockIdx.x, dt = blockIdx.y, t = threadIdx.x;
  __shared__ float T[64 * TS];
  __shared__ float CS[4 * 64];
  __shared__ int src[64];
  if (t < 64) src[t] = order[pt * 64 + t];
  __syncthreads();
  for (int i = 0; i < 4; i++) {
    int idx4 = i * 256 + t;
    int r = idx4 >> 4, c4 = (idx4 & 15) << 2;
    int s = src[r];
    float4 v = (s >= 0) ? *(const float4*)&X[(size_t)s * DD + dt * 64 + c4]
                        : make_float4(0.f, 0.f, 0.f, 0.f);
    T[r * TS + c4] = v.x; T[r * TS + c4 + 1] = v.y;
    T[r * TS + c4 + 2] = v.z; T[r * TS + c4 + 3] = v.w;
  }
  __syncthreads();
  for (int i = 0; i < 16; i++) {
    int lin = i * 256 + t;
    int d = lin >> 6, p = lin & 63;
    float v = T[p * TS + d];
    short hi = f2bf(v);
    float lov = v - bf2f(hi);
    size_t addr = (size_t)(dt * 64 + d) * NP + pt * 64 + p;
    XTh[addr] = hi;
    XTl[addr] = f2bf(lov);
  }
  int cls = cls_of_pt[pt];
  if (cls < 0) return;
  int g = t >> 6, d = t & 63;
  float s = 0.f;
  for (int p = g * 16; p < g * 16 + 16; p++) s += T[p * TS + d];
  CS[g * 64 + d] = s;
  __syncthreads();
  if (g == 0)
    atomicAdd(&sums[(size_t)cls * DD + dt * 64 + d],
              CS[d] + CS[64 + d] + CS[128 + d] + CS[192 + d]);
}

__global__ void k_mumu2(const float* sums, const float* m, const float* kapnu,
                        const float* cf, float* mu, float* mu2) {
  __shared__ float scratch[4];
  int c = blockIdx.x, t = threadIdx.x;
  float kap = kapnu[0];
  float denom = 1.0f / (kap + cf[c]);
  float s2 = 0.f;
  for (int j = t; j < DD; j += 256) {
    float v = (kap * m[j] + sums[(size_t)c * DD + j]) * denom;
    mu[(size_t)c * DD + j] = v;
    s2 += v * v;
  }
  float tot = reduce256(s2, scratch);
  if (t == 0) mu2[c] = tot;
}

__device__ __forceinline__ float lval(const float* td, const float* tl, int i, int j) {
  if (i == j) return fabsf(td[i]);
  if (i > j) return tl[(size_t)i * DD + j];
  return 0.f;
}

__global__ void k_base(const float* td, const float* tl, const float* m,
                       const float* kapnu, float* base) {
  int ti, tj; tri_decode(blockIdx.x, ti, tj);
  __shared__ float Ta[16][65], Tb[16][65];
  int t = threadIdx.x, tx = t & 15, ty = t >> 4;
  int r0 = ty * 4, c0 = tx * 4;
  float acc[4][4] = {};
  int kmax = (tj + 1) * 64;
  for (int kk = 0; kk < kmax; kk += 16) {
    __syncthreads();
    for (int idx = t; idx < 64 * 16; idx += 256) {
      int r = idx >> 4, p = idx & 15;
      Ta[p][r] = lval(td, tl, ti * 64 + r, kk + p);
      Tb[p][r] = lval(td, tl, tj * 64 + r, kk + p);
    }
    __syncthreads();
#pragma unroll
    for (int p = 0; p < 16; p++) {
      float av[4], bv[4];
#pragma unroll
      for (int a = 0; a < 4; a++) av[a] = Ta[p][r0 + a];
#pragma unroll
      for (int b = 0; b < 4; b++) bv[b] = Tb[p][c0 + b];
#pragma unroll
      for (int a = 0; a < 4; a++)
#pragma unroll
        for (int b = 0; b < 4; b++) acc[a][b] += av[a] * bv[b];
    }
  }
  float kap = kapnu[0];
#pragma unroll
  for (int a = 0; a < 4; a++)
#pragma unroll
    for (int b = 0; b < 4; b++) {
      int gi = ti * 64 + r0 + a, gj = tj * 64 + c0 + b;
      base[(size_t)gi * DD + gj] = acc[a][b] + kap * m[gi] * m[gj];
    }
}

__global__ __launch_bounds__(256) void k_syrk_mfma(const short* XTh, const short* XTl,
                                                   const float* base, const float* mu,
                                                   const float* beta, const float* invs,
                                                   const int* counts, const int* offsets,
                                                   float* sigma) {
  int bb = blockIdx.x;
  int cls = bb / 36, tr = bb % 36;
  int ti, tj; tri_decode(tr, ti, tj);
  int cnt = counts[cls], off = offsets[cls];
  float* Sg = sigma + ((size_t)cls << 20);
  const float* muc = mu + (size_t)cls * DD;
  __shared__ short Ah[128 * 40], Al[128 * 40], Bh[128 * 40], Bl[128 * 40];
  int t = threadIdx.x;
  int wave = t >> 6, lane = t & 63;
  int wr = wave >> 1, wc = wave & 1;
  int quad = lane >> 4, l15 = lane & 15;
  int i0 = ti * 128, j0 = tj * 128;
  bool same = (ti == tj);
  floatx4 acc[4][4];
#pragma unroll
  for (int a = 0; a < 4; a++)
#pragma unroll
    for (int b = 0; b < 4; b++) acc[a][b] = (floatx4){0.f, 0.f, 0.f, 0.f};
  for (int nn = 0; nn < cnt; nn += 32) {
    __syncthreads();
#pragma unroll
    for (int r = 0; r < 2; r++) {
      int lin = r * 256 + t;
      int row = lin >> 2, kg = (lin & 3) << 3;
      size_t sA = (size_t)(i0 + row) * NP + off + nn + kg;
      *(s16x8*)&Ah[row * 40 + kg] = *(const s16x8*)&XTh[sA];
      *(s16x8*)&Al[row * 40 + kg] = *(const s16x8*)&XTl[sA];
      if (!same) {
        size_t sB = (size_t)(j0 + row) * NP + off + nn + kg;
        *(s16x8*)&Bh[row * 40 + kg] = *(const s16x8*)&XTh[sB];
        *(s16x8*)&Bl[row * 40 + kg] = *(const s16x8*)&XTl[sB];
      }
    }
    __syncthreads();
    const short* PBh = same ? Ah : Bh;
    const short* PBl = same ? Al : Bl;
    s16x8 ah[4], al[4], bh[4], bl[4];
#pragma unroll
    for (int f = 0; f < 4; f++) {
      ah[f] = *(const s16x8*)&Ah[(wr * 64 + f * 16 + l15) * 40 + quad * 8];
      al[f] = *(const s16x8*)&Al[(wr * 64 + f * 16 + l15) * 40 + quad * 8];
      bh[f] = *(const s16x8*)&PBh[(wc * 64 + f * 16 + l15) * 40 + quad * 8];
      bl[f] = *(const s16x8*)&PBl[(wc * 64 + f * 16 + l15) * 40 + quad * 8];
    }
#pragma unroll
    for (int fi = 0; fi < 4; fi++)
#pragma unroll
      for (int fj = 0; fj < 4; fj++) {
        acc[fi][fj] = __builtin_amdgcn_mfma_f32_16x16x32_bf16(ah[fi], bh[fj], acc[fi][fj], 0, 0, 0);
        acc[fi][fj] = __builtin_amdgcn_mfma_f32_16x16x32_bf16(ah[fi], bl[fj], acc[fi][fj], 0, 0, 0);
        acc[fi][fj] = __builtin_amdgcn_mfma_f32_16x16x32_bf16(al[fi], bh[fj], acc[fi][fj], 0, 0, 0);
      }
  }
  float bet = beta[cls], isc = invs[cls];
#pragma unroll
  for (int fi = 0; fi < 4; fi++)
#pragma unroll
    for (int fj = 0; fj < 4; fj++)
#pragma unroll
      for (int reg = 0; reg < 4; reg++) {
        int gi = i0 + wr * 64 + fi * 16 + quad * 4 + reg;
        int gj = j0 + wc * 64 + fj * 16 + l15;
        float v = acc[fi][fj][reg] + base[(size_t)gi * DD + gj] - bet * muc[gi] * muc[gj];
        Sg[(size_t)gi * DD + gj] = v * isc;
      }
}

// ---------------- factorization ----------------
// R1-proven (best config: 1487us, R3): register-cached LDL^T elimination
// (63 rounds, 1 barrier/step) + level-doubling triangular inversion.
// CLOSED SUBSYSTEM: R2 (width-8 blocked), R4 (width-4 blocked), R7
// (wave-local shfl sweep) ALL regressed — redundant work/divergence,
// divergence, and serialized ds_bpermute latency respectively. The simple
// LDS-broadcast sweep is the latency floor at this granularity.
__device__ void chol_inv_reg(float areg[4][4], float* Dinv, int cls, int k, int t,
                             float* Asc, float* Wsc, float* Tsc) {
  __shared__ float colbuf[2][64];
  __shared__ float sdiag[64];
  int tx = t & 15, ty = t >> 4;
  int r0 = ty * 4, c0 = tx * 4;
  for (int j = 0; j < 63; j++) {
    float* cb = colbuf[j & 1];
    if (tx == (j >> 2)) {
      int jj = j & 3;
      cb[r0 + 0] = areg[0][jj];
      cb[r0 + 1] = areg[1][jj];
      cb[r0 + 2] = areg[2][jj];
      cb[r0 + 3] = areg[3][jj];
    }
    __syncthreads();
    float rd = 1.0f / cb[j];
    float rv[4], cv[4];
#pragma unroll
    for (int i = 0; i < 4; i++) rv[i] = cb[r0 + i];
#pragma unroll
    for (int b = 0; b < 4; b++) cv[b] = cb[c0 + b];
#pragma unroll
    for (int i = 0; i < 4; i++)
#pragma unroll
      for (int b = 0; b < 4; b++)
        if (c0 + b > j && c0 + b <= r0 + i)
          areg[i][b] -= rv[i] * cv[b] * rd;
  }
  __syncthreads();
  if (tx == ty) {
#pragma unroll
    for (int i = 0; i < 4; i++) sdiag[r0 + i] = 1.0f / sqrtf(areg[i][i]);
  }
  __syncthreads();
  float sd[4];
#pragma unroll
  for (int b = 0; b < 4; b++) sd[b] = sdiag[c0 + b];
  // L (scaled, lower; 0 above) -> Asc; zero Wsc
#pragma unroll
  for (int i = 0; i < 4; i++)
#pragma unroll
    for (int b = 0; b < 4; b++) {
      float lv = (r0 + i >= c0 + b) ? areg[i][b] * sd[b] : 0.f;
      Asc[(r0 + i) * TS + c0 + b] = lv;
      Wsc[(r0 + i) * TS + c0 + b] = 0.f;
    }
  __syncthreads();
  // --- level-doubling inversion of L (in Asc) into Wsc ---
  // base: invert the 16 diagonal 4x4 blocks (forward substitution, local)
  if (t < 16) {
    int c = t * 4;
    float l[4][4], w[4][4];
#pragma unroll
    for (int i = 0; i < 4; i++)
#pragma unroll
      for (int j = 0; j <= i; j++) l[i][j] = Asc[(c + i) * TS + c + j];
#pragma unroll
    for (int j = 0; j < 4; j++) {
      w[j][j] = 1.0f / l[j][j];
#pragma unroll
      for (int i = j + 1; i < 4; i++) {
        float s = 0.f;
#pragma unroll
        for (int kk = j; kk < i; kk++) s += l[i][kk] * w[kk][j];
        w[i][j] = -s / l[i][i];
      }
    }
#pragma unroll
    for (int i = 0; i < 4; i++)
#pragma unroll
      for (int j = 0; j <= i; j++) Wsc[(c + i) * TS + c + j] = w[i][j];
  }
  __syncthreads();
  // combine levels: for each pair [c,c+h) x [c+h,c+2h):
  //   T = L_BA * W_AA   (W_AA lower-tri)
  //   W_BA = -W_BB * T  (W_BB lower-tri)
#pragma unroll 4
  for (int h = 4; h <= 32; h <<= 1) {
    int hh = h * h;
    int total = 32 * h;  // (64/(2h)) pairs * h*h elements
    for (int idx = t; idx < total; idx += 256) {
      int pr = idx / hh;
      int rem = idx - pr * hh;
      int i = rem / h, j = rem - (rem / h) * h;
      int c = pr * 2 * h;
      float s = 0.f;
      for (int kk = j; kk < h; kk++)
        s += Asc[(c + h + i) * TS + c + kk] * Wsc[(c + kk) * TS + c + j];
      Tsc[idx] = s;
    }
    __syncthreads();
    for (int idx = t; idx < total; idx += 256) {
      int pr = idx / hh;
      int rem = idx - pr * hh;
      int i = rem / h, j = rem - (rem / h) * h;
      int c = pr * 2 * h;
      int tb = pr * hh;
      float s = 0.f;
      for (int kk = 0; kk <= i; kk++)
        s += Wsc[(c + h + i) * TS + c + h + kk] * Tsc[tb + kk * h + j];
      Wsc[(c + h + i) * TS + c + j] = -s;
    }
    __syncthreads();
  }
  float* Dv = Dinv + ((size_t)(cls * 16 + k)) * 4096;
  for (int idx4 = t; idx4 < 1024; idx4 += 256) {
    int r = idx4 >> 4, c4 = (idx4 & 15) << 2;
    float4 v = make_float4(Wsc[r * TS + c4], Wsc[r * TS + c4 + 1],
                           Wsc[r * TS + c4 + 2], Wsc[r * TS + c4 + 3]);
    *(float4*)&Dv[r * 64 + c4] = v;
  }
}

__global__ void k_diag0(float* sigma, float* Dinv) {
  __shared__ float A[64 * TS], W[64 * TS];
  __shared__ float Tq[1024];
  int cls = blockIdx.x, t = threadIdx.x;
  int tx = t & 15, ty = t >> 4;
  int r0 = ty * 4, c0 = tx * 4;
  float* Sg = sigma + ((size_t)cls << 20);
  float areg[4][4];
#pragma unroll
  for (int i = 0; i < 4; i++) {
    float4 s = *(const float4*)&Sg[(size_t)(r0 + i) * DD + c0];
    areg[i][0] = s.x; areg[i][1] = s.y; areg[i][2] = s.z; areg[i][3] = s.w;
  }
  chol_inv_reg(areg, Dinv, cls, 0, t, A, W, Tq);
}

// R3: split early steps (k<=7, trailing-work-dominated) into
// panel launch + update launch. Panels P_i = A(i,k)*W_k^T computed ONCE
// (16*nb blocks) and persisted to the upper mirror; update blocks READ the
// persisted panels and do a single 64^3 a3 matmul each.
__global__ void k_panel(float* sigma, const float* Dinv, int k) {
  __shared__ float B0[64 * TS], B1[64 * TS];
  int i_ = blockIdx.x, cls = blockIdx.y, t = threadIdx.x;
  int tx = t & 15, ty = t >> 4;
  int r0 = ty * 4, c0 = tx * 4;
  int it = k + 1 + i_;
  float* Sg = sigma + ((size_t)cls << 20);
  const float* Dv = Dinv + ((size_t)(cls * 16 + k)) * 4096;
  for (int i = 0; i < 4; i++) {
    int idx4 = i * 256 + t;
    int r = idx4 >> 4, c4 = (idx4 & 15) << 2;
    float4 v0 = *(const float4*)&Dv[r * 64 + c4];
    B0[r * TS + c4] = v0.x; B0[r * TS + c4 + 1] = v0.y;
    B0[r * TS + c4 + 2] = v0.z; B0[r * TS + c4 + 3] = v0.w;
    float4 v1 = *(const float4*)&Sg[(size_t)(it * 64 + r) * DD + k * 64 + c4];
    B1[r * TS + c4] = v1.x; B1[r * TS + c4 + 1] = v1.y;
    B1[r * TS + c4 + 2] = v1.z; B1[r * TS + c4 + 3] = v1.w;
  }
  __syncthreads();
  float a1[4][4] = {};
#pragma unroll 8
  for (int p = 0; p < 64; p++) {
    float bv[4], av1[4];
#pragma unroll
    for (int bq = 0; bq < 4; bq++) bv[bq] = B0[(c0 + bq) * TS + p];
#pragma unroll
    for (int a = 0; a < 4; a++) av1[a] = B1[(r0 + a) * TS + p];
#pragma unroll
    for (int a = 0; a < 4; a++)
#pragma unroll
      for (int bq = 0; bq < 4; bq++) a1[a][bq] += av1[a] * bv[bq];
  }
#pragma unroll
  for (int a = 0; a < 4; a++) {
    float4 v = make_float4(a1[a][0], a1[a][1], a1[a][2], a1[a][3]);
    *(float4*)&Sg[(size_t)(k * 64 + r0 + a) * DD + it * 64 + c0] = v;
  }
}

__global__ void k_update(float* sigma, float* Dinv, int k) {
  __shared__ float B0[64 * TS], B1[64 * TS], B2[64 * TS];
  int b = blockIdx.x, t = threadIdx.x;
  int tx = t & 15, ty = t >> 4;
  int r0 = ty * 4, c0 = tx * 4;
  int nb = 15 - k;
  int nt = nb * (nb + 1) / 2;
  int cls, a_, b_;
  bool special = (b < 16);
  if (special) { cls = b; a_ = 0; b_ = 0; }
  else {
    int jp = b - 16;
    cls = jp / (nt - 1);
    int s = jp % (nt - 1) + 1;
    tri_decode(s, a_, b_);
  }
  int it = k + 1 + a_, jt = k + 1 + b_;
  bool same = (it == jt);
  float* Sg = sigma + ((size_t)cls << 20);
  // load persisted panels P_it (B1) and P_jt (B2) from the upper mirror
  for (int i = 0; i < 4; i++) {
    int idx4 = i * 256 + t;
    int r = idx4 >> 4, c4 = (idx4 & 15) << 2;
    float4 v1 = *(const float4*)&Sg[(size_t)(k * 64 + r) * DD + it * 64 + c4];
    B1[r * TS + c4] = v1.x; B1[r * TS + c4 + 1] = v1.y;
    B1[r * TS + c4 + 2] = v1.z; B1[r * TS + c4 + 3] = v1.w;
    if (!same) {
      float4 v2 = *(const float4*)&Sg[(size_t)(k * 64 + r) * DD + jt * 64 + c4];
      B2[r * TS + c4] = v2.x; B2[r * TS + c4 + 1] = v2.y;
      B2[r * TS + c4 + 2] = v2.z; B2[r * TS + c4 + 3] = v2.w;
    }
  }
  __syncthreads();
  float* PB = same ? B1 : B2;
  float a3[4][4] = {};
#pragma unroll 8
  for (int p = 0; p < 64; p++) {
    float av[4], bv[4];
#pragma unroll
    for (int a = 0; a < 4; a++) av[a] = B1[(r0 + a) * TS + p];
#pragma unroll
    for (int bq = 0; bq < 4; bq++) bv[bq] = PB[(c0 + bq) * TS + p];
#pragma unroll
    for (int a = 0; a < 4; a++)
#pragma unroll
      for (int bq = 0; bq < 4; bq++) a3[a][bq] += av[a] * bv[bq];
  }
  if (!special) {
#pragma unroll
    for (int a = 0; a < 4; a++) {
      size_t addr = (size_t)(it * 64 + r0 + a) * DD + jt * 64 + c0;
      float4 s = *(const float4*)&Sg[addr];
      s.x -= a3[a][0]; s.y -= a3[a][1]; s.z -= a3[a][2]; s.w -= a3[a][3];
      *(float4*)&Sg[addr] = s;
    }
    return;
  }
  // special: updated (k+1,k+1) tile straight into registers, then factor
  float areg[4][4];
#pragma unroll
  for (int i = 0; i < 4; i++) {
    size_t addr = (size_t)(it * 64 + r0 + i) * DD + jt * 64 + c0;
    float4 s = *(const float4*)&Sg[addr];
    areg[i][0] = s.x - a3[i][0]; areg[i][1] = s.y - a3[i][1];
    areg[i][2] = s.z - a3[i][2]; areg[i][3] = s.w - a3[i][3];
  }
  __syncthreads();
  chol_inv_reg(areg, Dinv, cls, k + 1, t, B1, B2, B0);
}

// merged step k (used for k>7 where work is small / latency-dominated)
__global__ void k_cholstep(float* sigma, float* Dinv, int k) {
  __shared__ float B0[64 * TS], B1[64 * TS], B2[64 * TS];
  int b = blockIdx.x, t = threadIdx.x;
  int tx = t & 15, ty = t >> 4;
  int r0 = ty * 4, c0 = tx * 4;
  int nb = 15 - k;
  int nt = nb * (nb + 1) / 2;
  int cls, a_, b_;
  bool special = (b < 16);
  if (special) { cls = b; a_ = 0; b_ = 0; }
  else {
    int jp = b - 16;
    cls = jp / (nt - 1);
    int s = jp % (nt - 1) + 1;
    tri_decode(s, a_, b_);
  }
  int it = k + 1 + a_, jt = k + 1 + b_;
  bool same = (it == jt);
  float* Sg = sigma + ((size_t)cls << 20);
  const float* Dv = Dinv + ((size_t)(cls * 16 + k)) * 4096;
  for (int i = 0; i < 4; i++) {
    int idx4 = i * 256 + t;
    int r = idx4 >> 4, c4 = (idx4 & 15) << 2;
    float4 v0 = *(const float4*)&Dv[r * 64 + c4];
    B0[r * TS + c4] = v0.x; B0[r * TS + c4 + 1] = v0.y;
    B0[r * TS + c4 + 2] = v0.z; B0[r * TS + c4 + 3] = v0.w;
    float4 v1 = *(const float4*)&Sg[(size_t)(it * 64 + r) * DD + k * 64 + c4];
    B1[r * TS + c4] = v1.x; B1[r * TS + c4 + 1] = v1.y;
    B1[r * TS + c4 + 2] = v1.z; B1[r * TS + c4 + 3] = v1.w;
    if (!same) {
      float4 v2 = *(const float4*)&Sg[(size_t)(jt * 64 + r) * DD + k * 64 + c4];
      B2[r * TS + c4] = v2.x; B2[r * TS + c4 + 1] = v2.y;
      B2[r * TS + c4 + 2] = v2.z; B2[r * TS + c4 + 3] = v2.w;
    }
  }
  __syncthreads();
  // fused: a1 = B1*B0^T, a2 = B2*B0^T (shared bv)
  float a1[4][4] = {}, a2[4][4] = {};
#pragma unroll 8
  for (int p = 0; p < 64; p++) {
    float bv[4], av1[4];
#pragma unroll
    for (int bq = 0; bq < 4; bq++) bv[bq] = B0[(c0 + bq) * TS + p];
#pragma unroll
    for (int a = 0; a < 4; a++) av1[a] = B1[(r0 + a) * TS + p];
#pragma unroll
    for (int a = 0; a < 4; a++)
#pragma unroll
      for (int bq = 0; bq < 4; bq++) a1[a][bq] += av1[a] * bv[bq];
    if (!same) {
      float av2[4];
#pragma unroll
      for (int a = 0; a < 4; a++) av2[a] = B2[(r0 + a) * TS + p];
#pragma unroll
      for (int a = 0; a < 4; a++)
#pragma unroll
        for (int bq = 0; bq < 4; bq++) a2[a][bq] += av2[a] * bv[bq];
    }
  }
  __syncthreads();
#pragma unroll
  for (int a = 0; a < 4; a++)
#pragma unroll
    for (int bq = 0; bq < 4; bq++) {
      B1[(r0 + a) * TS + c0 + bq] = a1[a][bq];
      if (!same) B2[(r0 + a) * TS + c0 + bq] = a2[a][bq];
    }
  if (b_ == 0) {
#pragma unroll
    for (int a = 0; a < 4; a++) {
      float4 v = make_float4(a1[a][0], a1[a][1], a1[a][2], a1[a][3]);
      *(float4*)&Sg[(size_t)(k * 64 + r0 + a) * DD + it * 64 + c0] = v;
    }
  }
  __syncthreads();
  float* PB = same ? B1 : B2;
  float a3[4][4] = {};
#pragma unroll 8
  for (int p = 0; p < 64; p++) {
    float av[4], bv[4];
#pragma unroll
    for (int a = 0; a < 4; a++) av[a] = B1[(r0 + a) * TS + p];
#pragma unroll
    for (int bq = 0; bq < 4; bq++) bv[bq] = PB[(c0 + bq) * TS + p];
#pragma unroll
    for (int a = 0; a < 4; a++)
#pragma unroll
      for (int bq = 0; bq < 4; bq++) a3[a][bq] += av[a] * bv[bq];
  }
  if (!special) {
#pragma unroll
    for (int a = 0; a < 4; a++) {
      size_t addr = (size_t)(it * 64 + r0 + a) * DD + jt * 64 + c0;
      float4 s = *(const float4*)&Sg[addr];
      s.x -= a3[a][0]; s.y -= a3[a][1]; s.z -= a3[a][2]; s.w -= a3[a][3];
      *(float4*)&Sg[addr] = s;
    }
    return;
  }
  // special: updated (k+1,k+1) tile straight into registers, then factor
  float areg[4][4];
#pragma unroll
  for (int i = 0; i < 4; i++) {
    size_t addr = (size_t)(it * 64 + r0 + i) * DD + jt * 64 + c0;
    float4 s = *(const float4*)&Sg[addr];
    areg[i][0] = s.x - a3[i][0]; areg[i][1] = s.y - a3[i][1];
    areg[i][2] = s.z - a3[i][2]; areg[i][3] = s.w - a3[i][3];
  }
  __syncthreads();
  // B0 (held W_k) is dead here -> reuse as the level-doubling T scratch
  chol_inv_reg(areg, Dinv, cls, k + 1, t, B1, B2, B0);
}

// level-1 V combine (width 64->128), fully in-LDS: V21 = -W1 * R * W0
__global__ void k_vl1(float* sigma, const float* Dinv) {
  __shared__ float Rl[64 * TS], W0s[64 * TS], W1s[64 * TS], Ts[64 * TS];
  int b = blockIdx.x, t = threadIdx.x;
  int cls = b >> 3, i = b & 7;
  int t0 = 2 * i, t1 = 2 * i + 1;
  float* Sg = sigma + ((size_t)cls << 20);
  int tx = t & 15, ty = t >> 4;
  int r0 = ty * 4, c0 = tx * 4;
  const float* Dv0 = Dinv + ((size_t)(cls * 16 + t0)) * 4096;
  const float* Dv1 = Dinv + ((size_t)(cls * 16 + t1)) * 4096;
  for (int idx4 = t; idx4 < 1024; idx4 += 256) {
    int r = idx4 >> 4, c4 = (idx4 & 15) << 2;
    float4 vr = *(const float4*)&Sg[(size_t)(t0 * 64 + r) * DD + t1 * 64 + c4];
    Rl[r * TS + c4] = vr.x; Rl[r * TS + c4 + 1] = vr.y;
    Rl[r * TS + c4 + 2] = vr.z; Rl[r * TS + c4 + 3] = vr.w;
    float4 v0 = *(const float4*)&Dv0[r * 64 + c4];
    W0s[r * TS + c4] = v0.x; W0s[r * TS + c4 + 1] = v0.y;
    W0s[r * TS + c4 + 2] = v0.z; W0s[r * TS + c4 + 3] = v0.w;
    float4 v1 = *(const float4*)&Dv1[r * 64 + c4];
    W1s[r * TS + c4] = v1.x; W1s[r * TS + c4 + 1] = v1.y;
    W1s[r * TS + c4 + 2] = v1.z; W1s[r * TS + c4 + 3] = v1.w;
  }
  __syncthreads();
  float aT[4][4] = {};
#pragma unroll 8
  for (int p = 0; p < 64; p++) {
    float av[4], bv[4];
#pragma unroll
    for (int a = 0; a < 4; a++) av[a] = Rl[(r0 + a) * TS + p];
#pragma unroll
    for (int bq = 0; bq < 4; bq++) bv[bq] = W0s[p * TS + c0 + bq];
#pragma unroll
    for (int a = 0; a < 4; a++)
#pragma unroll
      for (int bq = 0; bq < 4; bq++) aT[a][bq] += av[a] * bv[bq];
  }
  __syncthreads();
#pragma unroll
  for (int a = 0; a < 4; a++)
#pragma unroll
    for (int bq = 0; bq < 4; bq++) Ts[(r0 + a) * TS + c0 + bq] = aT[a][bq];
  __syncthreads();
  float aV[4][4] = {};
#pragma unroll 8
  for (int p = 0; p < 64; p++) {
    float av[4], bv[4];
#pragma unroll
    for (int a = 0; a < 4; a++) av[a] = W1s[(r0 + a) * TS + p];
#pragma unroll
    for (int bq = 0; bq < 4; bq++) bv[bq] = Ts[p * TS + c0 + bq];
#pragma unroll
    for (int a = 0; a < 4; a++)
#pragma unroll
      for (int bq = 0; bq < 4; bq++) aV[a][bq] += av[a] * bv[bq];
  }
#pragma unroll
  for (int a = 0; a < 4; a++)
    *(float4*)&Sg[(size_t)(t0 * 64 + r0 + a) * DD + t1 * 64 + c0] =
        make_float4(-aV[a][0], -aV[a][1], -aV[a][2], -aV[a][3]);
}

// level-L launch A: T(a,b) = sum_m R21(a,m) * V11(m,b); T -> lower scratch
__global__ void k_vlA(float* sigma, const float* Dinv, int w) {
  __shared__ float Xs[64 * TS], Ys[64 * TS];
  int aa = blockIdx.x / w, bb = blockIdx.x % w;
  int base = blockIdx.y * 2 * w, cls = blockIdx.z;
  float* Sg = sigma + ((size_t)cls << 20);
  int t = threadIdx.x, tx = t & 15, ty = t >> 4;
  int r0 = ty * 4, c0 = tx * 4;
  float acc[4][4] = {};
  for (int m = bb; m < w; m++) {
    __syncthreads();
    for (int idx4 = t; idx4 < 1024; idx4 += 256) {
      int r = idx4 >> 4, c4 = (idx4 & 15) << 2;
      float4 v = *(const float4*)&Sg[(size_t)((base + m) * 64 + r) * DD + (base + w + aa) * 64 + c4];
      Xs[r * TS + c4] = v.x; Xs[r * TS + c4 + 1] = v.y;
      Xs[r * TS + c4 + 2] = v.z; Xs[r * TS + c4 + 3] = v.w;
    }
    if (m == bb) {
      const float* Dv = Dinv + ((size_t)(cls * 16 + base + bb)) * 4096;
      for (int idx4 = t; idx4 < 1024; idx4 += 256) {
        int r = idx4 >> 4, c4 = (idx4 & 15) << 2;
        float4 v = *(const float4*)&Dv[r * 64 + c4];
        Ys[r * TS + c4] = v.x; Ys[r * TS + c4 + 1] = v.y;
        Ys[r * TS + c4 + 2] = v.z; Ys[r * TS + c4 + 3] = v.w;
      }
    } else {
      for (int idx4 = t; idx4 < 1024; idx4 += 256) {
        int p = idx4 >> 4, c4 = (idx4 & 15) << 2;
        float4 v = *(const float4*)&Sg[(size_t)((base + bb) * 64 + p) * DD + (base + m) * 64 + c4];
        Ys[p * TS + c4] = v.x; Ys[p * TS + c4 + 1] = v.y;
        Ys[p * TS + c4 + 2] = v.z; Ys[p * TS + c4 + 3] = v.w;
      }
    }
    __syncthreads();
#pragma unroll 8
    for (int p = 0; p < 64; p++) {
      float av[4], bv[4];
#pragma unroll
      for (int a = 0; a < 4; a++) av[a] = Xs[(r0 + a) * TS + p];
#pragma unroll
      for (int bq = 0; bq < 4; bq++) bv[bq] = Ys[p * TS + c0 + bq];
#pragma unroll
      for (int a = 0; a < 4; a++)
#pragma unroll
        for (int bq = 0; bq < 4; bq++) acc[a][bq] += av[a] * bv[bq];
    }
  }
#pragma unroll
  for (int a = 0; a < 4; a++)
    *(float4*)&Sg[(size_t)((base + w + aa) * 64 + r0 + a) * DD + (base + bb) * 64 + c0] =
        make_float4(acc[a][0], acc[a][1], acc[a][2], acc[a][3]);
}

// level-L launch B: V21(a,b) = -sum_{m<=a} V22(a,m) * T(m,b); -> upper mirror
__global__ void k_vlB(float* sigma, const float* Dinv, int w) {
  __shared__ float Xs[64 * TS], Ys[64 * TS];
  int aa = blockIdx.x / w, bb = blockIdx.x % w;
  int base = blockIdx.y * 2 * w, cls = blockIdx.z;
  float* Sg = sigma + ((size_t)cls << 20);
  int t = threadIdx.x, tx = t & 15, ty = t >> 4;
  int r0 = ty * 4, c0 = tx * 4;
  float acc[4][4] = {};
  for (int m = 0; m <= aa; m++) {
    __syncthreads();
    if (m == aa) {
      const float* Dv = Dinv + ((size_t)(cls * 16 + base + w + aa)) * 4096;
      for (int idx4 = t; idx4 < 1024; idx4 += 256) {
        int r = idx4 >> 4, c4 = (idx4 & 15) << 2;
        float4 v = *(const float4*)&Dv[r * 64 + c4];
        Xs[r * TS + c4] = v.x; Xs[r * TS + c4 + 1] = v.y;
        Xs[r * TS + c4 + 2] = v.z; Xs[r * TS + c4 + 3] = v.w;
      }
    } else {
      for (int idx4 = t; idx4 < 1024; idx4 += 256) {
        int r = idx4 >> 4, c4 = (idx4 & 15) << 2;
        float4 v = *(const float4*)&Sg[(size_t)((base + w + m) * 64 + r) * DD + (base + w + aa) * 64 + c4];
        Xs[r * TS + c4] = v.x; Xs[r * TS + c4 + 1] = v.y;
        Xs[r * TS + c4 + 2] = v.z; Xs[r * TS + c4 + 3] = v.w;
      }
    }
    for (int idx4 = t; idx4 < 1024; idx4 += 256) {
      int p = idx4 >> 4, c4 = (idx4 & 15) << 2;
      float4 v = *(const float4*)&Sg[(size_t)((base + w + m) * 64 + p) * DD + (base + bb) * 64 + c4];
      Ys[p * TS + c4] = v.x; Ys[p * TS + c4 + 1] = v.y;
      Ys[p * TS + c4 + 2] = v.z; Ys[p * TS + c4 + 3] = v.w;
    }
    __syncthreads();
#pragma unroll 8
    for (int p = 0; p < 64; p++) {
      float av[4], bv[4];
#pragma unroll
      for (int a = 0; a < 4; a++) av[a] = Xs[(r0 + a) * TS + p];
#pragma unroll
      for (int bq = 0; bq < 4; bq++) bv[bq] = Ys[p * TS + c0 + bq];
#pragma unroll
      for (int a = 0; a < 4; a++)
#pragma unroll
        for (int bq = 0; bq < 4; bq++) acc[a][bq] += av[a] * bv[bq];
    }
  }
#pragma unroll
  for (int a = 0; a < 4; a++)
    *(float4*)&Sg[(size_t)((base + bb) * 64 + r0 + a) * DD + (base + w + aa) * 64 + c0] =
        make_float4(-acc[a][0], -acc[a][1], -acc[a][2], -acc[a][3]);
}

// 2176 blocks: packed-fp16 V-tile copy (half8 writes) + fused u-partial
__global__ void k_finalize(const float* sigma, const float* Dinv, const float* mu,
                           float* uarr, _Float16* UT) {
  __shared__ float U0[64 * TS];
  __shared__ float CS[4 * 64];
  int jp = blockIdx.x, t = threadIdx.x;
  int cls = jp / 136, tr = jp % 136;
  int nt_, kt_; tri_decode(tr, nt_, kt_);   // nt_ >= kt_
  const float* muc = mu + (size_t)cls * DD;
  _Float16* outp = UT + (size_t)cls * UT_CLS_STRIDE + (size_t)tr * 4096;
  const float* srcp;
  size_t row_stride;
  if (kt_ == nt_) {
    srcp = Dinv + ((size_t)(cls * 16 + nt_)) * 4096;
    row_stride = 64;
  } else {
    srcp = sigma + ((size_t)cls << 20) + (size_t)(kt_ * 64) * DD + nt_ * 64;
    row_stride = DD;
  }
  for (int i = 0; i < 2; i++) {
    int g8 = i * 256 + t;            // 512 groups of 8 halves
    int rr = g8 >> 3, c8 = (g8 & 7) << 3;
    float4 v0 = *(const float4*)&srcp[(size_t)rr * row_stride + c8];
    float4 v1 = *(const float4*)&srcp[(size_t)rr * row_stride + c8 + 4];
    half8 h;
    h[0] = (_Float16)v0.x; h[1] = (_Float16)v0.y; h[2] = (_Float16)v0.z; h[3] = (_Float16)v0.w;
    h[4] = (_Float16)v1.x; h[5] = (_Float16)v1.y; h[6] = (_Float16)v1.z; h[7] = (_Float16)v1.w;
    *(half8*)&outp[rr * 64 + c8] = h;
    U0[rr * TS + c8] = v0.x; U0[rr * TS + c8 + 1] = v0.y;
    U0[rr * TS + c8 + 2] = v0.z; U0[rr * TS + c8 + 3] = v0.w;
    U0[rr * TS + c8 + 4] = v1.x; U0[rr * TS + c8 + 5] = v1.y;
    U0[rr * TS + c8 + 6] = v1.z; U0[rr * TS + c8 + 7] = v1.w;
  }
  __syncthreads();
  int g = t >> 6, r = t & 63;
  float s = 0.f;
  for (int c = g * 16; c < g * 16 + 16; c++)
    s += U0[r * TS + c] * muc[kt_ * 64 + c];
  CS[g * 64 + r] = s;
  __syncthreads();
  if (g == 0)
    atomicAdd(&uarr[(size_t)cls * DD + nt_ * 64 + r],
              CS[r] + CS[64 + r] + CS[128 + r] + CS[192 + r]);
}

// ---------------- predict side ----------------
__global__ void k_xqdots(const float* Xq, const float* mu, float* xq2, float* xqmu,
                         _Float16* XqH) {
  __shared__ float xrow[DD];
  int m = blockIdx.x, t = threadIdx.x;
  for (int i = t; i < 256; i += 256)
    ((float4*)xrow)[i] = ((const float4*)(Xq + (size_t)m * DD))[i];
  __syncthreads();
  for (int i = t; i < 256; i += 256) {
    float4 v = ((const float4*)xrow)[i];
    half4 h = {(_Float16)v.x, (_Float16)v.y, (_Float16)v.z, (_Float16)v.w};
    *(half4*)&XqH[(size_t)m * DD + i * 4] = h;
  }
  int wave = t >> 6, lane = t & 63;
  for (int cc = 0; cc < 4; cc++) {
    int c = wave * 4 + cc;
    const float* muc = mu + (size_t)c * DD;
    float s = 0.f;
    for (int j = lane; j < DD; j += 64) s += xrow[j] * muc[j];
    for (int o = 32; o > 0; o >>= 1) s += __shfl_down(s, o, 64);
    if (lane == 0) xqmu[(size_t)m * 16 + c] = s;
  }
  if (wave == 0) {
    float s = 0.f;
    for (int j = lane; j < DD; j += 64) s += xrow[j] * xrow[j];
    for (int o = 32; o > 0; o >>= 1) s += __shfl_down(s, o, 64);
    if (lane == 0) xq2[m] = s;
  }
}

// R3-proven gemmG (160us) + single R8 delta: longest blocks (high ct)
// dispatched first via ct = 7 - blockIdx.y (load-balance tail; math-neutral).
// R6's global_load_lds rewrite REGRESSED (VALUBusy 21->55%) — staging is
// NOT the binding constraint at this 2-barrier structure.
__global__ __launch_bounds__(256) void k_gemmG_mfma(const _Float16* XqH, const _Float16* UT,
                                                    const float* u, float* dout) {
  int mt = blockIdx.x, ct = 7 - (int)blockIdx.y, cls = blockIdx.z;
  const _Float16* Uc = UT + (size_t)cls * UT_CLS_STRIDE;
  __shared__ _Float16 As[128 * 40];
  __shared__ _Float16 Bs[128 * 40];
  int t = threadIdx.x;
  int wave = t >> 6, lane = t & 63;
  int wr = wave >> 1, wc = wave & 1;
  int quad = lane >> 4, l15 = lane & 15;
  int m0 = mt * 128, n0 = ct * 128, NT0 = ct * 2;
  floatx4 acc[4][4];
#pragma unroll
  for (int a = 0; a < 4; a++)
#pragma unroll
    for (int b = 0; b < 4; b++) acc[a][b] = (floatx4){0.f, 0.f, 0.f, 0.f};
  int kmax = (ct + 1) * 128;
  for (int kk = 0; kk < kmax; kk += 32) {
    __syncthreads();
#pragma unroll
    for (int i = 0; i < 2; i++) {
      int lin = i * 256 + t;
      int r = lin >> 2, kg = (lin & 3) * 8;
      *(half8*)&As[r * 40 + kg] = *(const half8*)&XqH[(size_t)(m0 + r) * DD + kk + kg];
    }
    int kt = kk >> 6, k0 = kk & 63;
#pragma unroll
    for (int i = 0; i < 2; i++) {
      int lin = i * 256 + t;
      int nl = lin >> 2, kg = (lin & 3) * 8;
      int s = nl >> 6, np = nl & 63;
      int nt = NT0 + s;
      half8 v = {};
      if (kt <= nt)
        v = *(const half8*)&Uc[(size_t)(nt * (nt + 1) / 2 + kt) * 4096 + np * 64 + k0 + kg];
      *(half8*)&Bs[nl * 40 + kg] = v;
    }
    __syncthreads();
    half8 af[4], bf[4];
#pragma unroll
    for (int f = 0; f < 4; f++) {
      af[f] = *(const half8*)&As[(wr * 64 + f * 16 + l15) * 40 + quad * 8];
      bf[f] = *(const half8*)&Bs[(wc * 64 + f * 16 + l15) * 40 + quad * 8];
    }
#pragma unroll
    for (int fi = 0; fi < 4; fi++)
#pragma unroll
      for (int fj = 0; fj < 4; fj++)
        acc[fi][fj] = __builtin_amdgcn_mfma_f32_16x16x32_f16(af[fi], bf[fj], acc[fi][fj], 0, 0, 0);
  }
  float uv[4];
#pragma unroll
  for (int fj = 0; fj < 4; fj++)
    uv[fj] = u[(size_t)cls * DD + n0 + wc * 64 + fj * 16 + l15];
#pragma unroll
  for (int fi = 0; fi < 4; fi++) {
#pragma unroll
    for (int r = 0; r < 4; r++) {
      float p = 0.f;
#pragma unroll
      for (int fj = 0; fj < 4; fj++) {
        float e = acc[fi][fj][r] - uv[fj];
        p += e * e;
      }
      p += __shfl_xor(p, 1, 64);
      p += __shfl_xor(p, 2, 64);
      p += __shfl_xor(p, 4, 64);
      p += __shfl_xor(p, 8, 64);
      if (l15 == 0) {
        int m = m0 + wr * 64 + fi * 16 + quad * 4 + r;
        atomicAdd(&dout[(size_t)m * 16 + cls], p);
      }
    }
  }
}

__global__ void k_logits(const float* xq2, const float* xqmu, const float* mu2,
                         float* dout) {
  size_t idx = (size_t)blockIdx.x * 256 + threadIdx.x;
  int m = (int)(idx >> 4), c = (int)(idx & 15);
  float q1 = dout[idx];
  float q2 = xq2[m] - 2.0f * xqmu[idx] + mu2[c];
  dout[idx] = -(0.9f * q1 + 0.1f * q2);
}

extern "C" void kernel_launch(void* const* d_in, const int* in_sizes, int n_in,
                              void* d_out, int out_size, void* d_ws, size_t ws_size,
                              hipStream_t stream) {
  (void)in_sizes; (void)n_in; (void)out_size; (void)ws_size;
  const float* X  = (const float*)d_in[0];
  const int*   y  = (const int*)d_in[1];
  const float* Xq = (const float*)d_in[2];
  const float* m  = (const float*)d_in[3];
  const float* kappa = (const float*)d_in[4];
  const float* nu = (const float*)d_in[5];
  const float* td = (const float*)d_in[6];
  const float* tl = (const float*)d_in[7];
  float* out = (float*)d_out;
  float* ws = (float*)d_ws;

  short* XTh   = (short*)(ws + OFF_XTH);
  short* XTl   = (short*)(ws + OFF_XTL);
  _Float16* UT = (_Float16*)ws;              // overlays XT planes (dead after syrk)
  float* baseb = ws + OFF_BASE;
  float* sigma = ws + OFF_SIGMA;
  _Float16* XqH = (_Float16*)sigma;          // overlays sigma (dead after finalize)
  float* Dinv  = ws + OFF_DINV;
  float* sums  = ws + OFF_SUMS;
  float* mu    = ws + OFF_MU;
  float* uarr  = ws + OFF_U;
  float* mu2   = ws + OFF_MU2;
  float* xq2   = ws + OFF_XQ2;
  float* xqmu  = ws + OFF_XQMU;
  float* kapnu = ws + OFF_KAPNU;
  float* cf    = ws + OFF_CF;
  float* beta  = ws + OFF_BETA;
  float* invs  = ws + OFF_INVS;
  int* ints      = (int*)(ws + OFF_INTS);
  int* counts    = ints;
  int* offsets   = ints + 16;
  int* cls_of_pt = ints + 32;
  int* order     = ints + 32 + PT_TILES;

  k_scalars<<<1, 256, 0, stream>>>(y, kappa, nu, kapnu, cf, beta, invs,
                                   counts, offsets, cls_of_pt, order,
                                   sums, uarr, out);
  k_gatherT<<<dim3(PT_TILES, 16), 256, 0, stream>>>(X, order, cls_of_pt, XTh, XTl, sums);
  k_mumu2<<<16, 256, 0, stream>>>(sums, m, kapnu, cf, mu, mu2);
  k_base<<<136, 256, 0, stream>>>(td, tl, m, kapnu, baseb);
  k_syrk_mfma<<<16 * 36, 256, 0, stream>>>(XTh, XTl, baseb, mu, beta, invs,
                                           counts, offsets, sigma);
  k_diag0<<<16, 256, 0, stream>>>(sigma, Dinv);
  for (int k = 0; k < 15; k++) {
    int nb = 15 - k;
    int nt = nb * (nb + 1) / 2;
    if (k <= 7) {
      k_panel<<<dim3(nb, 16), 256, 0, stream>>>(sigma, Dinv, k);
      k_update<<<16 * nt, 256, 0, stream>>>(sigma, Dinv, k);
    } else {
      k_cholstep<<<16 * nt, 256, 0, stream>>>(sigma, Dinv, k);
    }
  }
  k_vl1<<<128, 256, 0, stream>>>(sigma, Dinv);
  for (int L = 2; L <= 4; L++) {
    int w = 1 << (L - 1);
    int ncomb = 8 >> (L - 1);
    k_vlA<<<dim3(w * w, ncomb, 16), 256, 0, stream>>>(sigma, Dinv, w);
    k_vlB<<<dim3(w * w, ncomb, 16), 256, 0, stream>>>(sigma, Dinv, w);
  }
  k_finalize<<<16 * 136, 256, 0, stream>>>(sigma, Dinv, mu, uarr, UT);
  k_xqdots<<<4096, 256, 0, stream>>>(Xq, mu, xq2, xqmu, XqH);
  k_gemmG_mfma<<<dim3(32, 8, 16), 256, 0, stream>>>(XqH, UT, uarr, out);
  k_logits<<<256, 256, 0, stream>>>(xq2, xqmu, mu2, out);
}

// Round 9
// 1470.147 us; speedup vs baseline: 1.8471x; 1.0072x over previous
//
#include <hip/hip_runtime.h>
#include <math.h>

#define DD 1024
#define NP 5120   // padded sample pitch (class offsets padded to 64)
#define PT_TILES 80
#define TS 65     // fp32 LDS tile stride (bank-step 4 for 4-row column reads => 2-way/free)

typedef _Float16 half8 __attribute__((ext_vector_type(8)));
typedef _Float16 half4 __attribute__((ext_vector_type(4)));
typedef float floatx4 __attribute__((ext_vector_type(4)));
typedef short s16x8 __attribute__((ext_vector_type(8)));

// ---------------- workspace layout (float offsets) ----------------
#define OFF_XTH   ((size_t)0)
#define OFF_XTL   ((size_t)2621440)
#define OFF_BASE  ((size_t)5242880)
#define OFF_SIGMA ((size_t)6291456)    // 16*1024*1024 fp32 (lower: Schur, upper: R panels then V)
#define OFF_DINV  ((size_t)23068672)
#define OFF_SUMS  ((size_t)24117248)
#define OFF_MU    ((size_t)24133632)
#define OFF_U     ((size_t)24150016)
#define OFF_MU2   ((size_t)24166400)
#define OFF_XQ2   ((size_t)24166416)
#define OFF_XQMU  ((size_t)24170512)
#define OFF_KAPNU ((size_t)24236048)
#define OFF_CF    ((size_t)24236056)
#define OFF_BETA  ((size_t)24236072)
#define OFF_INVS  ((size_t)24236088)
#define OFF_INTS  ((size_t)24236104)

#define UT_CLS_STRIDE ((size_t)557056) // 136 tiles * 4096 halves

__device__ __forceinline__ void tri_decode(int b, int& ti, int& tj) {
  int t = 0;
  while ((t + 1) * (t + 2) / 2 <= b) t++;
  ti = t;
  tj = b - t * (t + 1) / 2;
}

__device__ __forceinline__ short f2bf(float f) {
  union { float f; unsigned u; } v; v.f = f;
  unsigned r = v.u + 0x7FFF + ((v.u >> 16) & 1);
  return (short)(r >> 16);
}
__device__ __forceinline__ float bf2f(short b) {
  union { unsigned u; float f; } v; v.u = ((unsigned)(unsigned short)b) << 16; return v.f;
}

__device__ __forceinline__ float reduce256(float v, float* scratch) {
  for (int o = 32; o > 0; o >>= 1) v += __shfl_down(v, o, 64);
  int lane = threadIdx.x & 63, w = threadIdx.x >> 6;
  __syncthreads();
  if (lane == 0) scratch[w] = v;
  __syncthreads();
  return scratch[0] + scratch[1] + scratch[2] + scratch[3];
}

// ---------------- stats ----------------
__global__ void k_scalars(const int* y, const float* kappa, const float* nu,
                          float* kapnu, float* cf, float* beta, float* invs,
                          int* counts, int* offsets, int* cls_of_pt, int* order,
                          float* sums, float* uarr, float* dout) {
  __shared__ int h[16];
  __shared__ int cur[16];
  int t = threadIdx.x;
  if (t < 16) h[t] = 0;
  __syncthreads();
  for (int n = t; n < 4096; n += 256) atomicAdd(&h[y[n]], 1);
  __syncthreads();
  if (t == 0) {
    float kap = fabsf(kappa[0]) + 1e-6f;
    float nu_ = fmaxf(nu[0], 1024.0f - 1.0f + 1e-6f);
    kapnu[0] = kap; kapnu[1] = nu_;
    int off = 0, tile = 0;
    for (int c = 0; c < 16; c++) {
      counts[c] = h[c]; offsets[c] = off; cur[c] = off;
      cf[c] = (float)h[c];
      beta[c] = kap + (float)h[c];
      invs[c] = 1.0f / (nu_ + (float)h[c] + 1024.0f + 2.0f);
      int ntile = ((h[c] + 63) & ~63) >> 6;
      for (int q = 0; q < ntile && tile < PT_TILES; q++) cls_of_pt[tile++] = c;
      off += (h[c] + 63) & ~63;
    }
    while (tile < PT_TILES) cls_of_pt[tile++] = -1;
  }
  for (int i = t; i < NP; i += 256) order[i] = -1;
  for (int i = t; i < 16 * 1024; i += 256) { sums[i] = 0.f; uarr[i] = 0.f; }
  for (int i = t; i < 4096 * 16; i += 256) dout[i] = 0.f;
  __syncthreads();
  for (int n = t; n < 4096; n += 256) {
    int c = y[n];
    int p = atomicAdd(&cur[c], 1);
    order[p] = n;
  }
}

__global__ void k_gatherT(const float* X, const int* order, const int* cls_of_pt,
                          short* XTh, short* XTl, float* sums) {
  int pt = blockIdx.x, dt = blockIdx.y, t = threadIdx.x;
  __shared__ float T[64 * TS];
  __shared__ float CS[4 * 64];
  __shared__ int src[64];
  if (t < 64) src[t] = order[pt * 64 + t];
  __syncthreads();
  for (int i = 0; i < 4; i++) {
    int idx4 = i * 256 + t;
    int r = idx4 >> 4, c4 = (idx4 & 15) << 2;
    int s = src[r];
    float4 v = (s >= 0) ? *(const float4*)&X[(size_t)s * DD + dt * 64 + c4]
                        : make_float4(0.f, 0.f, 0.f, 0.f);
    T[r * TS + c4] = v.x; T[r * TS + c4 + 1] = v.y;
    T[r * TS + c4 + 2] = v.z; T[r * TS + c4 + 3] = v.w;
  }
  __syncthreads();
  for (int i = 0; i < 16; i++) {
    int lin = i * 256 + t;
    int d = lin >> 6, p = lin & 63;
    float v = T[p * TS + d];
    short hi = f2bf(v);
    float lov = v - bf2f(hi);
    size_t addr = (size_t)(dt * 64 + d) * NP + pt * 64 + p;
    XTh[addr] = hi;
    XTl[addr] = f2bf(lov);
  }
  int cls = cls_of_pt[pt];
  if (cls < 0) return;
  int g = t >> 6, d = t & 63;
  float s = 0.f;
  for (int p = g * 16; p < g * 16 + 16; p++) s += T[p * TS + d];
  CS[g * 64 + d] = s;
  __syncthreads();
  if (g == 0)
    atomicAdd(&sums[(size_t)cls * DD + dt * 64 + d],
              CS[d] + CS[64 + d] + CS[128 + d] + CS[192 + d]);
}

__global__ void k_mumu2(const float* sums, const float* m, const float* kapnu,
                        const float* cf, float* mu, float* mu2) {
  __shared__ float scratch[4];
  int c = blockIdx.x, t = threadIdx.x;
  float kap = kapnu[0];
  float denom = 1.0f / (kap + cf[c]);
  float s2 = 0.f;
  for (int j = t; j < DD; j += 256) {
    float v = (kap * m[j] + sums[(size_t)c * DD + j]) * denom;
    mu[(size_t)c * DD + j] = v;
    s2 += v * v;
  }
  float tot = reduce256(s2, scratch);
  if (t == 0) mu2[c] = tot;
}

__device__ __forceinline__ float lval(const float* td, const float* tl, int i, int j) {
  if (i == j) return fabsf(td[i]);
  if (i > j) return tl[(size_t)i * DD + j];
  return 0.f;
}

__global__ void k_base(const float* td, const float* tl, const float* m,
                       const float* kapnu, float* base) {
  int ti, tj; tri_decode(blockIdx.x, ti, tj);
  __shared__ float Ta[16][65], Tb[16][65];
  int t = threadIdx.x, tx = t & 15, ty = t >> 4;
  int r0 = ty * 4, c0 = tx * 4;
  float acc[4][4] = {};
  int kmax = (tj + 1) * 64;
  for (int kk = 0; kk < kmax; kk += 16) {
    __syncthreads();
    for (int idx = t; idx < 64 * 16; idx += 256) {
      int r = idx >> 4, p = idx & 15;
      Ta[p][r] = lval(td, tl, ti * 64 + r, kk + p);
      Tb[p][r] = lval(td, tl, tj * 64 + r, kk + p);
    }
    __syncthreads();
#pragma unroll
    for (int p = 0; p < 16; p++) {
      float av[4], bv[4];
#pragma unroll
      for (int a = 0; a < 4; a++) av[a] = Ta[p][r0 + a];
#pragma unroll
      for (int b = 0; b < 4; b++) bv[b] = Tb[p][c0 + b];
#pragma unroll
      for (int a = 0; a < 4; a++)
#pragma unroll
        for (int b = 0; b < 4; b++) acc[a][b] += av[a] * bv[b];
    }
  }
  float kap = kapnu[0];
#pragma unroll
  for (int a = 0; a < 4; a++)
#pragma unroll
    for (int b = 0; b < 4; b++) {
      int gi = ti * 64 + r0 + a, gj = tj * 64 + c0 + b;
      base[(size_t)gi * DD + gj] = acc[a][b] + kap * m[gi] * m[gj];
    }
}

__global__ __launch_bounds__(256) void k_syrk_mfma(const short* XTh, const short* XTl,
                                                   const float* base, const float* mu,
                                                   const float* beta, const float* invs,
                                                   const int* counts, const int* offsets,
                                                   float* sigma) {
  int bb = blockIdx.x;
  int cls = bb / 36, tr = bb % 36;
  int ti, tj; tri_decode(tr, ti, tj);
  int cnt = counts[cls], off = offsets[cls];
  float* Sg = sigma + ((size_t)cls << 20);
  const float* muc = mu + (size_t)cls * DD;
  __shared__ short Ah[128 * 40], Al[128 * 40], Bh[128 * 40], Bl[128 * 40];
  int t = threadIdx.x;
  int wave = t >> 6, lane = t & 63;
  int wr = wave >> 1, wc = wave & 1;
  int quad = lane >> 4, l15 = lane & 15;
  int i0 = ti * 128, j0 = tj * 128;
  bool same = (ti == tj);
  floatx4 acc[4][4];
#pragma unroll
  for (int a = 0; a < 4; a++)
#pragma unroll
    for (int b = 0; b < 4; b++) acc[a][b] = (floatx4){0.f, 0.f, 0.f, 0.f};
  for (int nn = 0; nn < cnt; nn += 32) {
    __syncthreads();
#pragma unroll
    for (int r = 0; r < 2; r++) {
      int lin = r * 256 + t;
      int row = lin >> 2, kg = (lin & 3) << 3;
      size_t sA = (size_t)(i0 + row) * NP + off + nn + kg;
      *(s16x8*)&Ah[row * 40 + kg] = *(const s16x8*)&XTh[sA];
      *(s16x8*)&Al[row * 40 + kg] = *(const s16x8*)&XTl[sA];
      if (!same) {
        size_t sB = (size_t)(j0 + row) * NP + off + nn + kg;
        *(s16x8*)&Bh[row * 40 + kg] = *(const s16x8*)&XTh[sB];
        *(s16x8*)&Bl[row * 40 + kg] = *(const s16x8*)&XTl[sB];
      }
    }
    __syncthreads();
    const short* PBh = same ? Ah : Bh;
    const short* PBl = same ? Al : Bl;
    s16x8 ah[4], al[4], bh[4], bl[4];
#pragma unroll
    for (int f = 0; f < 4; f++) {
      ah[f] = *(const s16x8*)&Ah[(wr * 64 + f * 16 + l15) * 40 + quad * 8];
      al[f] = *(const s16x8*)&Al[(wr * 64 + f * 16 + l15) * 40 + quad * 8];
      bh[f] = *(const s16x8*)&PBh[(wc * 64 + f * 16 + l15) * 40 + quad * 8];
      bl[f] = *(const s16x8*)&PBl[(wc * 64 + f * 16 + l15) * 40 + quad * 8];
    }
#pragma unroll
    for (int fi = 0; fi < 4; fi++)
#pragma unroll
      for (int fj = 0; fj < 4; fj++) {
        acc[fi][fj] = __builtin_amdgcn_mfma_f32_16x16x32_bf16(ah[fi], bh[fj], acc[fi][fj], 0, 0, 0);
        acc[fi][fj] = __builtin_amdgcn_mfma_f32_16x16x32_bf16(ah[fi], bl[fj], acc[fi][fj], 0, 0, 0);
        acc[fi][fj] = __builtin_amdgcn_mfma_f32_16x16x32_bf16(al[fi], bh[fj], acc[fi][fj], 0, 0, 0);
      }
  }
  float bet = beta[cls], isc = invs[cls];
#pragma unroll
  for (int fi = 0; fi < 4; fi++)
#pragma unroll
    for (int fj = 0; fj < 4; fj++)
#pragma unroll
      for (int reg = 0; reg < 4; reg++) {
        int gi = i0 + wr * 64 + fi * 16 + quad * 4 + reg;
        int gj = j0 + wc * 64 + fj * 16 + l15;
        float v = acc[fi][fj][reg] + base[(size_t)gi * DD + gj] - bet * muc[gi] * muc[gj];
        Sg[(size_t)gi * DD + gj] = v * isc;
      }
}

// ---------------- factorization ----------------
// R1-proven (best config: 1480us, R8): register-cached LDL^T elimination
// (63 rounds, 1 barrier/step) + level-doubling triangular inversion.
// CLOSED SUBSYSTEM: R2 (width-8 blocked), R4 (width-4 blocked), R7
// (wave-local shfl sweep) ALL regressed. Do not re-attempt.
__device__ void chol_inv_reg(float areg[4][4], float* Dinv, int cls, int k, int t,
                             float* Asc, float* Wsc, float* Tsc) {
  __shared__ float colbuf[2][64];
  __shared__ float sdiag[64];
  int tx = t & 15, ty = t >> 4;
  int r0 = ty * 4, c0 = tx * 4;
  for (int j = 0; j < 63; j++) {
    float* cb = colbuf[j & 1];
    if (tx == (j >> 2)) {
      int jj = j & 3;
      cb[r0 + 0] = areg[0][jj];
      cb[r0 + 1] = areg[1][jj];
      cb[r0 + 2] = areg[2][jj];
      cb[r0 + 3] = areg[3][jj];
    }
    __syncthreads();
    float rd = 1.0f / cb[j];
    float rv[4], cv[4];
#pragma unroll
    for (int i = 0; i < 4; i++) rv[i] = cb[r0 + i];
#pragma unroll
    for (int b = 0; b < 4; b++) cv[b] = cb[c0 + b];
#pragma unroll
    for (int i = 0; i < 4; i++)
#pragma unroll
      for (int b = 0; b < 4; b++)
        if (c0 + b > j && c0 + b <= r0 + i)
          areg[i][b] -= rv[i] * cv[b] * rd;
  }
  __syncthreads();
  if (tx == ty) {
#pragma unroll
    for (int i = 0; i < 4; i++) sdiag[r0 + i] = 1.0f / sqrtf(areg[i][i]);
  }
  __syncthreads();
  float sd[4];
#pragma unroll
  for (int b = 0; b < 4; b++) sd[b] = sdiag[c0 + b];
  // L (scaled, lower; 0 above) -> Asc; zero Wsc
#pragma unroll
  for (int i = 0; i < 4; i++)
#pragma unroll
    for (int b = 0; b < 4; b++) {
      float lv = (r0 + i >= c0 + b) ? areg[i][b] * sd[b] : 0.f;
      Asc[(r0 + i) * TS + c0 + b] = lv;
      Wsc[(r0 + i) * TS + c0 + b] = 0.f;
    }
  __syncthreads();
  // --- level-doubling inversion of L (in Asc) into Wsc ---
  // base: invert the 16 diagonal 4x4 blocks (forward substitution, local)
  if (t < 16) {
    int c = t * 4;
    float l[4][4], w[4][4];
#pragma unroll
    for (int i = 0; i < 4; i++)
#pragma unroll
      for (int j = 0; j <= i; j++) l[i][j] = Asc[(c + i) * TS + c + j];
#pragma unroll
    for (int j = 0; j < 4; j++) {
      w[j][j] = 1.0f / l[j][j];
#pragma unroll
      for (int i = j + 1; i < 4; i++) {
        float s = 0.f;
#pragma unroll
        for (int kk = j; kk < i; kk++) s += l[i][kk] * w[kk][j];
        w[i][j] = -s / l[i][i];
      }
    }
#pragma unroll
    for (int i = 0; i < 4; i++)
#pragma unroll
      for (int j = 0; j <= i; j++) Wsc[(c + i) * TS + c + j] = w[i][j];
  }
  __syncthreads();
  // combine levels: for each pair [c,c+h) x [c+h,c+2h):
  //   T = L_BA * W_AA   (W_AA lower-tri)
  //   W_BA = -W_BB * T  (W_BB lower-tri)
#pragma unroll 4
  for (int h = 4; h <= 32; h <<= 1) {
    int hh = h * h;
    int total = 32 * h;  // (64/(2h)) pairs * h*h elements
    for (int idx = t; idx < total; idx += 256) {
      int pr = idx / hh;
      int rem = idx - pr * hh;
      int i = rem / h, j = rem - (rem / h) * h;
      int c = pr * 2 * h;
      float s = 0.f;
      for (int kk = j; kk < h; kk++)
        s += Asc[(c + h + i) * TS + c + kk] * Wsc[(c + kk) * TS + c + j];
      Tsc[idx] = s;
    }
    __syncthreads();
    for (int idx = t; idx < total; idx += 256) {
      int pr = idx / hh;
      int rem = idx - pr * hh;
      int i = rem / h, j = rem - (rem / h) * h;
      int c = pr * 2 * h;
      int tb = pr * hh;
      float s = 0.f;
      for (int kk = 0; kk <= i; kk++)
        s += Wsc[(c + h + i) * TS + c + h + kk] * Tsc[tb + kk * h + j];
      Wsc[(c + h + i) * TS + c + j] = -s;
    }
    __syncthreads();
  }
  float* Dv = Dinv + ((size_t)(cls * 16 + k)) * 4096;
  for (int idx4 = t; idx4 < 1024; idx4 += 256) {
    int r = idx4 >> 4, c4 = (idx4 & 15) << 2;
    float4 v = make_float4(Wsc[r * TS + c4], Wsc[r * TS + c4 + 1],
                           Wsc[r * TS + c4 + 2], Wsc[r * TS + c4 + 3]);
    *(float4*)&Dv[r * 64 + c4] = v;
  }
}

__global__ void k_diag0(float* sigma, float* Dinv) {
  __shared__ float A[64 * TS], W[64 * TS];
  __shared__ float Tq[1024];
  int cls = blockIdx.x, t = threadIdx.x;
  int tx = t & 15, ty = t >> 4;
  int r0 = ty * 4, c0 = tx * 4;
  float* Sg = sigma + ((size_t)cls << 20);
  float areg[4][4];
#pragma unroll
  for (int i = 0; i < 4; i++) {
    float4 s = *(const float4*)&Sg[(size_t)(r0 + i) * DD + c0];
    areg[i][0] = s.x; areg[i][1] = s.y; areg[i][2] = s.z; areg[i][3] = s.w;
  }
  chol_inv_reg(areg, Dinv, cls, 0, t, A, W, Tq);
}

// R3: split early steps (k<=7, trailing-work-dominated) into
// panel launch + update launch. Panels P_i = A(i,k)*W_k^T computed ONCE
// (16*nb blocks) and persisted to the upper mirror; update blocks READ the
// persisted panels and do a single 64^3 a3 matmul each.
__global__ void k_panel(float* sigma, const float* Dinv, int k) {
  __shared__ float B0[64 * TS], B1[64 * TS];
  int i_ = blockIdx.x, cls = blockIdx.y, t = threadIdx.x;
  int tx = t & 15, ty = t >> 4;
  int r0 = ty * 4, c0 = tx * 4;
  int it = k + 1 + i_;
  float* Sg = sigma + ((size_t)cls << 20);
  const float* Dv = Dinv + ((size_t)(cls * 16 + k)) * 4096;
  for (int i = 0; i < 4; i++) {
    int idx4 = i * 256 + t;
    int r = idx4 >> 4, c4 = (idx4 & 15) << 2;
    float4 v0 = *(const float4*)&Dv[r * 64 + c4];
    B0[r * TS + c4] = v0.x; B0[r * TS + c4 + 1] = v0.y;
    B0[r * TS + c4 + 2] = v0.z; B0[r * TS + c4 + 3] = v0.w;
    float4 v1 = *(const float4*)&Sg[(size_t)(it * 64 + r) * DD + k * 64 + c4];
    B1[r * TS + c4] = v1.x; B1[r * TS + c4 + 1] = v1.y;
    B1[r * TS + c4 + 2] = v1.z; B1[r * TS + c4 + 3] = v1.w;
  }
  __syncthreads();
  float a1[4][4] = {};
#pragma unroll 8
  for (int p = 0; p < 64; p++) {
    float bv[4], av1[4];
#pragma unroll
    for (int bq = 0; bq < 4; bq++) bv[bq] = B0[(c0 + bq) * TS + p];
#pragma unroll
    for (int a = 0; a < 4; a++) av1[a] = B1[(r0 + a) * TS + p];
#pragma unroll
    for (int a = 0; a < 4; a++)
#pragma unroll
      for (int bq = 0; bq < 4; bq++) a1[a][bq] += av1[a] * bv[bq];
  }
#pragma unroll
  for (int a = 0; a < 4; a++) {
    float4 v = make_float4(a1[a][0], a1[a][1], a1[a][2], a1[a][3]);
    *(float4*)&Sg[(size_t)(k * 64 + r0 + a) * DD + it * 64 + c0] = v;
  }
}

__global__ void k_update(float* sigma, float* Dinv, int k) {
  __shared__ float B0[64 * TS], B1[64 * TS], B2[64 * TS];
  int b = blockIdx.x, t = threadIdx.x;
  int tx = t & 15, ty = t >> 4;
  int r0 = ty * 4, c0 = tx * 4;
  int nb = 15 - k;
  int nt = nb * (nb + 1) / 2;
  int cls, a_, b_;
  bool special = (b < 16);
  if (special) { cls = b; a_ = 0; b_ = 0; }
  else {
    int jp = b - 16;
    cls = jp / (nt - 1);
    int s = jp % (nt - 1) + 1;
    tri_decode(s, a_, b_);
  }
  int it = k + 1 + a_, jt = k + 1 + b_;
  bool same = (it == jt);
  float* Sg = sigma + ((size_t)cls << 20);
  // load persisted panels P_it (B1) and P_jt (B2) from the upper mirror
  for (int i = 0; i < 4; i++) {
    int idx4 = i * 256 + t;
    int r = idx4 >> 4, c4 = (idx4 & 15) << 2;
    float4 v1 = *(const float4*)&Sg[(size_t)(k * 64 + r) * DD + it * 64 + c4];
    B1[r * TS + c4] = v1.x; B1[r * TS + c4 + 1] = v1.y;
    B1[r * TS + c4 + 2] = v1.z; B1[r * TS + c4 + 3] = v1.w;
    if (!same) {
      float4 v2 = *(const float4*)&Sg[(size_t)(k * 64 + r) * DD + jt * 64 + c4];
      B2[r * TS + c4] = v2.x; B2[r * TS + c4 + 1] = v2.y;
      B2[r * TS + c4 + 2] = v2.z; B2[r * TS + c4 + 3] = v2.w;
    }
  }
  __syncthreads();
  float* PB = same ? B1 : B2;
  float a3[4][4] = {};
#pragma unroll 8
  for (int p = 0; p < 64; p++) {
    float av[4], bv[4];
#pragma unroll
    for (int a = 0; a < 4; a++) av[a] = B1[(r0 + a) * TS + p];
#pragma unroll
    for (int bq = 0; bq < 4; bq++) bv[bq] = PB[(c0 + bq) * TS + p];
#pragma unroll
    for (int a = 0; a < 4; a++)
#pragma unroll
      for (int bq = 0; bq < 4; bq++) a3[a][bq] += av[a] * bv[bq];
  }
  if (!special) {
#pragma unroll
    for (int a = 0; a < 4; a++) {
      size_t addr = (size_t)(it * 64 + r0 + a) * DD + jt * 64 + c0;
      float4 s = *(const float4*)&Sg[addr];
      s.x -= a3[a][0]; s.y -= a3[a][1]; s.z -= a3[a][2]; s.w -= a3[a][3];
      *(float4*)&Sg[addr] = s;
    }
    return;
  }
  // special: updated (k+1,k+1) tile straight into registers, then factor
  float areg[4][4];
#pragma unroll
  for (int i = 0; i < 4; i++) {
    size_t addr = (size_t)(it * 64 + r0 + i) * DD + jt * 64 + c0;
    float4 s = *(const float4*)&Sg[addr];
    areg[i][0] = s.x - a3[i][0]; areg[i][1] = s.y - a3[i][1];
    areg[i][2] = s.z - a3[i][2]; areg[i][3] = s.w - a3[i][3];
  }
  __syncthreads();
  chol_inv_reg(areg, Dinv, cls, k + 1, t, B1, B2, B0);
}

// merged step k (used for k>7 where work is small / latency-dominated)
__global__ void k_cholstep(float* sigma, float* Dinv, int k) {
  __shared__ float B0[64 * TS], B1[64 * TS], B2[64 * TS];
  int b = blockIdx.x, t = threadIdx.x;
  int tx = t & 15, ty = t >> 4;
  int r0 = ty * 4, c0 = tx * 4;
  int nb = 15 - k;
  int nt = nb * (nb + 1) / 2;
  int cls, a_, b_;
  bool special = (b < 16);
  if (special) { cls = b; a_ = 0; b_ = 0; }
  else {
    int jp = b - 16;
    cls = jp / (nt - 1);
    int s = jp % (nt - 1) + 1;
    tri_decode(s, a_, b_);
  }
  int it = k + 1 + a_, jt = k + 1 + b_;
  bool same = (it == jt);
  float* Sg = sigma + ((size_t)cls << 20);
  const float* Dv = Dinv + ((size_t)(cls * 16 + k)) * 4096;
  for (int i = 0; i < 4; i++) {
    int idx4 = i * 256 + t;
    int r = idx4 >> 4, c4 = (idx4 & 15) << 2;
    float4 v0 = *(const float4*)&Dv[r * 64 + c4];
    B0[r * TS + c4] = v0.x; B0[r * TS + c4 + 1] = v0.y;
    B0[r * TS + c4 + 2] = v0.z; B0[r * TS + c4 + 3] = v0.w;
    float4 v1 = *(const float4*)&Sg[(size_t)(it * 64 + r) * DD + k * 64 + c4];
    B1[r * TS + c4] = v1.x; B1[r * TS + c4 + 1] = v1.y;
    B1[r * TS + c4 + 2] = v1.z; B1[r * TS + c4 + 3] = v1.w;
    if (!same) {
      float4 v2 = *(const float4*)&Sg[(size_t)(jt * 64 + r) * DD + k * 64 + c4];
      B2[r * TS + c4] = v2.x; B2[r * TS + c4 + 1] = v2.y;
      B2[r * TS + c4 + 2] = v2.z; B2[r * TS + c4 + 3] = v2.w;
    }
  }
  __syncthreads();
  // fused: a1 = B1*B0^T, a2 = B2*B0^T (shared bv)
  float a1[4][4] = {}, a2[4][4] = {};
#pragma unroll 8
  for (int p = 0; p < 64; p++) {
    float bv[4], av1[4];
#pragma unroll
    for (int bq = 0; bq < 4; bq++) bv[bq] = B0[(c0 + bq) * TS + p];
#pragma unroll
    for (int a = 0; a < 4; a++) av1[a] = B1[(r0 + a) * TS + p];
#pragma unroll
    for (int a = 0; a < 4; a++)
#pragma unroll
      for (int bq = 0; bq < 4; bq++) a1[a][bq] += av1[a] * bv[bq];
    if (!same) {
      float av2[4];
#pragma unroll
      for (int a = 0; a < 4; a++) av2[a] = B2[(r0 + a) * TS + p];
#pragma unroll
      for (int a = 0; a < 4; a++)
#pragma unroll
        for (int bq = 0; bq < 4; bq++) a2[a][bq] += av2[a] * bv[bq];
    }
  }
  __syncthreads();
#pragma unroll
  for (int a = 0; a < 4; a++)
#pragma unroll
    for (int bq = 0; bq < 4; bq++) {
      B1[(r0 + a) * TS + c0 + bq] = a1[a][bq];
      if (!same) B2[(r0 + a) * TS + c0 + bq] = a2[a][bq];
    }
  if (b_ == 0) {
#pragma unroll
    for (int a = 0; a < 4; a++) {
      float4 v = make_float4(a1[a][0], a1[a][1], a1[a][2], a1[a][3]);
      *(float4*)&Sg[(size_t)(k * 64 + r0 + a) * DD + it * 64 + c0] = v;
    }
  }
  __syncthreads();
  float* PB = same ? B1 : B2;
  float a3[4][4] = {};
#pragma unroll 8
  for (int p = 0; p < 64; p++) {
    float av[4], bv[4];
#pragma unroll
    for (int a = 0; a < 4; a++) av[a] = B1[(r0 + a) * TS + p];
#pragma unroll
    for (int bq = 0; bq < 4; bq++) bv[bq] = PB[(c0 + bq) * TS + p];
#pragma unroll
    for (int a = 0; a < 4; a++)
#pragma unroll
      for (int bq = 0; bq < 4; bq++) a3[a][bq] += av[a] * bv[bq];
  }
  if (!special) {
#pragma unroll
    for (int a = 0; a < 4; a++) {
      size_t addr = (size_t)(it * 64 + r0 + a) * DD + jt * 64 + c0;
      float4 s = *(const float4*)&Sg[addr];
      s.x -= a3[a][0]; s.y -= a3[a][1]; s.z -= a3[a][2]; s.w -= a3[a][3];
      *(float4*)&Sg[addr] = s;
    }
    return;
  }
  // special: updated (k+1,k+1) tile straight into registers, then factor
  float areg[4][4];
#pragma unroll
  for (int i = 0; i < 4; i++) {
    size_t addr = (size_t)(it * 64 + r0 + i) * DD + jt * 64 + c0;
    float4 s = *(const float4*)&Sg[addr];
    areg[i][0] = s.x - a3[i][0]; areg[i][1] = s.y - a3[i][1];
    areg[i][2] = s.z - a3[i][2]; areg[i][3] = s.w - a3[i][3];
  }
  __syncthreads();
  // B0 (held W_k) is dead here -> reuse as the level-doubling T scratch
  chol_inv_reg(areg, Dinv, cls, k + 1, t, B1, B2, B0);
}

// level-1 V combine (width 64->128), fully in-LDS: V21 = -W1 * R * W0
__global__ void k_vl1(float* sigma, const float* Dinv) {
  __shared__ float Rl[64 * TS], W0s[64 * TS], W1s[64 * TS], Ts[64 * TS];
  int b = blockIdx.x, t = threadIdx.x;
  int cls = b >> 3, i = b & 7;
  int t0 = 2 * i, t1 = 2 * i + 1;
  float* Sg = sigma + ((size_t)cls << 20);
  int tx = t & 15, ty = t >> 4;
  int r0 = ty * 4, c0 = tx * 4;
  const float* Dv0 = Dinv + ((size_t)(cls * 16 + t0)) * 4096;
  const float* Dv1 = Dinv + ((size_t)(cls * 16 + t1)) * 4096;
  for (int idx4 = t; idx4 < 1024; idx4 += 256) {
    int r = idx4 >> 4, c4 = (idx4 & 15) << 2;
    float4 vr = *(const float4*)&Sg[(size_t)(t0 * 64 + r) * DD + t1 * 64 + c4];
    Rl[r * TS + c4] = vr.x; Rl[r * TS + c4 + 1] = vr.y;
    Rl[r * TS + c4 + 2] = vr.z; Rl[r * TS + c4 + 3] = vr.w;
    float4 v0 = *(const float4*)&Dv0[r * 64 + c4];
    W0s[r * TS + c4] = v0.x; W0s[r * TS + c4 + 1] = v0.y;
    W0s[r * TS + c4 + 2] = v0.z; W0s[r * TS + c4 + 3] = v0.w;
    float4 v1 = *(const float4*)&Dv1[r * 64 + c4];
    W1s[r * TS + c4] = v1.x; W1s[r * TS + c4 + 1] = v1.y;
    W1s[r * TS + c4 + 2] = v1.z; W1s[r * TS + c4 + 3] = v1.w;
  }
  __syncthreads();
  float aT[4][4] = {};
#pragma unroll 8
  for (int p = 0; p < 64; p++) {
    float av[4], bv[4];
#pragma unroll
    for (int a = 0; a < 4; a++) av[a] = Rl[(r0 + a) * TS + p];
#pragma unroll
    for (int bq = 0; bq < 4; bq++) bv[bq] = W0s[p * TS + c0 + bq];
#pragma unroll
    for (int a = 0; a < 4; a++)
#pragma unroll
      for (int bq = 0; bq < 4; bq++) aT[a][bq] += av[a] * bv[bq];
  }
  __syncthreads();
#pragma unroll
  for (int a = 0; a < 4; a++)
#pragma unroll
    for (int bq = 0; bq < 4; bq++) Ts[(r0 + a) * TS + c0 + bq] = aT[a][bq];
  __syncthreads();
  float aV[4][4] = {};
#pragma unroll 8
  for (int p = 0; p < 64; p++) {
    float av[4], bv[4];
#pragma unroll
    for (int a = 0; a < 4; a++) av[a] = W1s[(r0 + a) * TS + p];
#pragma unroll
    for (int bq = 0; bq < 4; bq++) bv[bq] = Ts[p * TS + c0 + bq];
#pragma unroll
    for (int a = 0; a < 4; a++)
#pragma unroll
      for (int bq = 0; bq < 4; bq++) aV[a][bq] += av[a] * bv[bq];
  }
#pragma unroll
  for (int a = 0; a < 4; a++)
    *(float4*)&Sg[(size_t)(t0 * 64 + r0 + a) * DD + t1 * 64 + c0] =
        make_float4(-aV[a][0], -aV[a][1], -aV[a][2], -aV[a][3]);
}

// level-L launch A: T(a,b) = sum_m R21(a,m) * V11(m,b); T -> lower scratch
__global__ void k_vlA(float* sigma, const float* Dinv, int w) {
  __shared__ float Xs[64 * TS], Ys[64 * TS];
  int aa = blockIdx.x / w, bb = blockIdx.x % w;
  int base = blockIdx.y * 2 * w, cls = blockIdx.z;
  float* Sg = sigma + ((size_t)cls << 20);
  int t = threadIdx.x, tx = t & 15, ty = t >> 4;
  int r0 = ty * 4, c0 = tx * 4;
  float acc[4][4] = {};
  for (int m = bb; m < w; m++) {
    __syncthreads();
    for (int idx4 = t; idx4 < 1024; idx4 += 256) {
      int r = idx4 >> 4, c4 = (idx4 & 15) << 2;
      float4 v = *(const float4*)&Sg[(size_t)((base + m) * 64 + r) * DD + (base + w + aa) * 64 + c4];
      Xs[r * TS + c4] = v.x; Xs[r * TS + c4 + 1] = v.y;
      Xs[r * TS + c4 + 2] = v.z; Xs[r * TS + c4 + 3] = v.w;
    }
    if (m == bb) {
      const float* Dv = Dinv + ((size_t)(cls * 16 + base + bb)) * 4096;
      for (int idx4 = t; idx4 < 1024; idx4 += 256) {
        int r = idx4 >> 4, c4 = (idx4 & 15) << 2;
        float4 v = *(const float4*)&Dv[r * 64 + c4];
        Ys[r * TS + c4] = v.x; Ys[r * TS + c4 + 1] = v.y;
        Ys[r * TS + c4 + 2] = v.z; Ys[r * TS + c4 + 3] = v.w;
      }
    } else {
      for (int idx4 = t; idx4 < 1024; idx4 += 256) {
        int p = idx4 >> 4, c4 = (idx4 & 15) << 2;
        float4 v = *(const float4*)&Sg[(size_t)((base + bb) * 64 + p) * DD + (base + m) * 64 + c4];
        Ys[p * TS + c4] = v.x; Ys[p * TS + c4 + 1] = v.y;
        Ys[p * TS + c4 + 2] = v.z; Ys[p * TS + c4 + 3] = v.w;
      }
    }
    __syncthreads();
#pragma unroll 8
    for (int p = 0; p < 64; p++) {
      float av[4], bv[4];
#pragma unroll
      for (int a = 0; a < 4; a++) av[a] = Xs[(r0 + a) * TS + p];
#pragma unroll
      for (int bq = 0; bq < 4; bq++) bv[bq] = Ys[p * TS + c0 + bq];
#pragma unroll
      for (int a = 0; a < 4; a++)
#pragma unroll
        for (int bq = 0; bq < 4; bq++) acc[a][bq] += av[a] * bv[bq];
    }
  }
#pragma unroll
  for (int a = 0; a < 4; a++)
    *(float4*)&Sg[(size_t)((base + w + aa) * 64 + r0 + a) * DD + (base + bb) * 64 + c0] =
        make_float4(acc[a][0], acc[a][1], acc[a][2], acc[a][3]);
}

// level-L launch B: V21(a,b) = -sum_{m<=a} V22(a,m) * T(m,b); -> upper mirror
__global__ void k_vlB(float* sigma, const float* Dinv, int w) {
  __shared__ float Xs[64 * TS], Ys[64 * TS];
  int aa = blockIdx.x / w, bb = blockIdx.x % w;
  int base = blockIdx.y * 2 * w, cls = blockIdx.z;
  float* Sg = sigma + ((size_t)cls << 20);
  int t = threadIdx.x, tx = t & 15, ty = t >> 4;
  int r0 = ty * 4, c0 = tx * 4;
  float acc[4][4] = {};
  for (int m = 0; m <= aa; m++) {
    __syncthreads();
    if (m == aa) {
      const float* Dv = Dinv + ((size_t)(cls * 16 + base + w + aa)) * 4096;
      for (int idx4 = t; idx4 < 1024; idx4 += 256) {
        int r = idx4 >> 4, c4 = (idx4 & 15) << 2;
        float4 v = *(const float4*)&Dv[r * 64 + c4];
        Xs[r * TS + c4] = v.x; Xs[r * TS + c4 + 1] = v.y;
        Xs[r * TS + c4 + 2] = v.z; Xs[r * TS + c4 + 3] = v.w;
      }
    } else {
      for (int idx4 = t; idx4 < 1024; idx4 += 256) {
        int r = idx4 >> 4, c4 = (idx4 & 15) << 2;
        float4 v = *(const float4*)&Sg[(size_t)((base + w + m) * 64 + r) * DD + (base + w + aa) * 64 + c4];
        Xs[r * TS + c4] = v.x; Xs[r * TS + c4 + 1] = v.y;
        Xs[r * TS + c4 + 2] = v.z; Xs[r * TS + c4 + 3] = v.w;
      }
    }
    for (int idx4 = t; idx4 < 1024; idx4 += 256) {
      int p = idx4 >> 4, c4 = (idx4 & 15) << 2;
      float4 v = *(const float4*)&Sg[(size_t)((base + w + m) * 64 + p) * DD + (base + bb) * 64 + c4];
      Ys[p * TS + c4] = v.x; Ys[p * TS + c4 + 1] = v.y;
      Ys[p * TS + c4 + 2] = v.z; Ys[p * TS + c4 + 3] = v.w;
    }
    __syncthreads();
#pragma unroll 8
    for (int p = 0; p < 64; p++) {
      float av[4], bv[4];
#pragma unroll
      for (int a = 0; a < 4; a++) av[a] = Xs[(r0 + a) * TS + p];
#pragma unroll
      for (int bq = 0; bq < 4; bq++) bv[bq] = Ys[p * TS + c0 + bq];
#pragma unroll
      for (int a = 0; a < 4; a++)
#pragma unroll
        for (int bq = 0; bq < 4; bq++) acc[a][bq] += av[a] * bv[bq];
    }
  }
#pragma unroll
  for (int a = 0; a < 4; a++)
    *(float4*)&Sg[(size_t)((base + bb) * 64 + r0 + a) * DD + (base + w + aa) * 64 + c0] =
        make_float4(-acc[a][0], -acc[a][1], -acc[a][2], -acc[a][3]);
}

// 2176 blocks: packed-fp16 V-tile copy (half8 writes) + fused u-partial
__global__ void k_finalize(const float* sigma, const float* Dinv, const float* mu,
                           float* uarr, _Float16* UT) {
  __shared__ float U0[64 * TS];
  __shared__ float CS[4 * 64];
  int jp = blockIdx.x, t = threadIdx.x;
  int cls = jp / 136, tr = jp % 136;
  int nt_, kt_; tri_decode(tr, nt_, kt_);   // nt_ >= kt_
  const float* muc = mu + (size_t)cls * DD;
  _Float16* outp = UT + (size_t)cls * UT_CLS_STRIDE + (size_t)tr * 4096;
  const float* srcp;
  size_t row_stride;
  if (kt_ == nt_) {
    srcp = Dinv + ((size_t)(cls * 16 + nt_)) * 4096;
    row_stride = 64;
  } else {
    srcp = sigma + ((size_t)cls << 20) + (size_t)(kt_ * 64) * DD + nt_ * 64;
    row_stride = DD;
  }
  for (int i = 0; i < 2; i++) {
    int g8 = i * 256 + t;            // 512 groups of 8 halves
    int rr = g8 >> 3, c8 = (g8 & 7) << 3;
    float4 v0 = *(const float4*)&srcp[(size_t)rr * row_stride + c8];
    float4 v1 = *(const float4*)&srcp[(size_t)rr * row_stride + c8 + 4];
    half8 h;
    h[0] = (_Float16)v0.x; h[1] = (_Float16)v0.y; h[2] = (_Float16)v0.z; h[3] = (_Float16)v0.w;
    h[4] = (_Float16)v1.x; h[5] = (_Float16)v1.y; h[6] = (_Float16)v1.z; h[7] = (_Float16)v1.w;
    *(half8*)&outp[rr * 64 + c8] = h;
    U0[rr * TS + c8] = v0.x; U0[rr * TS + c8 + 1] = v0.y;
    U0[rr * TS + c8 + 2] = v0.z; U0[rr * TS + c8 + 3] = v0.w;
    U0[rr * TS + c8 + 4] = v1.x; U0[rr * TS + c8 + 5] = v1.y;
    U0[rr * TS + c8 + 6] = v1.z; U0[rr * TS + c8 + 7] = v1.w;
  }
  __syncthreads();
  int g = t >> 6, r = t & 63;
  float s = 0.f;
  for (int c = g * 16; c < g * 16 + 16; c++)
    s += U0[r * TS + c] * muc[kt_ * 64 + c];
  CS[g * 64 + r] = s;
  __syncthreads();
  if (g == 0)
    atomicAdd(&uarr[(size_t)cls * DD + nt_ * 64 + r],
              CS[r] + CS[64 + r] + CS[128 + r] + CS[192 + r]);
}

// ---------------- predict side ----------------
__global__ void k_xqdots(const float* Xq, const float* mu, float* xq2, float* xqmu,
                         _Float16* XqH) {
  __shared__ float xrow[DD];
  int m = blockIdx.x, t = threadIdx.x;
  for (int i = t; i < 256; i += 256)
    ((float4*)xrow)[i] = ((const float4*)(Xq + (size_t)m * DD))[i];
  __syncthreads();
  for (int i = t; i < 256; i += 256) {
    float4 v = ((const float4*)xrow)[i];
    half4 h = {(_Float16)v.x, (_Float16)v.y, (_Float16)v.z, (_Float16)v.w};
    *(half4*)&XqH[(size_t)m * DD + i * 4] = h;
  }
  int wave = t >> 6, lane = t & 63;
  for (int cc = 0; cc < 4; cc++) {
    int c = wave * 4 + cc;
    const float* muc = mu + (size_t)c * DD;
    float s = 0.f;
    for (int j = lane; j < DD; j += 64) s += xrow[j] * muc[j];
    for (int o = 32; o > 0; o >>= 1) s += __shfl_down(s, o, 64);
    if (lane == 0) xqmu[(size_t)m * 16 + c] = s;
  }
  if (wave == 0) {
    float s = 0.f;
    for (int j = lane; j < DD; j += 64) s += xrow[j] * xrow[j];
    for (int o = 32; o > 0; o >>= 1) s += __shfl_down(s, o, 64);
    if (lane == 0) xq2[m] = s;
  }
}

// R9: 256-row M tile via 8 waves (512 thr). Per-wave fragment pattern is
// byte-identical to the proven R3/R8 kernel (wr now spans 0..3); the B tile
// in LDS is consumed by 2x the waves -> B global traffic halves, barriers
// amortize over 2x MFMA, block count halves. Counters said latency-bound
// (MfmaUtil 21 / VALUBusy 22 / occ 29) with FETCH 74MB >> 26MB inputs =
// B-panel refetch; this targets exactly that. ct-reversed dispatch kept (R8).
__global__ __launch_bounds__(512) void k_gemmG_mfma(const _Float16* XqH, const _Float16* UT,
                                                    const float* u, float* dout) {
  int mt = blockIdx.x, ct = 7 - (int)blockIdx.y, cls = blockIdx.z;
  const _Float16* Uc = UT + (size_t)cls * UT_CLS_STRIDE;
  __shared__ _Float16 As[256 * 40];
  __shared__ _Float16 Bs[128 * 40];
  int t = threadIdx.x;
  int wave = t >> 6, lane = t & 63;
  int wr = wave >> 1, wc = wave & 1;      // wr in [0,4): 256 rows; wc in {0,1}
  int quad = lane >> 4, l15 = lane & 15;
  int m0 = mt * 256, n0 = ct * 128, NT0 = ct * 2;
  floatx4 acc[4][4];
#pragma unroll
  for (int a = 0; a < 4; a++)
#pragma unroll
    for (int b = 0; b < 4; b++) acc[a][b] = (floatx4){0.f, 0.f, 0.f, 0.f};
  int kmax = (ct + 1) * 128;
  for (int kk = 0; kk < kmax; kk += 32) {
    __syncthreads();
    // As: 256 rows x 32 halves = 1024 half8-groups, 2 iters of 512 threads
#pragma unroll
    for (int i = 0; i < 2; i++) {
      int lin = i * 512 + t;
      int r = lin >> 2, kg = (lin & 3) * 8;
      *(half8*)&As[r * 40 + kg] = *(const half8*)&XqH[(size_t)(m0 + r) * DD + kk + kg];
    }
    int kt = kk >> 6, k0 = kk & 63;
    // Bs: 128 rows x 32 halves = 512 groups, exactly 1 per thread
    {
      int nl = t >> 2, kg = (t & 3) * 8;
      int s = nl >> 6, np = nl & 63;
      int nt = NT0 + s;
      half8 v = {};
      if (kt <= nt)
        v = *(const half8*)&Uc[(size_t)(nt * (nt + 1) / 2 + kt) * 4096 + np * 64 + k0 + kg];
      *(half8*)&Bs[nl * 40 + kg] = v;
    }
    __syncthreads();
    half8 af[4], bf[4];
#pragma unroll
    for (int f = 0; f < 4; f++) {
      af[f] = *(const half8*)&As[(wr * 64 + f * 16 + l15) * 40 + quad * 8];
      bf[f] = *(const half8*)&Bs[(wc * 64 + f * 16 + l15) * 40 + quad * 8];
    }
#pragma unroll
    for (int fi = 0; fi < 4; fi++)
#pragma unroll
      for (int fj = 0; fj < 4; fj++)
        acc[fi][fj] = __builtin_amdgcn_mfma_f32_16x16x32_f16(af[fi], bf[fj], acc[fi][fj], 0, 0, 0);
  }
  float uv[4];
#pragma unroll
  for (int fj = 0; fj < 4; fj++)
    uv[fj] = u[(size_t)cls * DD + n0 + wc * 64 + fj * 16 + l15];
#pragma unroll
  for (int fi = 0; fi < 4; fi++) {
#pragma unroll
    for (int r = 0; r < 4; r++) {
      float p = 0.f;
#pragma unroll
      for (int fj = 0; fj < 4; fj++) {
        float e = acc[fi][fj][r] - uv[fj];
        p += e * e;
      }
      p += __shfl_xor(p, 1, 64);
      p += __shfl_xor(p, 2, 64);
      p += __shfl_xor(p, 4, 64);
      p += __shfl_xor(p, 8, 64);
      if (l15 == 0) {
        int m = m0 + wr * 64 + fi * 16 + quad * 4 + r;
        atomicAdd(&dout[(size_t)m * 16 + cls], p);
      }
    }
  }
}

__global__ void k_logits(const float* xq2, const float* xqmu, const float* mu2,
                         float* dout) {
  size_t idx = (size_t)blockIdx.x * 256 + threadIdx.x;
  int m = (int)(idx >> 4), c = (int)(idx & 15);
  float q1 = dout[idx];
  float q2 = xq2[m] - 2.0f * xqmu[idx] + mu2[c];
  dout[idx] = -(0.9f * q1 + 0.1f * q2);
}

extern "C" void kernel_launch(void* const* d_in, const int* in_sizes, int n_in,
                              void* d_out, int out_size, void* d_ws, size_t ws_size,
                              hipStream_t stream) {
  (void)in_sizes; (void)n_in; (void)out_size; (void)ws_size;
  const float* X  = (const float*)d_in[0];
  const int*   y  = (const int*)d_in[1];
  const float* Xq = (const float*)d_in[2];
  const float* m  = (const float*)d_in[3];
  const float* kappa = (const float*)d_in[4];
  const float* nu = (const float*)d_in[5];
  const float* td = (const float*)d_in[6];
  const float* tl = (const float*)d_in[7];
  float* out = (float*)d_out;
  float* ws = (float*)d_ws;

  short* XTh   = (short*)(ws + OFF_XTH);
  short* XTl   = (short*)(ws + OFF_XTL);
  _Float16* UT = (_Float16*)ws;              // overlays XT planes (dead after syrk)
  float* baseb = ws + OFF_BASE;
  float* sigma = ws + OFF_SIGMA;
  _Float16* XqH = (_Float16*)sigma;          // overlays sigma (dead after finalize)
  float* Dinv  = ws + OFF_DINV;
  float* sums  = ws + OFF_SUMS;
  float* mu    = ws + OFF_MU;
  float* uarr  = ws + OFF_U;
  float* mu2   = ws + OFF_MU2;
  float* xq2   = ws + OFF_XQ2;
  float* xqmu  = ws + OFF_XQMU;
  float* kapnu = ws + OFF_KAPNU;
  float* cf    = ws + OFF_CF;
  float* beta  = ws + OFF_BETA;
  float* invs  = ws + OFF_INVS;
  int* ints      = (int*)(ws + OFF_INTS);
  int* counts    = ints;
  int* offsets   = ints + 16;
  int* cls_of_pt = ints + 32;
  int* order     = ints + 32 + PT_TILES;

  k_scalars<<<1, 256, 0, stream>>>(y, kappa, nu, kapnu, cf, beta, invs,
                                   counts, offsets, cls_of_pt, order,
                                   sums, uarr, out);
  k_gatherT<<<dim3(PT_TILES, 16), 256, 0, stream>>>(X, order, cls_of_pt, XTh, XTl, sums);
  k_mumu2<<<16, 256, 0, stream>>>(sums, m, kapnu, cf, mu, mu2);
  k_base<<<136, 256, 0, stream>>>(td, tl, m, kapnu, baseb);
  k_syrk_mfma<<<16 * 36, 256, 0, stream>>>(XTh, XTl, baseb, mu, beta, invs,
                                           counts, offsets, sigma);
  k_diag0<<<16, 256, 0, stream>>>(sigma, Dinv);
  for (int k = 0; k < 15; k++) {
    int nb = 15 - k;
    int nt = nb * (nb + 1) / 2;
    if (k <= 7) {
      k_panel<<<dim3(nb, 16), 256, 0, stream>>>(sigma, Dinv, k);
      k_update<<<16 * nt, 256, 0, stream>>>(sigma, Dinv, k);
    } else {
      k_cholstep<<<16 * nt, 256, 0, stream>>>(sigma, Dinv, k);
    }
  }
  k_vl1<<<128, 256, 0, stream>>>(sigma, Dinv);
  for (int L = 2; L <= 4; L++) {
    int w = 1 << (L - 1);
    int ncomb = 8 >> (L - 1);
    k_vlA<<<dim3(w * w, ncomb, 16), 256, 0, stream>>>(sigma, Dinv, w);
    k_vlB<<<dim3(w * w, ncomb, 16), 256, 0, stream>>>(sigma, Dinv, w);
  }
  k_finalize<<<16 * 136, 256, 0, stream>>>(sigma, Dinv, mu, uarr, UT);
  k_xqdots<<<4096, 256, 0, stream>>>(Xq, mu, xq2, xqmu, XqH);
  k_gemmG_mfma<<<dim3(16, 8, 16), 512, 0, stream>>>(XqH, UT, uarr, out);
  k_logits<<<256, 256, 0, stream>>>(xq2, xqmu, mu2, out);
}

// Round 10
// 1381.765 us; speedup vs baseline: 1.9652x; 1.0640x over previous
//
#include <hip/hip_runtime.h>
#include <math.h>

#define DD 1024
#define NP 5120   // padded sample pitch (class offsets padded to 64)
#define PT_TILES 80
#define TS 65     // fp32 LDS tile stride (bank-step 4 for 4-row column reads => 2-way/free)

typedef _Float16 half8 __attribute__((ext_vector_type(8)));
typedef _Float16 half4 __attribute__((ext_vector_type(4)));
typedef float floatx4 __attribute__((ext_vector_type(4)));
typedef short s16x8 __attribute__((ext_vector_type(8)));

// ---------------- workspace layout (float offsets) ----------------
#define OFF_XTH   ((size_t)0)
#define OFF_XTL   ((size_t)2621440)
#define OFF_BASE  ((size_t)5242880)
#define OFF_SIGMA ((size_t)6291456)    // 16*1024*1024 fp32 (lower: Schur, upper: R panels then V)
#define OFF_DINV  ((size_t)23068672)
#define OFF_SUMS  ((size_t)24117248)
#define OFF_MU    ((size_t)24133632)
#define OFF_U     ((size_t)24150016)
#define OFF_MU2   ((size_t)24166400)
#define OFF_XQ2   ((size_t)24166416)
#define OFF_XQMU  ((size_t)24170512)
#define OFF_KAPNU ((size_t)24236048)
#define OFF_CF    ((size_t)24236056)
#define OFF_BETA  ((size_t)24236072)
#define OFF_INVS  ((size_t)24236088)
#define OFF_INTS  ((size_t)24236104)

#define UT_CLS_STRIDE ((size_t)557056) // 136 tiles * 4096 halves

__device__ __forceinline__ void tri_decode(int b, int& ti, int& tj) {
  int t = 0;
  while ((t + 1) * (t + 2) / 2 <= b) t++;
  ti = t;
  tj = b - t * (t + 1) / 2;
}

__device__ __forceinline__ short f2bf(float f) {
  union { float f; unsigned u; } v; v.f = f;
  unsigned r = v.u + 0x7FFF + ((v.u >> 16) & 1);
  return (short)(r >> 16);
}
__device__ __forceinline__ float bf2f(short b) {
  union { unsigned u; float f; } v; v.u = ((unsigned)(unsigned short)b) << 16; return v.f;
}

__device__ __forceinline__ float reduce256(float v, float* scratch) {
  for (int o = 32; o > 0; o >>= 1) v += __shfl_down(v, o, 64);
  int lane = threadIdx.x & 63, w = threadIdx.x >> 6;
  __syncthreads();
  if (lane == 0) scratch[w] = v;
  __syncthreads();
  return scratch[0] + scratch[1] + scratch[2] + scratch[3];
}

// ---------------- stats ----------------
__global__ void k_scalars(const int* y, const float* kappa, const float* nu,
                          float* kapnu, float* cf, float* beta, float* invs,
                          int* counts, int* offsets, int* cls_of_pt, int* order,
                          float* sums, float* uarr, float* dout) {
  __shared__ int h[16];
  __shared__ int cur[16];
  int t = threadIdx.x;
  if (t < 16) h[t] = 0;
  __syncthreads();
  for (int n = t; n < 4096; n += 256) atomicAdd(&h[y[n]], 1);
  __syncthreads();
  if (t == 0) {
    float kap = fabsf(kappa[0]) + 1e-6f;
    float nu_ = fmaxf(nu[0], 1024.0f - 1.0f + 1e-6f);
    kapnu[0] = kap; kapnu[1] = nu_;
    int off = 0, tile = 0;
    for (int c = 0; c < 16; c++) {
      counts[c] = h[c]; offsets[c] = off; cur[c] = off;
      cf[c] = (float)h[c];
      beta[c] = kap + (float)h[c];
      invs[c] = 1.0f / (nu_ + (float)h[c] + 1024.0f + 2.0f);
      int ntile = ((h[c] + 63) & ~63) >> 6;
      for (int q = 0; q < ntile && tile < PT_TILES; q++) cls_of_pt[tile++] = c;
      off += (h[c] + 63) & ~63;
    }
    while (tile < PT_TILES) cls_of_pt[tile++] = -1;
  }
  for (int i = t; i < NP; i += 256) order[i] = -1;
  for (int i = t; i < 16 * 1024; i += 256) { sums[i] = 0.f; uarr[i] = 0.f; }
  for (int i = t; i < 4096 * 16; i += 256) dout[i] = 0.f;
  __syncthreads();
  for (int n = t; n < 4096; n += 256) {
    int c = y[n];
    int p = atomicAdd(&cur[c], 1);
    order[p] = n;
  }
}

// R10: base init = kap*m_i*m_j (full square; upper subtiles were always
// unread-or-overwritten scratch). Lets split-K k_base accumulate via atomics.
__global__ void k_binit(const float* m, const float* kapnu, float* base) {
  int gi = blockIdx.x, t = threadIdx.x;
  float kap = kapnu[0];
  float mi = m[gi];
  float4 mv = ((const float4*)m)[t];
  float4 v = make_float4(kap * mi * mv.x, kap * mi * mv.y,
                         kap * mi * mv.z, kap * mi * mv.w);
  ((float4*)(base + (size_t)gi * DD))[t] = v;
}

__global__ void k_gatherT(const float* X, const int* order, const int* cls_of_pt,
                          short* XTh, short* XTl, float* sums) {
  int pt = blockIdx.x, dt = blockIdx.y, t = threadIdx.x;
  __shared__ float T[64 * TS];
  __shared__ float CS[4 * 64];
  __shared__ int src[64];
  if (t < 64) src[t] = order[pt * 64 + t];
  __syncthreads();
  for (int i = 0; i < 4; i++) {
    int idx4 = i * 256 + t;
    int r = idx4 >> 4, c4 = (idx4 & 15) << 2;
    int s = src[r];
    float4 v = (s >= 0) ? *(const float4*)&X[(size_t)s * DD + dt * 64 + c4]
                        : make_float4(0.f, 0.f, 0.f, 0.f);
    T[r * TS + c4] = v.x; T[r * TS + c4 + 1] = v.y;
    T[r * TS + c4 + 2] = v.z; T[r * TS + c4 + 3] = v.w;
  }
  __syncthreads();
  for (int i = 0; i < 16; i++) {
    int lin = i * 256 + t;
    int d = lin >> 6, p = lin & 63;
    float v = T[p * TS + d];
    short hi = f2bf(v);
    float lov = v - bf2f(hi);
    size_t addr = (size_t)(dt * 64 + d) * NP + pt * 64 + p;
    XTh[addr] = hi;
    XTl[addr] = f2bf(lov);
  }
  int cls = cls_of_pt[pt];
  if (cls < 0) return;
  int g = t >> 6, d = t & 63;
  float s = 0.f;
  for (int p = g * 16; p < g * 16 + 16; p++) s += T[p * TS + d];
  CS[g * 64 + d] = s;
  __syncthreads();
  if (g == 0)
    atomicAdd(&sums[(size_t)cls * DD + dt * 64 + d],
              CS[d] + CS[64 + d] + CS[128 + d] + CS[192 + d]);
}

__global__ void k_mumu2(const float* sums, const float* m, const float* kapnu,
                        const float* cf, float* mu, float* mu2) {
  __shared__ float scratch[4];
  int c = blockIdx.x, t = threadIdx.x;
  float kap = kapnu[0];
  float denom = 1.0f / (kap + cf[c]);
  float s2 = 0.f;
  for (int j = t; j < DD; j += 256) {
    float v = (kap * m[j] + sums[(size_t)c * DD + j]) * denom;
    mu[(size_t)c * DD + j] = v;
    s2 += v * v;
  }
  float tot = reduce256(s2, scratch);
  if (t == 0) mu2[c] = tot;
}

__device__ __forceinline__ float lval(const float* td, const float* tl, int i, int j) {
  if (i == j) return fabsf(td[i]);
  if (i > j) return tl[(size_t)i * DD + j];
  return 0.f;
}

// R10: split-K (grid.y = 4 chunks, round-robin 64-wide k-tiles -> balanced).
// Old single-pass version was the top dispatch (~145us) at VALUBusy 3% /
// occ 2.5% — pure exposed barrier/LDS latency on the longest (tj=15) block
// (64 staging iters x 2 barriers, runtime = slowest block). Chunking cuts
// the critical block 4x; partials atomicAdd onto k_binit's kap*m*m init.
__global__ void k_base(const float* td, const float* tl, float* base) {
  int ti, tj; tri_decode(blockIdx.x, ti, tj);
  int ch = blockIdx.y;
  if (ch > tj) return;                  // block-uniform: no barrier hazards
  __shared__ float Ta[16][65], Tb[16][65];
  int t = threadIdx.x, tx = t & 15, ty = t >> 4;
  int r0 = ty * 4, c0 = tx * 4;
  float acc[4][4] = {};
  for (int kt = ch; kt <= tj; kt += 4) {
    for (int kko = 0; kko < 64; kko += 16) {
      int kk = kt * 64 + kko;
      __syncthreads();
      for (int idx = t; idx < 64 * 16; idx += 256) {
        int r = idx >> 4, p = idx & 15;
        Ta[p][r] = lval(td, tl, ti * 64 + r, kk + p);
        Tb[p][r] = lval(td, tl, tj * 64 + r, kk + p);
      }
      __syncthreads();
#pragma unroll
      for (int p = 0; p < 16; p++) {
        float av[4], bv[4];
#pragma unroll
        for (int a = 0; a < 4; a++) av[a] = Ta[p][r0 + a];
#pragma unroll
        for (int b = 0; b < 4; b++) bv[b] = Tb[p][c0 + b];
#pragma unroll
        for (int a = 0; a < 4; a++)
#pragma unroll
          for (int b = 0; b < 4; b++) acc[a][b] += av[a] * bv[b];
      }
    }
  }
#pragma unroll
  for (int a = 0; a < 4; a++)
#pragma unroll
    for (int b = 0; b < 4; b++) {
      int gi = ti * 64 + r0 + a, gj = tj * 64 + c0 + b;
      atomicAdd(&base[(size_t)gi * DD + gj], acc[a][b]);
    }
}

__global__ __launch_bounds__(256) void k_syrk_mfma(const short* XTh, const short* XTl,
                                                   const float* base, const float* mu,
                                                   const float* beta, const float* invs,
                                                   const int* counts, const int* offsets,
                                                   float* sigma) {
  int bb = blockIdx.x;
  int cls = bb / 36, tr = bb % 36;
  int ti, tj; tri_decode(tr, ti, tj);
  int cnt = counts[cls], off = offsets[cls];
  float* Sg = sigma + ((size_t)cls << 20);
  const float* muc = mu + (size_t)cls * DD;
  __shared__ short Ah[128 * 40], Al[128 * 40], Bh[128 * 40], Bl[128 * 40];
  int t = threadIdx.x;
  int wave = t >> 6, lane = t & 63;
  int wr = wave >> 1, wc = wave & 1;
  int quad = lane >> 4, l15 = lane & 15;
  int i0 = ti * 128, j0 = tj * 128;
  bool same = (ti == tj);
  floatx4 acc[4][4];
#pragma unroll
  for (int a = 0; a < 4; a++)
#pragma unroll
    for (int b = 0; b < 4; b++) acc[a][b] = (floatx4){0.f, 0.f, 0.f, 0.f};
  for (int nn = 0; nn < cnt; nn += 32) {
    __syncthreads();
#pragma unroll
    for (int r = 0; r < 2; r++) {
      int lin = r * 256 + t;
      int row = lin >> 2, kg = (lin & 3) << 3;
      size_t sA = (size_t)(i0 + row) * NP + off + nn + kg;
      *(s16x8*)&Ah[row * 40 + kg] = *(const s16x8*)&XTh[sA];
      *(s16x8*)&Al[row * 40 + kg] = *(const s16x8*)&XTl[sA];
      if (!same) {
        size_t sB = (size_t)(j0 + row) * NP + off + nn + kg;
        *(s16x8*)&Bh[row * 40 + kg] = *(const s16x8*)&XTh[sB];
        *(s16x8*)&Bl[row * 40 + kg] = *(const s16x8*)&XTl[sB];
      }
    }
    __syncthreads();
    const short* PBh = same ? Ah : Bh;
    const short* PBl = same ? Al : Bl;
    s16x8 ah[4], al[4], bh[4], bl[4];
#pragma unroll
    for (int f = 0; f < 4; f++) {
      ah[f] = *(const s16x8*)&Ah[(wr * 64 + f * 16 + l15) * 40 + quad * 8];
      al[f] = *(const s16x8*)&Al[(wr * 64 + f * 16 + l15) * 40 + quad * 8];
      bh[f] = *(const s16x8*)&PBh[(wc * 64 + f * 16 + l15) * 40 + quad * 8];
      bl[f] = *(const s16x8*)&PBl[(wc * 64 + f * 16 + l15) * 40 + quad * 8];
    }
#pragma unroll
    for (int fi = 0; fi < 4; fi++)
#pragma unroll
      for (int fj = 0; fj < 4; fj++) {
        acc[fi][fj] = __builtin_amdgcn_mfma_f32_16x16x32_bf16(ah[fi], bh[fj], acc[fi][fj], 0, 0, 0);
        acc[fi][fj] = __builtin_amdgcn_mfma_f32_16x16x32_bf16(ah[fi], bl[fj], acc[fi][fj], 0, 0, 0);
        acc[fi][fj] = __builtin_amdgcn_mfma_f32_16x16x32_bf16(al[fi], bh[fj], acc[fi][fj], 0, 0, 0);
      }
  }
  float bet = beta[cls], isc = invs[cls];
#pragma unroll
  for (int fi = 0; fi < 4; fi++)
#pragma unroll
    for (int fj = 0; fj < 4; fj++)
#pragma unroll
      for (int reg = 0; reg < 4; reg++) {
        int gi = i0 + wr * 64 + fi * 16 + quad * 4 + reg;
        int gj = j0 + wc * 64 + fj * 16 + l15;
        float v = acc[fi][fj][reg] + base[(size_t)gi * DD + gj] - bet * muc[gi] * muc[gj];
        Sg[(size_t)gi * DD + gj] = v * isc;
      }
}

// ---------------- factorization ----------------
// R1-proven (best config: 1470us, R9): register-cached LDL^T elimination
// (63 rounds, 1 barrier/step) + level-doubling triangular inversion.
// CLOSED SUBSYSTEM: R2 (width-8 blocked), R4 (width-4 blocked), R7
// (wave-local shfl sweep) ALL regressed. Do not re-attempt.
__device__ void chol_inv_reg(float areg[4][4], float* Dinv, int cls, int k, int t,
                             float* Asc, float* Wsc, float* Tsc) {
  __shared__ float colbuf[2][64];
  __shared__ float sdiag[64];
  int tx = t & 15, ty = t >> 4;
  int r0 = ty * 4, c0 = tx * 4;
  for (int j = 0; j < 63; j++) {
    float* cb = colbuf[j & 1];
    if (tx == (j >> 2)) {
      int jj = j & 3;
      cb[r0 + 0] = areg[0][jj];
      cb[r0 + 1] = areg[1][jj];
      cb[r0 + 2] = areg[2][jj];
      cb[r0 + 3] = areg[3][jj];
    }
    __syncthreads();
    float rd = 1.0f / cb[j];
    float rv[4], cv[4];
#pragma unroll
    for (int i = 0; i < 4; i++) rv[i] = cb[r0 + i];
#pragma unroll
    for (int b = 0; b < 4; b++) cv[b] = cb[c0 + b];
#pragma unroll
    for (int i = 0; i < 4; i++)
#pragma unroll
      for (int b = 0; b < 4; b++)
        if (c0 + b > j && c0 + b <= r0 + i)
          areg[i][b] -= rv[i] * cv[b] * rd;
  }
  __syncthreads();
  if (tx == ty) {
#pragma unroll
    for (int i = 0; i < 4; i++) sdiag[r0 + i] = 1.0f / sqrtf(areg[i][i]);
  }
  __syncthreads();
  float sd[4];
#pragma unroll
  for (int b = 0; b < 4; b++) sd[b] = sdiag[c0 + b];
  // L (scaled, lower; 0 above) -> Asc; zero Wsc
#pragma unroll
  for (int i = 0; i < 4; i++)
#pragma unroll
    for (int b = 0; b < 4; b++) {
      float lv = (r0 + i >= c0 + b) ? areg[i][b] * sd[b] : 0.f;
      Asc[(r0 + i) * TS + c0 + b] = lv;
      Wsc[(r0 + i) * TS + c0 + b] = 0.f;
    }
  __syncthreads();
  // --- level-doubling inversion of L (in Asc) into Wsc ---
  // base: invert the 16 diagonal 4x4 blocks (forward substitution, local)
  if (t < 16) {
    int c = t * 4;
    float l[4][4], w[4][4];
#pragma unroll
    for (int i = 0; i < 4; i++)
#pragma unroll
      for (int j = 0; j <= i; j++) l[i][j] = Asc[(c + i) * TS + c + j];
#pragma unroll
    for (int j = 0; j < 4; j++) {
      w[j][j] = 1.0f / l[j][j];
#pragma unroll
      for (int i = j + 1; i < 4; i++) {
        float s = 0.f;
#pragma unroll
        for (int kk = j; kk < i; kk++) s += l[i][kk] * w[kk][j];
        w[i][j] = -s / l[i][i];
      }
    }
#pragma unroll
    for (int i = 0; i < 4; i++)
#pragma unroll
      for (int j = 0; j <= i; j++) Wsc[(c + i) * TS + c + j] = w[i][j];
  }
  __syncthreads();
  // combine levels: for each pair [c,c+h) x [c+h,c+2h):
  //   T = L_BA * W_AA   (W_AA lower-tri)
  //   W_BA = -W_BB * T  (W_BB lower-tri)
#pragma unroll 4
  for (int h = 4; h <= 32; h <<= 1) {
    int hh = h * h;
    int total = 32 * h;  // (64/(2h)) pairs * h*h elements
    for (int idx = t; idx < total; idx += 256) {
      int pr = idx / hh;
      int rem = idx - pr * hh;
      int i = rem / h, j = rem - (rem / h) * h;
      int c = pr * 2 * h;
      float s = 0.f;
      for (int kk = j; kk < h; kk++)
        s += Asc[(c + h + i) * TS + c + kk] * Wsc[(c + kk) * TS + c + j];
      Tsc[idx] = s;
    }
    __syncthreads();
    for (int idx = t; idx < total; idx += 256) {
      int pr = idx / hh;
      int rem = idx - pr * hh;
      int i = rem / h, j = rem - (rem / h) * h;
      int c = pr * 2 * h;
      int tb = pr * hh;
      float s = 0.f;
      for (int kk = 0; kk <= i; kk++)
        s += Wsc[(c + h + i) * TS + c + h + kk] * Tsc[tb + kk * h + j];
      Wsc[(c + h + i) * TS + c + j] = -s;
    }
    __syncthreads();
  }
  float* Dv = Dinv + ((size_t)(cls * 16 + k)) * 4096;
  for (int idx4 = t; idx4 < 1024; idx4 += 256) {
    int r = idx4 >> 4, c4 = (idx4 & 15) << 2;
    float4 v = make_float4(Wsc[r * TS + c4], Wsc[r * TS + c4 + 1],
                           Wsc[r * TS + c4 + 2], Wsc[r * TS + c4 + 3]);
    *(float4*)&Dv[r * 64 + c4] = v;
  }
}

__global__ void k_diag0(float* sigma, float* Dinv) {
  __shared__ float A[64 * TS], W[64 * TS];
  __shared__ float Tq[1024];
  int cls = blockIdx.x, t = threadIdx.x;
  int tx = t & 15, ty = t >> 4;
  int r0 = ty * 4, c0 = tx * 4;
  float* Sg = sigma + ((size_t)cls << 20);
  float areg[4][4];
#pragma unroll
  for (int i = 0; i < 4; i++) {
    float4 s = *(const float4*)&Sg[(size_t)(r0 + i) * DD + c0];
    areg[i][0] = s.x; areg[i][1] = s.y; areg[i][2] = s.z; areg[i][3] = s.w;
  }
  chol_inv_reg(areg, Dinv, cls, 0, t, A, W, Tq);
}

// R3: split early steps (k<=7, trailing-work-dominated) into
// panel launch + update launch. Panels P_i = A(i,k)*W_k^T computed ONCE
// (16*nb blocks) and persisted to the upper mirror; update blocks READ the
// persisted panels and do a single 64^3 a3 matmul each.
__global__ void k_panel(float* sigma, const float* Dinv, int k) {
  __shared__ float B0[64 * TS], B1[64 * TS];
  int i_ = blockIdx.x, cls = blockIdx.y, t = threadIdx.x;
  int tx = t & 15, ty = t >> 4;
  int r0 = ty * 4, c0 = tx * 4;
  int it = k + 1 + i_;
  float* Sg = sigma + ((size_t)cls << 20);
  const float* Dv = Dinv + ((size_t)(cls * 16 + k)) * 4096;
  for (int i = 0; i < 4; i++) {
    int idx4 = i * 256 + t;
    int r = idx4 >> 4, c4 = (idx4 & 15) << 2;
    float4 v0 = *(const float4*)&Dv[r * 64 + c4];
    B0[r * TS + c4] = v0.x; B0[r * TS + c4 + 1] = v0.y;
    B0[r * TS + c4 + 2] = v0.z; B0[r * TS + c4 + 3] = v0.w;
    float4 v1 = *(const float4*)&Sg[(size_t)(it * 64 + r) * DD + k * 64 + c4];
    B1[r * TS + c4] = v1.x; B1[r * TS + c4 + 1] = v1.y;
    B1[r * TS + c4 + 2] = v1.z; B1[r * TS + c4 + 3] = v1.w;
  }
  __syncthreads();
  float a1[4][4] = {};
#pragma unroll 8
  for (int p = 0; p < 64; p++) {
    float bv[4], av1[4];
#pragma unroll
    for (int bq = 0; bq < 4; bq++) bv[bq] = B0[(c0 + bq) * TS + p];
#pragma unroll
    for (int a = 0; a < 4; a++) av1[a] = B1[(r0 + a) * TS + p];
#pragma unroll
    for (int a = 0; a < 4; a++)
#pragma unroll
      for (int bq = 0; bq < 4; bq++) a1[a][bq] += av1[a] * bv[bq];
  }
#pragma unroll
  for (int a = 0; a < 4; a++) {
    float4 v = make_float4(a1[a][0], a1[a][1], a1[a][2], a1[a][3]);
    *(float4*)&Sg[(size_t)(k * 64 + r0 + a) * DD + it * 64 + c0] = v;
  }
}

__global__ void k_update(float* sigma, float* Dinv, int k) {
  __shared__ float B0[64 * TS], B1[64 * TS], B2[64 * TS];
  int b = blockIdx.x, t = threadIdx.x;
  int tx = t & 15, ty = t >> 4;
  int r0 = ty * 4, c0 = tx * 4;
  int nb = 15 - k;
  int nt = nb * (nb + 1) / 2;
  int cls, a_, b_;
  bool special = (b < 16);
  if (special) { cls = b; a_ = 0; b_ = 0; }
  else {
    int jp = b - 16;
    cls = jp / (nt - 1);
    int s = jp % (nt - 1) + 1;
    tri_decode(s, a_, b_);
  }
  int it = k + 1 + a_, jt = k + 1 + b_;
  bool same = (it == jt);
  float* Sg = sigma + ((size_t)cls << 20);
  // load persisted panels P_it (B1) and P_jt (B2) from the upper mirror
  for (int i = 0; i < 4; i++) {
    int idx4 = i * 256 + t;
    int r = idx4 >> 4, c4 = (idx4 & 15) << 2;
    float4 v1 = *(const float4*)&Sg[(size_t)(k * 64 + r) * DD + it * 64 + c4];
    B1[r * TS + c4] = v1.x; B1[r * TS + c4 + 1] = v1.y;
    B1[r * TS + c4 + 2] = v1.z; B1[r * TS + c4 + 3] = v1.w;
    if (!same) {
      float4 v2 = *(const float4*)&Sg[(size_t)(k * 64 + r) * DD + jt * 64 + c4];
      B2[r * TS + c4] = v2.x; B2[r * TS + c4 + 1] = v2.y;
      B2[r * TS + c4 + 2] = v2.z; B2[r * TS + c4 + 3] = v2.w;
    }
  }
  __syncthreads();
  float* PB = same ? B1 : B2;
  float a3[4][4] = {};
#pragma unroll 8
  for (int p = 0; p < 64; p++) {
    float av[4], bv[4];
#pragma unroll
    for (int a = 0; a < 4; a++) av[a] = B1[(r0 + a) * TS + p];
#pragma unroll
    for (int bq = 0; bq < 4; bq++) bv[bq] = PB[(c0 + bq) * TS + p];
#pragma unroll
    for (int a = 0; a < 4; a++)
#pragma unroll
      for (int bq = 0; bq < 4; bq++) a3[a][bq] += av[a] * bv[bq];
  }
  if (!special) {
#pragma unroll
    for (int a = 0; a < 4; a++) {
      size_t addr = (size_t)(it * 64 + r0 + a) * DD + jt * 64 + c0;
      float4 s = *(const float4*)&Sg[addr];
      s.x -= a3[a][0]; s.y -= a3[a][1]; s.z -= a3[a][2]; s.w -= a3[a][3];
      *(float4*)&Sg[addr] = s;
    }
    return;
  }
  // special: updated (k+1,k+1) tile straight into registers, then factor
  float areg[4][4];
#pragma unroll
  for (int i = 0; i < 4; i++) {
    size_t addr = (size_t)(it * 64 + r0 + i) * DD + jt * 64 + c0;
    float4 s = *(const float4*)&Sg[addr];
    areg[i][0] = s.x - a3[i][0]; areg[i][1] = s.y - a3[i][1];
    areg[i][2] = s.z - a3[i][2]; areg[i][3] = s.w - a3[i][3];
  }
  __syncthreads();
  chol_inv_reg(areg, Dinv, cls, k + 1, t, B1, B2, B0);
}

// merged step k (used for k>7 where work is small / latency-dominated)
__global__ void k_cholstep(float* sigma, float* Dinv, int k) {
  __shared__ float B0[64 * TS], B1[64 * TS], B2[64 * TS];
  int b = blockIdx.x, t = threadIdx.x;
  int tx = t & 15, ty = t >> 4;
  int r0 = ty * 4, c0 = tx * 4;
  int nb = 15 - k;
  int nt = nb * (nb + 1) / 2;
  int cls, a_, b_;
  bool special = (b < 16);
  if (special) { cls = b; a_ = 0; b_ = 0; }
  else {
    int jp = b - 16;
    cls = jp / (nt - 1);
    int s = jp % (nt - 1) + 1;
    tri_decode(s, a_, b_);
  }
  int it = k + 1 + a_, jt = k + 1 + b_;
  bool same = (it == jt);
  float* Sg = sigma + ((size_t)cls << 20);
  const float* Dv = Dinv + ((size_t)(cls * 16 + k)) * 4096;
  for (int i = 0; i < 4; i++) {
    int idx4 = i * 256 + t;
    int r = idx4 >> 4, c4 = (idx4 & 15) << 2;
    float4 v0 = *(const float4*)&Dv[r * 64 + c4];
    B0[r * TS + c4] = v0.x; B0[r * TS + c4 + 1] = v0.y;
    B0[r * TS + c4 + 2] = v0.z; B0[r * TS + c4 + 3] = v0.w;
    float4 v1 = *(const float4*)&Sg[(size_t)(it * 64 + r) * DD + k * 64 + c4];
    B1[r * TS + c4] = v1.x; B1[r * TS + c4 + 1] = v1.y;
    B1[r * TS + c4 + 2] = v1.z; B1[r * TS + c4 + 3] = v1.w;
    if (!same) {
      float4 v2 = *(const float4*)&Sg[(size_t)(jt * 64 + r) * DD + k * 64 + c4];
      B2[r * TS + c4] = v2.x; B2[r * TS + c4 + 1] = v2.y;
      B2[r * TS + c4 + 2] = v2.z; B2[r * TS + c4 + 3] = v2.w;
    }
  }
  __syncthreads();
  // fused: a1 = B1*B0^T, a2 = B2*B0^T (shared bv)
  float a1[4][4] = {}, a2[4][4] = {};
#pragma unroll 8
  for (int p = 0; p < 64; p++) {
    float bv[4], av1[4];
#pragma unroll
    for (int bq = 0; bq < 4; bq++) bv[bq] = B0[(c0 + bq) * TS + p];
#pragma unroll
    for (int a = 0; a < 4; a++) av1[a] = B1[(r0 + a) * TS + p];
#pragma unroll
    for (int a = 0; a < 4; a++)
#pragma unroll
      for (int bq = 0; bq < 4; bq++) a1[a][bq] += av1[a] * bv[bq];
    if (!same) {
      float av2[4];
#pragma unroll
      for (int a = 0; a < 4; a++) av2[a] = B2[(r0 + a) * TS + p];
#pragma unroll
      for (int a = 0; a < 4; a++)
#pragma unroll
        for (int bq = 0; bq < 4; bq++) a2[a][bq] += av2[a] * bv[bq];
    }
  }
  __syncthreads();
#pragma unroll
  for (int a = 0; a < 4; a++)
#pragma unroll
    for (int bq = 0; bq < 4; bq++) {
      B1[(r0 + a) * TS + c0 + bq] = a1[a][bq];
      if (!same) B2[(r0 + a) * TS + c0 + bq] = a2[a][bq];
    }
  if (b_ == 0) {
#pragma unroll
    for (int a = 0; a < 4; a++) {
      float4 v = make_float4(a1[a][0], a1[a][1], a1[a][2], a1[a][3]);
      *(float4*)&Sg[(size_t)(k * 64 + r0 + a) * DD + it * 64 + c0] = v;
    }
  }
  __syncthreads();
  float* PB = same ? B1 : B2;
  float a3[4][4] = {};
#pragma unroll 8
  for (int p = 0; p < 64; p++) {
    float av[4], bv[4];
#pragma unroll
    for (int a = 0; a < 4; a++) av[a] = B1[(r0 + a) * TS + p];
#pragma unroll
    for (int bq = 0; bq < 4; bq++) bv[bq] = PB[(c0 + bq) * TS + p];
#pragma unroll
    for (int a = 0; a < 4; a++)
#pragma unroll
      for (int bq = 0; bq < 4; bq++) a3[a][bq] += av[a] * bv[bq];
  }
  if (!special) {
#pragma unroll
    for (int a = 0; a < 4; a++) {
      size_t addr = (size_t)(it * 64 + r0 + a) * DD + jt * 64 + c0;
      float4 s = *(const float4*)&Sg[addr];
      s.x -= a3[a][0]; s.y -= a3[a][1]; s.z -= a3[a][2]; s.w -= a3[a][3];
      *(float4*)&Sg[addr] = s;
    }
    return;
  }
  // special: updated (k+1,k+1) tile straight into registers, then factor
  float areg[4][4];
#pragma unroll
  for (int i = 0; i < 4; i++) {
    size_t addr = (size_t)(it * 64 + r0 + i) * DD + jt * 64 + c0;
    float4 s = *(const float4*)&Sg[addr];
    areg[i][0] = s.x - a3[i][0]; areg[i][1] = s.y - a3[i][1];
    areg[i][2] = s.z - a3[i][2]; areg[i][3] = s.w - a3[i][3];
  }
  __syncthreads();
  // B0 (held W_k) is dead here -> reuse as the level-doubling T scratch
  chol_inv_reg(areg, Dinv, cls, k + 1, t, B1, B2, B0);
}

// level-1 V combine (width 64->128), fully in-LDS: V21 = -W1 * R * W0
__global__ void k_vl1(float* sigma, const float* Dinv) {
  __shared__ float Rl[64 * TS], W0s[64 * TS], W1s[64 * TS], Ts[64 * TS];
  int b = blockIdx.x, t = threadIdx.x;
  int cls = b >> 3, i = b & 7;
  int t0 = 2 * i, t1 = 2 * i + 1;
  float* Sg = sigma + ((size_t)cls << 20);
  int tx = t & 15, ty = t >> 4;
  int r0 = ty * 4, c0 = tx * 4;
  const float* Dv0 = Dinv + ((size_t)(cls * 16 + t0)) * 4096;
  const float* Dv1 = Dinv + ((size_t)(cls * 16 + t1)) * 4096;
  for (int idx4 = t; idx4 < 1024; idx4 += 256) {
    int r = idx4 >> 4, c4 = (idx4 & 15) << 2;
    float4 vr = *(const float4*)&Sg[(size_t)(t0 * 64 + r) * DD + t1 * 64 + c4];
    Rl[r * TS + c4] = vr.x; Rl[r * TS + c4 + 1] = vr.y;
    Rl[r * TS + c4 + 2] = vr.z; Rl[r * TS + c4 + 3] = vr.w;
    float4 v0 = *(const float4*)&Dv0[r * 64 + c4];
    W0s[r * TS + c4] = v0.x; W0s[r * TS + c4 + 1] = v0.y;
    W0s[r * TS + c4 + 2] = v0.z; W0s[r * TS + c4 + 3] = v0.w;
    float4 v1 = *(const float4*)&Dv1[r * 64 + c4];
    W1s[r * TS + c4] = v1.x; W1s[r * TS + c4 + 1] = v1.y;
    W1s[r * TS + c4 + 2] = v1.z; W1s[r * TS + c4 + 3] = v1.w;
  }
  __syncthreads();
  float aT[4][4] = {};
#pragma unroll 8
  for (int p = 0; p < 64; p++) {
    float av[4], bv[4];
#pragma unroll
    for (int a = 0; a < 4; a++) av[a] = Rl[(r0 + a) * TS + p];
#pragma unroll
    for (int bq = 0; bq < 4; bq++) bv[bq] = W0s[p * TS + c0 + bq];
#pragma unroll
    for (int a = 0; a < 4; a++)
#pragma unroll
      for (int bq = 0; bq < 4; bq++) aT[a][bq] += av[a] * bv[bq];
  }
  __syncthreads();
#pragma unroll
  for (int a = 0; a < 4; a++)
#pragma unroll
    for (int bq = 0; bq < 4; bq++) Ts[(r0 + a) * TS + c0 + bq] = aT[a][bq];
  __syncthreads();
  float aV[4][4] = {};
#pragma unroll 8
  for (int p = 0; p < 64; p++) {
    float av[4], bv[4];
#pragma unroll
    for (int a = 0; a < 4; a++) av[a] = W1s[(r0 + a) * TS + p];
#pragma unroll
    for (int bq = 0; bq < 4; bq++) bv[bq] = Ts[p * TS + c0 + bq];
#pragma unroll
    for (int a = 0; a < 4; a++)
#pragma unroll
      for (int bq = 0; bq < 4; bq++) aV[a][bq] += av[a] * bv[bq];
  }
#pragma unroll
  for (int a = 0; a < 4; a++)
    *(float4*)&Sg[(size_t)(t0 * 64 + r0 + a) * DD + t1 * 64 + c0] =
        make_float4(-aV[a][0], -aV[a][1], -aV[a][2], -aV[a][3]);
}

// level-L launch A: T(a,b) = sum_m R21(a,m) * V11(m,b); T -> lower scratch
__global__ void k_vlA(float* sigma, const float* Dinv, int w) {
  __shared__ float Xs[64 * TS], Ys[64 * TS];
  int aa = blockIdx.x / w, bb = blockIdx.x % w;
  int base = blockIdx.y * 2 * w, cls = blockIdx.z;
  float* Sg = sigma + ((size_t)cls << 20);
  int t = threadIdx.x, tx = t & 15, ty = t >> 4;
  int r0 = ty * 4, c0 = tx * 4;
  float acc[4][4] = {};
  for (int m = bb; m < w; m++) {
    __syncthreads();
    for (int idx4 = t; idx4 < 1024; idx4 += 256) {
      int r = idx4 >> 4, c4 = (idx4 & 15) << 2;
      float4 v = *(const float4*)&Sg[(size_t)((base + m) * 64 + r) * DD + (base + w + aa) * 64 + c4];
      Xs[r * TS + c4] = v.x; Xs[r * TS + c4 + 1] = v.y;
      Xs[r * TS + c4 + 2] = v.z; Xs[r * TS + c4 + 3] = v.w;
    }
    if (m == bb) {
      const float* Dv = Dinv + ((size_t)(cls * 16 + base + bb)) * 4096;
      for (int idx4 = t; idx4 < 1024; idx4 += 256) {
        int r = idx4 >> 4, c4 = (idx4 & 15) << 2;
        float4 v = *(const float4*)&Dv[r * 64 + c4];
        Ys[r * TS + c4] = v.x; Ys[r * TS + c4 + 1] = v.y;
        Ys[r * TS + c4 + 2] = v.z; Ys[r * TS + c4 + 3] = v.w;
      }
    } else {
      for (int idx4 = t; idx4 < 1024; idx4 += 256) {
        int p = idx4 >> 4, c4 = (idx4 & 15) << 2;
        float4 v = *(const float4*)&Sg[(size_t)((base + bb) * 64 + p) * DD + (base + m) * 64 + c4];
        Ys[p * TS + c4] = v.x; Ys[p * TS + c4 + 1] = v.y;
        Ys[p * TS + c4 + 2] = v.z; Ys[p * TS + c4 + 3] = v.w;
      }
    }
    __syncthreads();
#pragma unroll 8
    for (int p = 0; p < 64; p++) {
      float av[4], bv[4];
#pragma unroll
      for (int a = 0; a < 4; a++) av[a] = Xs[(r0 + a) * TS + p];
#pragma unroll
      for (int bq = 0; bq < 4; bq++) bv[bq] = Ys[p * TS + c0 + bq];
#pragma unroll
      for (int a = 0; a < 4; a++)
#pragma unroll
        for (int bq = 0; bq < 4; bq++) acc[a][bq] += av[a] * bv[bq];
    }
  }
#pragma unroll
  for (int a = 0; a < 4; a++)
    *(float4*)&Sg[(size_t)((base + w + aa) * 64 + r0 + a) * DD + (base + bb) * 64 + c0] =
        make_float4(acc[a][0], acc[a][1], acc[a][2], acc[a][3]);
}

// level-L launch B: V21(a,b) = -sum_{m<=a} V22(a,m) * T(m,b); -> upper mirror
__global__ void k_vlB(float* sigma, const float* Dinv, int w) {
  __shared__ float Xs[64 * TS], Ys[64 * TS];
  int aa = blockIdx.x / w, bb = blockIdx.x % w;
  int base = blockIdx.y * 2 * w, cls = blockIdx.z;
  float* Sg = sigma + ((size_t)cls << 20);
  int t = threadIdx.x, tx = t & 15, ty = t >> 4;
  int r0 = ty * 4, c0 = tx * 4;
  float acc[4][4] = {};
  for (int m = 0; m <= aa; m++) {
    __syncthreads();
    if (m == aa) {
      const float* Dv = Dinv + ((size_t)(cls * 16 + base + w + aa)) * 4096;
      for (int idx4 = t; idx4 < 1024; idx4 += 256) {
        int r = idx4 >> 4, c4 = (idx4 & 15) << 2;
        float4 v = *(const float4*)&Dv[r * 64 + c4];
        Xs[r * TS + c4] = v.x; Xs[r * TS + c4 + 1] = v.y;
        Xs[r * TS + c4 + 2] = v.z; Xs[r * TS + c4 + 3] = v.w;
      }
    } else {
      for (int idx4 = t; idx4 < 1024; idx4 += 256) {
        int r = idx4 >> 4, c4 = (idx4 & 15) << 2;
        float4 v = *(const float4*)&Sg[(size_t)((base + w + m) * 64 + r) * DD + (base + w + aa) * 64 + c4];
        Xs[r * TS + c4] = v.x; Xs[r * TS + c4 + 1] = v.y;
        Xs[r * TS + c4 + 2] = v.z; Xs[r * TS + c4 + 3] = v.w;
      }
    }
    for (int idx4 = t; idx4 < 1024; idx4 += 256) {
      int p = idx4 >> 4, c4 = (idx4 & 15) << 2;
      float4 v = *(const float4*)&Sg[(size_t)((base + w + m) * 64 + p) * DD + (base + bb) * 64 + c4];
      Ys[p * TS + c4] = v.x; Ys[p * TS + c4 + 1] = v.y;
      Ys[p * TS + c4 + 2] = v.z; Ys[p * TS + c4 + 3] = v.w;
    }
    __syncthreads();
#pragma unroll 8
    for (int p = 0; p < 64; p++) {
      float av[4], bv[4];
#pragma unroll
      for (int a = 0; a < 4; a++) av[a] = Xs[(r0 + a) * TS + p];
#pragma unroll
      for (int bq = 0; bq < 4; bq++) bv[bq] = Ys[p * TS + c0 + bq];
#pragma unroll
      for (int a = 0; a < 4; a++)
#pragma unroll
        for (int bq = 0; bq < 4; bq++) acc[a][bq] += av[a] * bv[bq];
    }
  }
#pragma unroll
  for (int a = 0; a < 4; a++)
    *(float4*)&Sg[(size_t)((base + bb) * 64 + r0 + a) * DD + (base + w + aa) * 64 + c0] =
        make_float4(-acc[a][0], -acc[a][1], -acc[a][2], -acc[a][3]);
}

// 2176 blocks: packed-fp16 V-tile copy (half8 writes) + fused u-partial
__global__ void k_finalize(const float* sigma, const float* Dinv, const float* mu,
                           float* uarr, _Float16* UT) {
  __shared__ float U0[64 * TS];
  __shared__ float CS[4 * 64];
  int jp = blockIdx.x, t = threadIdx.x;
  int cls = jp / 136, tr = jp % 136;
  int nt_, kt_; tri_decode(tr, nt_, kt_);   // nt_ >= kt_
  const float* muc = mu + (size_t)cls * DD;
  _Float16* outp = UT + (size_t)cls * UT_CLS_STRIDE + (size_t)tr * 4096;
  const float* srcp;
  size_t row_stride;
  if (kt_ == nt_) {
    srcp = Dinv + ((size_t)(cls * 16 + nt_)) * 4096;
    row_stride = 64;
  } else {
    srcp = sigma + ((size_t)cls << 20) + (size_t)(kt_ * 64) * DD + nt_ * 64;
    row_stride = DD;
  }
  for (int i = 0; i < 2; i++) {
    int g8 = i * 256 + t;            // 512 groups of 8 halves
    int rr = g8 >> 3, c8 = (g8 & 7) << 3;
    float4 v0 = *(const float4*)&srcp[(size_t)rr * row_stride + c8];
    float4 v1 = *(const float4*)&srcp[(size_t)rr * row_stride + c8 + 4];
    half8 h;
    h[0] = (_Float16)v0.x; h[1] = (_Float16)v0.y; h[2] = (_Float16)v0.z; h[3] = (_Float16)v0.w;
    h[4] = (_Float16)v1.x; h[5] = (_Float16)v1.y; h[6] = (_Float16)v1.z; h[7] = (_Float16)v1.w;
    *(half8*)&outp[rr * 64 + c8] = h;
    U0[rr * TS + c8] = v0.x; U0[rr * TS + c8 + 1] = v0.y;
    U0[rr * TS + c8 + 2] = v0.z; U0[rr * TS + c8 + 3] = v0.w;
    U0[rr * TS + c8 + 4] = v1.x; U0[rr * TS + c8 + 5] = v1.y;
    U0[rr * TS + c8 + 6] = v1.z; U0[rr * TS + c8 + 7] = v1.w;
  }
  __syncthreads();
  int g = t >> 6, r = t & 63;
  float s = 0.f;
  for (int c = g * 16; c < g * 16 + 16; c++)
    s += U0[r * TS + c] * muc[kt_ * 64 + c];
  CS[g * 64 + r] = s;
  __syncthreads();
  if (g == 0)
    atomicAdd(&uarr[(size_t)cls * DD + nt_ * 64 + r],
              CS[r] + CS[64 + r] + CS[128 + r] + CS[192 + r]);
}

// ---------------- predict side ----------------
__global__ void k_xqdots(const float* Xq, const float* mu, float* xq2, float* xqmu,
                         _Float16* XqH) {
  __shared__ float xrow[DD];
  int m = blockIdx.x, t = threadIdx.x;
  for (int i = t; i < 256; i += 256)
    ((float4*)xrow)[i] = ((const float4*)(Xq + (size_t)m * DD))[i];
  __syncthreads();
  for (int i = t; i < 256; i += 256) {
    float4 v = ((const float4*)xrow)[i];
    half4 h = {(_Float16)v.x, (_Float16)v.y, (_Float16)v.z, (_Float16)v.w};
    *(half4*)&XqH[(size_t)m * DD + i * 4] = h;
  }
  int wave = t >> 6, lane = t & 63;
  for (int cc = 0; cc < 4; cc++) {
    int c = wave * 4 + cc;
    const float* muc = mu + (size_t)c * DD;
    float s = 0.f;
    for (int j = lane; j < DD; j += 64) s += xrow[j] * muc[j];
    for (int o = 32; o > 0; o >>= 1) s += __shfl_down(s, o, 64);
    if (lane == 0) xqmu[(size_t)m * 16 + c] = s;
  }
  if (wave == 0) {
    float s = 0.f;
    for (int j = lane; j < DD; j += 64) s += xrow[j] * xrow[j];
    for (int o = 32; o > 0; o >>= 1) s += __shfl_down(s, o, 64);
    if (lane == 0) xq2[m] = s;
  }
}

// R9-proven (gemmG off the top-5): 256-row M tile via 8 waves (512 thr),
// ct-reversed dispatch. Per-wave fragment pattern identical to R3/R8.
__global__ __launch_bounds__(512) void k_gemmG_mfma(const _Float16* XqH, const _Float16* UT,
                                                    const float* u, float* dout) {
  int mt = blockIdx.x, ct = 7 - (int)blockIdx.y, cls = blockIdx.z;
  const _Float16* Uc = UT + (size_t)cls * UT_CLS_STRIDE;
  __shared__ _Float16 As[256 * 40];
  __shared__ _Float16 Bs[128 * 40];
  int t = threadIdx.x;
  int wave = t >> 6, lane = t & 63;
  int wr = wave >> 1, wc = wave & 1;      // wr in [0,4): 256 rows; wc in {0,1}
  int quad = lane >> 4, l15 = lane & 15;
  int m0 = mt * 256, n0 = ct * 128, NT0 = ct * 2;
  floatx4 acc[4][4];
#pragma unroll
  for (int a = 0; a < 4; a++)
#pragma unroll
    for (int b = 0; b < 4; b++) acc[a][b] = (floatx4){0.f, 0.f, 0.f, 0.f};
  int kmax = (ct + 1) * 128;
  for (int kk = 0; kk < kmax; kk += 32) {
    __syncthreads();
    // As: 256 rows x 32 halves = 1024 half8-groups, 2 iters of 512 threads
#pragma unroll
    for (int i = 0; i < 2; i++) {
      int lin = i * 512 + t;
      int r = lin >> 2, kg = (lin & 3) * 8;
      *(half8*)&As[r * 40 + kg] = *(const half8*)&XqH[(size_t)(m0 + r) * DD + kk + kg];
    }
    int kt = kk >> 6, k0 = kk & 63;
    // Bs: 128 rows x 32 halves = 512 groups, exactly 1 per thread
    {
      int nl = t >> 2, kg = (t & 3) * 8;
      int s = nl >> 6, np = nl & 63;
      int nt = NT0 + s;
      half8 v = {};
      if (kt <= nt)
        v = *(const half8*)&Uc[(size_t)(nt * (nt + 1) / 2 + kt) * 4096 + np * 64 + k0 + kg];
      *(half8*)&Bs[nl * 40 + kg] = v;
    }
    __syncthreads();
    half8 af[4], bf[4];
#pragma unroll
    for (int f = 0; f < 4; f++) {
      af[f] = *(const half8*)&As[(wr * 64 + f * 16 + l15) * 40 + quad * 8];
      bf[f] = *(const half8*)&Bs[(wc * 64 + f * 16 + l15) * 40 + quad * 8];
    }
#pragma unroll
    for (int fi = 0; fi < 4; fi++)
#pragma unroll
      for (int fj = 0; fj < 4; fj++)
        acc[fi][fj] = __builtin_amdgcn_mfma_f32_16x16x32_f16(af[fi], bf[fj], acc[fi][fj], 0, 0, 0);
  }
  float uv[4];
#pragma unroll
  for (int fj = 0; fj < 4; fj++)
    uv[fj] = u[(size_t)cls * DD + n0 + wc * 64 + fj * 16 + l15];
#pragma unroll
  for (int fi = 0; fi < 4; fi++) {
#pragma unroll
    for (int r = 0; r < 4; r++) {
      float p = 0.f;
#pragma unroll
      for (int fj = 0; fj < 4; fj++) {
        float e = acc[fi][fj][r] - uv[fj];
        p += e * e;
      }
      p += __shfl_xor(p, 1, 64);
      p += __shfl_xor(p, 2, 64);
      p += __shfl_xor(p, 4, 64);
      p += __shfl_xor(p, 8, 64);
      if (l15 == 0) {
        int m = m0 + wr * 64 + fi * 16 + quad * 4 + r;
        atomicAdd(&dout[(size_t)m * 16 + cls], p);
      }
    }
  }
}

__global__ void k_logits(const float* xq2, const float* xqmu, const float* mu2,
                         float* dout) {
  size_t idx = (size_t)blockIdx.x * 256 + threadIdx.x;
  int m = (int)(idx >> 4), c = (int)(idx & 15);
  float q1 = dout[idx];
  float q2 = xq2[m] - 2.0f * xqmu[idx] + mu2[c];
  dout[idx] = -(0.9f * q1 + 0.1f * q2);
}

extern "C" void kernel_launch(void* const* d_in, const int* in_sizes, int n_in,
                              void* d_out, int out_size, void* d_ws, size_t ws_size,
                              hipStream_t stream) {
  (void)in_sizes; (void)n_in; (void)out_size; (void)ws_size;
  const float* X  = (const float*)d_in[0];
  const int*   y  = (const int*)d_in[1];
  const float* Xq = (const float*)d_in[2];
  const float* m  = (const float*)d_in[3];
  const float* kappa = (const float*)d_in[4];
  const float* nu = (const float*)d_in[5];
  const float* td = (const float*)d_in[6];
  const float* tl = (const float*)d_in[7];
  float* out = (float*)d_out;
  float* ws = (float*)d_ws;

  short* XTh   = (short*)(ws + OFF_XTH);
  short* XTl   = (short*)(ws + OFF_XTL);
  _Float16* UT = (_Float16*)ws;              // overlays XT planes (dead after syrk)
  float* baseb = ws + OFF_BASE;
  float* sigma = ws + OFF_SIGMA;
  _Float16* XqH = (_Float16*)sigma;          // overlays sigma (dead after finalize)
  float* Dinv  = ws + OFF_DINV;
  float* sums  = ws + OFF_SUMS;
  float* mu    = ws + OFF_MU;
  float* uarr  = ws + OFF_U;
  float* mu2   = ws + OFF_MU2;
  float* xq2   = ws + OFF_XQ2;
  float* xqmu  = ws + OFF_XQMU;
  float* kapnu = ws + OFF_KAPNU;
  float* cf    = ws + OFF_CF;
  float* beta  = ws + OFF_BETA;
  float* invs  = ws + OFF_INVS;
  int* ints      = (int*)(ws + OFF_INTS);
  int* counts    = ints;
  int* offsets   = ints + 16;
  int* cls_of_pt = ints + 32;
  int* order     = ints + 32 + PT_TILES;

  k_scalars<<<1, 256, 0, stream>>>(y, kappa, nu, kapnu, cf, beta, invs,
                                   counts, offsets, cls_of_pt, order,
                                   sums, uarr, out);
  k_binit<<<1024, 256, 0, stream>>>(m, kapnu, baseb);
  k_gatherT<<<dim3(PT_TILES, 16), 256, 0, stream>>>(X, order, cls_of_pt, XTh, XTl, sums);
  k_mumu2<<<16, 256, 0, stream>>>(sums, m, kapnu, cf, mu, mu2);
  k_base<<<dim3(136, 4), 256, 0, stream>>>(td, tl, baseb);
  k_syrk_mfma<<<16 * 36, 256, 0, stream>>>(XTh, XTl, baseb, mu, beta, invs,
                                           counts, offsets, sigma);
  k_diag0<<<16, 256, 0, stream>>>(sigma, Dinv);
  for (int k = 0; k < 15; k++) {
    int nb = 15 - k;
    int nt = nb * (nb + 1) / 2;
    if (k <= 7) {
      k_panel<<<dim3(nb, 16), 256, 0, stream>>>(sigma, Dinv, k);
      k_update<<<16 * nt, 256, 0, stream>>>(sigma, Dinv, k);
    } else {
      k_cholstep<<<16 * nt, 256, 0, stream>>>(sigma, Dinv, k);
    }
  }
  k_vl1<<<128, 256, 0, stream>>>(sigma, Dinv);
  for (int L = 2; L <= 4; L++) {
    int w = 1 << (L - 1);
    int ncomb = 8 >> (L - 1);
    k_vlA<<<dim3(w * w, ncomb, 16), 256, 0, stream>>>(sigma, Dinv, w);
    k_vlB<<<dim3(w * w, ncomb, 16), 256, 0, stream>>>(sigma, Dinv, w);
  }
  k_finalize<<<16 * 136, 256, 0, stream>>>(sigma, Dinv, mu, uarr, UT);
  k_xqdots<<<4096, 256, 0, stream>>>(Xq, mu, xq2, xqmu, XqH);
  k_gemmG_mfma<<<dim3(16, 8, 16), 512, 0, stream>>>(XqH, UT, uarr, out);
  k_logits<<<256, 256, 0, stream>>>(xq2, xqmu, mu2, out);
}

// Round 11
// 1366.614 us; speedup vs baseline: 1.9870x; 1.0111x over previous
//
#include <hip/hip_runtime.h>
#include <math.h>

#define DD 1024
#define NP 5120   // padded sample pitch (class offsets padded to 64)
#define PT_TILES 80
#define TS 65     // fp32 LDS tile stride (bank-step 4 for 4-row column reads => 2-way/free)

typedef _Float16 half8 __attribute__((ext_vector_type(8)));
typedef _Float16 half4 __attribute__((ext_vector_type(4)));
typedef float floatx4 __attribute__((ext_vector_type(4)));
typedef short s16x8 __attribute__((ext_vector_type(8)));

// ---------------- workspace layout (float offsets) ----------------
#define OFF_XTH   ((size_t)0)
#define OFF_XTL   ((size_t)2621440)
#define OFF_BASE  ((size_t)5242880)
#define OFF_SIGMA ((size_t)6291456)    // 16*1024*1024 fp32 (lower: Schur, upper: R panels then V)
#define OFF_DINV  ((size_t)23068672)
#define OFF_SUMS  ((size_t)24117248)
#define OFF_MU    ((size_t)24133632)
#define OFF_U     ((size_t)24150016)
#define OFF_MU2   ((size_t)24166400)
#define OFF_XQ2   ((size_t)24166416)
#define OFF_XQMU  ((size_t)24170512)
#define OFF_KAPNU ((size_t)24236048)
#define OFF_CF    ((size_t)24236056)
#define OFF_BETA  ((size_t)24236072)
#define OFF_INVS  ((size_t)24236088)
#define OFF_INTS  ((size_t)24236104)

#define UT_CLS_STRIDE ((size_t)557056) // 136 tiles * 4096 halves

__device__ __forceinline__ void tri_decode(int b, int& ti, int& tj) {
  int t = 0;
  while ((t + 1) * (t + 2) / 2 <= b) t++;
  ti = t;
  tj = b - t * (t + 1) / 2;
}

__device__ __forceinline__ short f2bf(float f) {
  union { float f; unsigned u; } v; v.f = f;
  unsigned r = v.u + 0x7FFF + ((v.u >> 16) & 1);
  return (short)(r >> 16);
}
__device__ __forceinline__ float bf2f(short b) {
  union { unsigned u; float f; } v; v.u = ((unsigned)(unsigned short)b) << 16; return v.f;
}

__device__ __forceinline__ float reduce256(float v, float* scratch) {
  for (int o = 32; o > 0; o >>= 1) v += __shfl_down(v, o, 64);
  int lane = threadIdx.x & 63, w = threadIdx.x >> 6;
  __syncthreads();
  if (lane == 0) scratch[w] = v;
  __syncthreads();
  return scratch[0] + scratch[1] + scratch[2] + scratch[3];
}

// ---------------- stats ----------------
__global__ void k_scalars(const int* y, const float* kappa, const float* nu,
                          float* kapnu, float* cf, float* beta, float* invs,
                          int* counts, int* offsets, int* cls_of_pt, int* order,
                          float* sums, float* uarr, float* dout) {
  __shared__ int h[16];
  __shared__ int cur[16];
  int t = threadIdx.x;
  if (t < 16) h[t] = 0;
  __syncthreads();
  for (int n = t; n < 4096; n += 256) atomicAdd(&h[y[n]], 1);
  __syncthreads();
  if (t == 0) {
    float kap = fabsf(kappa[0]) + 1e-6f;
    float nu_ = fmaxf(nu[0], 1024.0f - 1.0f + 1e-6f);
    kapnu[0] = kap; kapnu[1] = nu_;
    int off = 0, tile = 0;
    for (int c = 0; c < 16; c++) {
      counts[c] = h[c]; offsets[c] = off; cur[c] = off;
      cf[c] = (float)h[c];
      beta[c] = kap + (float)h[c];
      invs[c] = 1.0f / (nu_ + (float)h[c] + 1024.0f + 2.0f);
      int ntile = ((h[c] + 63) & ~63) >> 6;
      for (int q = 0; q < ntile && tile < PT_TILES; q++) cls_of_pt[tile++] = c;
      off += (h[c] + 63) & ~63;
    }
    while (tile < PT_TILES) cls_of_pt[tile++] = -1;
  }
  for (int i = t; i < NP; i += 256) order[i] = -1;
  for (int i = t; i < 16 * 1024; i += 256) { sums[i] = 0.f; uarr[i] = 0.f; }
  for (int i = t; i < 4096 * 16; i += 256) dout[i] = 0.f;
  __syncthreads();
  for (int n = t; n < 4096; n += 256) {
    int c = y[n];
    int p = atomicAdd(&cur[c], 1);
    order[p] = n;
  }
}

// R10: base init = kap*m_i*m_j (full square; upper subtiles were always
// unread-or-overwritten scratch). Lets split-K k_base accumulate via atomics.
__global__ void k_binit(const float* m, const float* kapnu, float* base) {
  int gi = blockIdx.x, t = threadIdx.x;
  float kap = kapnu[0];
  float mi = m[gi];
  float4 mv = ((const float4*)m)[t];
  float4 v = make_float4(kap * mi * mv.x, kap * mi * mv.y,
                         kap * mi * mv.z, kap * mi * mv.w);
  ((float4*)(base + (size_t)gi * DD))[t] = v;
}

__global__ void k_gatherT(const float* X, const int* order, const int* cls_of_pt,
                          short* XTh, short* XTl, float* sums) {
  int pt = blockIdx.x, dt = blockIdx.y, t = threadIdx.x;
  __shared__ float T[64 * TS];
  __shared__ float CS[4 * 64];
  __shared__ int src[64];
  if (t < 64) src[t] = order[pt * 64 + t];
  __syncthreads();
  for (int i = 0; i < 4; i++) {
    int idx4 = i * 256 + t;
    int r = idx4 >> 4, c4 = (idx4 & 15) << 2;
    int s = src[r];
    float4 v = (s >= 0) ? *(const float4*)&X[(size_t)s * DD + dt * 64 + c4]
                        : make_float4(0.f, 0.f, 0.f, 0.f);
    T[r * TS + c4] = v.x; T[r * TS + c4 + 1] = v.y;
    T[r * TS + c4 + 2] = v.z; T[r * TS + c4 + 3] = v.w;
  }
  __syncthreads();
  for (int i = 0; i < 16; i++) {
    int lin = i * 256 + t;
    int d = lin >> 6, p = lin & 63;
    float v = T[p * TS + d];
    short hi = f2bf(v);
    float lov = v - bf2f(hi);
    size_t addr = (size_t)(dt * 64 + d) * NP + pt * 64 + p;
    XTh[addr] = hi;
    XTl[addr] = f2bf(lov);
  }
  int cls = cls_of_pt[pt];
  if (cls < 0) return;
  int g = t >> 6, d = t & 63;
  float s = 0.f;
  for (int p = g * 16; p < g * 16 + 16; p++) s += T[p * TS + d];
  CS[g * 64 + d] = s;
  __syncthreads();
  if (g == 0)
    atomicAdd(&sums[(size_t)cls * DD + dt * 64 + d],
              CS[d] + CS[64 + d] + CS[128 + d] + CS[192 + d]);
}

__global__ void k_mumu2(const float* sums, const float* m, const float* kapnu,
                        const float* cf, float* mu, float* mu2) {
  __shared__ float scratch[4];
  int c = blockIdx.x, t = threadIdx.x;
  float kap = kapnu[0];
  float denom = 1.0f / (kap + cf[c]);
  float s2 = 0.f;
  for (int j = t; j < DD; j += 256) {
    float v = (kap * m[j] + sums[(size_t)c * DD + j]) * denom;
    mu[(size_t)c * DD + j] = v;
    s2 += v * v;
  }
  float tot = reduce256(s2, scratch);
  if (t == 0) mu2[c] = tot;
}

__device__ __forceinline__ float lval(const float* td, const float* tl, int i, int j) {
  if (i == j) return fabsf(td[i]);
  if (i > j) return tl[(size_t)i * DD + j];
  return 0.f;
}

// R11: split-K chunks 4 -> 8 (round-robin; longest chunk 8 staging iters).
// R10's split-4 removed k_base from the top-5 (145 -> ~40us); this halves
// the critical block again. Partials atomicAdd onto k_binit's kap*m*m init.
__global__ void k_base(const float* td, const float* tl, float* base) {
  int ti, tj; tri_decode(blockIdx.x, ti, tj);
  int ch = blockIdx.y;
  if (ch > tj) return;                  // block-uniform: no barrier hazards
  __shared__ float Ta[16][65], Tb[16][65];
  int t = threadIdx.x, tx = t & 15, ty = t >> 4;
  int r0 = ty * 4, c0 = tx * 4;
  float acc[4][4] = {};
  for (int kt = ch; kt <= tj; kt += 8) {
    for (int kko = 0; kko < 64; kko += 16) {
      int kk = kt * 64 + kko;
      __syncthreads();
      for (int idx = t; idx < 64 * 16; idx += 256) {
        int r = idx >> 4, p = idx & 15;
        Ta[p][r] = lval(td, tl, ti * 64 + r, kk + p);
        Tb[p][r] = lval(td, tl, tj * 64 + r, kk + p);
      }
      __syncthreads();
#pragma unroll
      for (int p = 0; p < 16; p++) {
        float av[4], bv[4];
#pragma unroll
        for (int a = 0; a < 4; a++) av[a] = Ta[p][r0 + a];
#pragma unroll
        for (int b = 0; b < 4; b++) bv[b] = Tb[p][c0 + b];
#pragma unroll
        for (int a = 0; a < 4; a++)
#pragma unroll
          for (int b = 0; b < 4; b++) acc[a][b] += av[a] * bv[b];
      }
    }
  }
#pragma unroll
  for (int a = 0; a < 4; a++)
#pragma unroll
    for (int b = 0; b < 4; b++) {
      int gi = ti * 64 + r0 + a, gj = tj * 64 + c0 + b;
      atomicAdd(&base[(size_t)gi * DD + gj], acc[a][b]);
    }
}

__global__ __launch_bounds__(256) void k_syrk_mfma(const short* XTh, const short* XTl,
                                                   const float* base, const float* mu,
                                                   const float* beta, const float* invs,
                                                   const int* counts, const int* offsets,
                                                   float* sigma) {
  int bb = blockIdx.x;
  int cls = bb / 36, tr = bb % 36;
  int ti, tj; tri_decode(tr, ti, tj);
  int cnt = counts[cls], off = offsets[cls];
  float* Sg = sigma + ((size_t)cls << 20);
  const float* muc = mu + (size_t)cls * DD;
  __shared__ short Ah[128 * 40], Al[128 * 40], Bh[128 * 40], Bl[128 * 40];
  int t = threadIdx.x;
  int wave = t >> 6, lane = t & 63;
  int wr = wave >> 1, wc = wave & 1;
  int quad = lane >> 4, l15 = lane & 15;
  int i0 = ti * 128, j0 = tj * 128;
  bool same = (ti == tj);
  floatx4 acc[4][4];
#pragma unroll
  for (int a = 0; a < 4; a++)
#pragma unroll
    for (int b = 0; b < 4; b++) acc[a][b] = (floatx4){0.f, 0.f, 0.f, 0.f};
  for (int nn = 0; nn < cnt; nn += 32) {
    __syncthreads();
#pragma unroll
    for (int r = 0; r < 2; r++) {
      int lin = r * 256 + t;
      int row = lin >> 2, kg = (lin & 3) << 3;
      size_t sA = (size_t)(i0 + row) * NP + off + nn + kg;
      *(s16x8*)&Ah[row * 40 + kg] = *(const s16x8*)&XTh[sA];
      *(s16x8*)&Al[row * 40 + kg] = *(const s16x8*)&XTl[sA];
      if (!same) {
        size_t sB = (size_t)(j0 + row) * NP + off + nn + kg;
        *(s16x8*)&Bh[row * 40 + kg] = *(const s16x8*)&XTh[sB];
        *(s16x8*)&Bl[row * 40 + kg] = *(const s16x8*)&XTl[sB];
      }
    }
    __syncthreads();
    const short* PBh = same ? Ah : Bh;
    const short* PBl = same ? Al : Bl;
    s16x8 ah[4], al[4], bh[4], bl[4];
#pragma unroll
    for (int f = 0; f < 4; f++) {
      ah[f] = *(const s16x8*)&Ah[(wr * 64 + f * 16 + l15) * 40 + quad * 8];
      al[f] = *(const s16x8*)&Al[(wr * 64 + f * 16 + l15) * 40 + quad * 8];
      bh[f] = *(const s16x8*)&PBh[(wc * 64 + f * 16 + l15) * 40 + quad * 8];
      bl[f] = *(const s16x8*)&PBl[(wc * 64 + f * 16 + l15) * 40 + quad * 8];
    }
#pragma unroll
    for (int fi = 0; fi < 4; fi++)
#pragma unroll
      for (int fj = 0; fj < 4; fj++) {
        acc[fi][fj] = __builtin_amdgcn_mfma_f32_16x16x32_bf16(ah[fi], bh[fj], acc[fi][fj], 0, 0, 0);
        acc[fi][fj] = __builtin_amdgcn_mfma_f32_16x16x32_bf16(ah[fi], bl[fj], acc[fi][fj], 0, 0, 0);
        acc[fi][fj] = __builtin_amdgcn_mfma_f32_16x16x32_bf16(al[fi], bh[fj], acc[fi][fj], 0, 0, 0);
      }
  }
  float bet = beta[cls], isc = invs[cls];
#pragma unroll
  for (int fi = 0; fi < 4; fi++)
#pragma unroll
    for (int fj = 0; fj < 4; fj++)
#pragma unroll
      for (int reg = 0; reg < 4; reg++) {
        int gi = i0 + wr * 64 + fi * 16 + quad * 4 + reg;
        int gj = j0 + wc * 64 + fj * 16 + l15;
        float v = acc[fi][fj][reg] + base[(size_t)gi * DD + gj] - bet * muc[gi] * muc[gj];
        Sg[(size_t)gi * DD + gj] = v * isc;
      }
}

// ---------------- factorization ----------------
// R1-proven: register-cached LDL^T elimination (63 rounds, 1 barrier/step)
// + level-doubling triangular inversion. CLOSED SUBSYSTEM (R2/R4/R7 all
// regressed). Do not re-attempt.
__device__ void chol_inv_reg(float areg[4][4], float* Dinv, int cls, int k, int t,
                             float* Asc, float* Wsc, float* Tsc) {
  __shared__ float colbuf[2][64];
  __shared__ float sdiag[64];
  int tx = t & 15, ty = t >> 4;
  int r0 = ty * 4, c0 = tx * 4;
  for (int j = 0; j < 63; j++) {
    float* cb = colbuf[j & 1];
    if (tx == (j >> 2)) {
      int jj = j & 3;
      cb[r0 + 0] = areg[0][jj];
      cb[r0 + 1] = areg[1][jj];
      cb[r0 + 2] = areg[2][jj];
      cb[r0 + 3] = areg[3][jj];
    }
    __syncthreads();
    float rd = 1.0f / cb[j];
    float rv[4], cv[4];
#pragma unroll
    for (int i = 0; i < 4; i++) rv[i] = cb[r0 + i];
#pragma unroll
    for (int b = 0; b < 4; b++) cv[b] = cb[c0 + b];
#pragma unroll
    for (int i = 0; i < 4; i++)
#pragma unroll
      for (int b = 0; b < 4; b++)
        if (c0 + b > j && c0 + b <= r0 + i)
          areg[i][b] -= rv[i] * cv[b] * rd;
  }
  __syncthreads();
  if (tx == ty) {
#pragma unroll
    for (int i = 0; i < 4; i++) sdiag[r0 + i] = 1.0f / sqrtf(areg[i][i]);
  }
  __syncthreads();
  float sd[4];
#pragma unroll
  for (int b = 0; b < 4; b++) sd[b] = sdiag[c0 + b];
  // L (scaled, lower; 0 above) -> Asc; zero Wsc
#pragma unroll
  for (int i = 0; i < 4; i++)
#pragma unroll
    for (int b = 0; b < 4; b++) {
      float lv = (r0 + i >= c0 + b) ? areg[i][b] * sd[b] : 0.f;
      Asc[(r0 + i) * TS + c0 + b] = lv;
      Wsc[(r0 + i) * TS + c0 + b] = 0.f;
    }
  __syncthreads();
  // --- level-doubling inversion of L (in Asc) into Wsc ---
  if (t < 16) {
    int c = t * 4;
    float l[4][4], w[4][4];
#pragma unroll
    for (int i = 0; i < 4; i++)
#pragma unroll
      for (int j = 0; j <= i; j++) l[i][j] = Asc[(c + i) * TS + c + j];
#pragma unroll
    for (int j = 0; j < 4; j++) {
      w[j][j] = 1.0f / l[j][j];
#pragma unroll
      for (int i = j + 1; i < 4; i++) {
        float s = 0.f;
#pragma unroll
        for (int kk = j; kk < i; kk++) s += l[i][kk] * w[kk][j];
        w[i][j] = -s / l[i][i];
      }
    }
#pragma unroll
    for (int i = 0; i < 4; i++)
#pragma unroll
      for (int j = 0; j <= i; j++) Wsc[(c + i) * TS + c + j] = w[i][j];
  }
  __syncthreads();
#pragma unroll 4
  for (int h = 4; h <= 32; h <<= 1) {
    int hh = h * h;
    int total = 32 * h;  // (64/(2h)) pairs * h*h elements
    for (int idx = t; idx < total; idx += 256) {
      int pr = idx / hh;
      int rem = idx - pr * hh;
      int i = rem / h, j = rem - (rem / h) * h;
      int c = pr * 2 * h;
      float s = 0.f;
      for (int kk = j; kk < h; kk++)
        s += Asc[(c + h + i) * TS + c + kk] * Wsc[(c + kk) * TS + c + j];
      Tsc[idx] = s;
    }
    __syncthreads();
    for (int idx = t; idx < total; idx += 256) {
      int pr = idx / hh;
      int rem = idx - pr * hh;
      int i = rem / h, j = rem - (rem / h) * h;
      int c = pr * 2 * h;
      int tb = pr * hh;
      float s = 0.f;
      for (int kk = 0; kk <= i; kk++)
        s += Wsc[(c + h + i) * TS + c + h + kk] * Tsc[tb + kk * h + j];
      Wsc[(c + h + i) * TS + c + j] = -s;
    }
    __syncthreads();
  }
  float* Dv = Dinv + ((size_t)(cls * 16 + k)) * 4096;
  for (int idx4 = t; idx4 < 1024; idx4 += 256) {
    int r = idx4 >> 4, c4 = (idx4 & 15) << 2;
    float4 v = make_float4(Wsc[r * TS + c4], Wsc[r * TS + c4 + 1],
                           Wsc[r * TS + c4 + 2], Wsc[r * TS + c4 + 3]);
    *(float4*)&Dv[r * 64 + c4] = v;
  }
}

__global__ void k_diag0(float* sigma, float* Dinv) {
  __shared__ float A[64 * TS], W[64 * TS];
  __shared__ float Tq[1024];
  int cls = blockIdx.x, t = threadIdx.x;
  int tx = t & 15, ty = t >> 4;
  int r0 = ty * 4, c0 = tx * 4;
  float* Sg = sigma + ((size_t)cls << 20);
  float areg[4][4];
#pragma unroll
  for (int i = 0; i < 4; i++) {
    float4 s = *(const float4*)&Sg[(size_t)(r0 + i) * DD + c0];
    areg[i][0] = s.x; areg[i][1] = s.y; areg[i][2] = s.z; areg[i][3] = s.w;
  }
  chol_inv_reg(areg, Dinv, cls, 0, t, A, W, Tq);
}

// R3: split early steps (k<=7) into panel + update launches.
__global__ void k_panel(float* sigma, const float* Dinv, int k) {
  __shared__ float B0[64 * TS], B1[64 * TS];
  int i_ = blockIdx.x, cls = blockIdx.y, t = threadIdx.x;
  int tx = t & 15, ty = t >> 4;
  int r0 = ty * 4, c0 = tx * 4;
  int it = k + 1 + i_;
  float* Sg = sigma + ((size_t)cls << 20);
  const float* Dv = Dinv + ((size_t)(cls * 16 + k)) * 4096;
  for (int i = 0; i < 4; i++) {
    int idx4 = i * 256 + t;
    int r = idx4 >> 4, c4 = (idx4 & 15) << 2;
    float4 v0 = *(const float4*)&Dv[r * 64 + c4];
    B0[r * TS + c4] = v0.x; B0[r * TS + c4 + 1] = v0.y;
    B0[r * TS + c4 + 2] = v0.z; B0[r * TS + c4 + 3] = v0.w;
    float4 v1 = *(const float4*)&Sg[(size_t)(it * 64 + r) * DD + k * 64 + c4];
    B1[r * TS + c4] = v1.x; B1[r * TS + c4 + 1] = v1.y;
    B1[r * TS + c4 + 2] = v1.z; B1[r * TS + c4 + 3] = v1.w;
  }
  __syncthreads();
  float a1[4][4] = {};
#pragma unroll 8
  for (int p = 0; p < 64; p++) {
    float bv[4], av1[4];
#pragma unroll
    for (int bq = 0; bq < 4; bq++) bv[bq] = B0[(c0 + bq) * TS + p];
#pragma unroll
    for (int a = 0; a < 4; a++) av1[a] = B1[(r0 + a) * TS + p];
#pragma unroll
    for (int a = 0; a < 4; a++)
#pragma unroll
      for (int bq = 0; bq < 4; bq++) a1[a][bq] += av1[a] * bv[bq];
  }
#pragma unroll
  for (int a = 0; a < 4; a++) {
    float4 v = make_float4(a1[a][0], a1[a][1], a1[a][2], a1[a][3]);
    *(float4*)&Sg[(size_t)(k * 64 + r0 + a) * DD + it * 64 + c0] = v;
  }
}

__global__ void k_update(float* sigma, float* Dinv, int k) {
  __shared__ float B0[64 * TS], B1[64 * TS], B2[64 * TS];
  int b = blockIdx.x, t = threadIdx.x;
  int tx = t & 15, ty = t >> 4;
  int r0 = ty * 4, c0 = tx * 4;
  int nb = 15 - k;
  int nt = nb * (nb + 1) / 2;
  int cls, a_, b_;
  bool special = (b < 16);
  if (special) { cls = b; a_ = 0; b_ = 0; }
  else {
    int jp = b - 16;
    cls = jp / (nt - 1);
    int s = jp % (nt - 1) + 1;
    tri_decode(s, a_, b_);
  }
  int it = k + 1 + a_, jt = k + 1 + b_;
  bool same = (it == jt);
  float* Sg = sigma + ((size_t)cls << 20);
  // load persisted panels P_it (B1) and P_jt (B2) from the upper mirror
  for (int i = 0; i < 4; i++) {
    int idx4 = i * 256 + t;
    int r = idx4 >> 4, c4 = (idx4 & 15) << 2;
    float4 v1 = *(const float4*)&Sg[(size_t)(k * 64 + r) * DD + it * 64 + c4];
    B1[r * TS + c4] = v1.x; B1[r * TS + c4 + 1] = v1.y;
    B1[r * TS + c4 + 2] = v1.z; B1[r * TS + c4 + 3] = v1.w;
    if (!same) {
      float4 v2 = *(const float4*)&Sg[(size_t)(k * 64 + r) * DD + jt * 64 + c4];
      B2[r * TS + c4] = v2.x; B2[r * TS + c4 + 1] = v2.y;
      B2[r * TS + c4 + 2] = v2.z; B2[r * TS + c4 + 3] = v2.w;
    }
  }
  __syncthreads();
  float* PB = same ? B1 : B2;
  float a3[4][4] = {};
#pragma unroll 8
  for (int p = 0; p < 64; p++) {
    float av[4], bv[4];
#pragma unroll
    for (int a = 0; a < 4; a++) av[a] = B1[(r0 + a) * TS + p];
#pragma unroll
    for (int bq = 0; bq < 4; bq++) bv[bq] = PB[(c0 + bq) * TS + p];
#pragma unroll
    for (int a = 0; a < 4; a++)
#pragma unroll
      for (int bq = 0; bq < 4; bq++) a3[a][bq] += av[a] * bv[bq];
  }
  if (!special) {
#pragma unroll
    for (int a = 0; a < 4; a++) {
      size_t addr = (size_t)(it * 64 + r0 + a) * DD + jt * 64 + c0;
      float4 s = *(const float4*)&Sg[addr];
      s.x -= a3[a][0]; s.y -= a3[a][1]; s.z -= a3[a][2]; s.w -= a3[a][3];
      *(float4*)&Sg[addr] = s;
    }
    return;
  }
  // special: updated (k+1,k+1) tile straight into registers, then factor
  float areg[4][4];
#pragma unroll
  for (int i = 0; i < 4; i++) {
    size_t addr = (size_t)(it * 64 + r0 + i) * DD + jt * 64 + c0;
    float4 s = *(const float4*)&Sg[addr];
    areg[i][0] = s.x - a3[i][0]; areg[i][1] = s.y - a3[i][1];
    areg[i][2] = s.z - a3[i][2]; areg[i][3] = s.w - a3[i][3];
  }
  __syncthreads();
  chol_inv_reg(areg, Dinv, cls, k + 1, t, B1, B2, B0);
}

// merged step k (used for k>7 where work is small / latency-dominated)
__global__ void k_cholstep(float* sigma, float* Dinv, int k) {
  __shared__ float B0[64 * TS], B1[64 * TS], B2[64 * TS];
  int b = blockIdx.x, t = threadIdx.x;
  int tx = t & 15, ty = t >> 4;
  int r0 = ty * 4, c0 = tx * 4;
  int nb = 15 - k;
  int nt = nb * (nb + 1) / 2;
  int cls, a_, b_;
  bool special = (b < 16);
  if (special) { cls = b; a_ = 0; b_ = 0; }
  else {
    int jp = b - 16;
    cls = jp / (nt - 1);
    int s = jp % (nt - 1) + 1;
    tri_decode(s, a_, b_);
  }
  int it = k + 1 + a_, jt = k + 1 + b_;
  bool same = (it == jt);
  float* Sg = sigma + ((size_t)cls << 20);
  const float* Dv = Dinv + ((size_t)(cls * 16 + k)) * 4096;
  for (int i = 0; i < 4; i++) {
    int idx4 = i * 256 + t;
    int r = idx4 >> 4, c4 = (idx4 & 15) << 2;
    float4 v0 = *(const float4*)&Dv[r * 64 + c4];
    B0[r * TS + c4] = v0.x; B0[r * TS + c4 + 1] = v0.y;
    B0[r * TS + c4 + 2] = v0.z; B0[r * TS + c4 + 3] = v0.w;
    float4 v1 = *(const float4*)&Sg[(size_t)(it * 64 + r) * DD + k * 64 + c4];
    B1[r * TS + c4] = v1.x; B1[r * TS + c4 + 1] = v1.y;
    B1[r * TS + c4 + 2] = v1.z; B1[r * TS + c4 + 3] = v1.w;
    if (!same) {
      float4 v2 = *(const float4*)&Sg[(size_t)(jt * 64 + r) * DD + k * 64 + c4];
      B2[r * TS + c4] = v2.x; B2[r * TS + c4 + 1] = v2.y;
      B2[r * TS + c4 + 2] = v2.z; B2[r * TS + c4 + 3] = v2.w;
    }
  }
  __syncthreads();
  // fused: a1 = B1*B0^T, a2 = B2*B0^T (shared bv)
  float a1[4][4] = {}, a2[4][4] = {};
#pragma unroll 8
  for (int p = 0; p < 64; p++) {
    float bv[4], av1[4];
#pragma unroll
    for (int bq = 0; bq < 4; bq++) bv[bq] = B0[(c0 + bq) * TS + p];
#pragma unroll
    for (int a = 0; a < 4; a++) av1[a] = B1[(r0 + a) * TS + p];
#pragma unroll
    for (int a = 0; a < 4; a++)
#pragma unroll
      for (int bq = 0; bq < 4; bq++) a1[a][bq] += av1[a] * bv[bq];
    if (!same) {
      float av2[4];
#pragma unroll
      for (int a = 0; a < 4; a++) av2[a] = B2[(r0 + a) * TS + p];
#pragma unroll
      for (int a = 0; a < 4; a++)
#pragma unroll
        for (int bq = 0; bq < 4; bq++) a2[a][bq] += av2[a] * bv[bq];
    }
  }
  __syncthreads();
#pragma unroll
  for (int a = 0; a < 4; a++)
#pragma unroll
    for (int bq = 0; bq < 4; bq++) {
      B1[(r0 + a) * TS + c0 + bq] = a1[a][bq];
      if (!same) B2[(r0 + a) * TS + c0 + bq] = a2[a][bq];
    }
  if (b_ == 0) {
#pragma unroll
    for (int a = 0; a < 4; a++) {
      float4 v = make_float4(a1[a][0], a1[a][1], a1[a][2], a1[a][3]);
      *(float4*)&Sg[(size_t)(k * 64 + r0 + a) * DD + it * 64 + c0] = v;
    }
  }
  __syncthreads();
  float* PB = same ? B1 : B2;
  float a3[4][4] = {};
#pragma unroll 8
  for (int p = 0; p < 64; p++) {
    float av[4], bv[4];
#pragma unroll
    for (int a = 0; a < 4; a++) av[a] = B1[(r0 + a) * TS + p];
#pragma unroll
    for (int bq = 0; bq < 4; bq++) bv[bq] = PB[(c0 + bq) * TS + p];
#pragma unroll
    for (int a = 0; a < 4; a++)
#pragma unroll
      for (int bq = 0; bq < 4; bq++) a3[a][bq] += av[a] * bv[bq];
  }
  if (!special) {
#pragma unroll
    for (int a = 0; a < 4; a++) {
      size_t addr = (size_t)(it * 64 + r0 + a) * DD + jt * 64 + c0;
      float4 s = *(const float4*)&Sg[addr];
      s.x -= a3[a][0]; s.y -= a3[a][1]; s.z -= a3[a][2]; s.w -= a3[a][3];
      *(float4*)&Sg[addr] = s;
    }
    return;
  }
  // special: updated (k+1,k+1) tile straight into registers, then factor
  float areg[4][4];
#pragma unroll
  for (int i = 0; i < 4; i++) {
    size_t addr = (size_t)(it * 64 + r0 + i) * DD + jt * 64 + c0;
    float4 s = *(const float4*)&Sg[addr];
    areg[i][0] = s.x - a3[i][0]; areg[i][1] = s.y - a3[i][1];
    areg[i][2] = s.z - a3[i][2]; areg[i][3] = s.w - a3[i][3];
  }
  __syncthreads();
  // B0 (held W_k) is dead here -> reuse as the level-doubling T scratch
  chol_inv_reg(areg, Dinv, cls, k + 1, t, B1, B2, B0);
}

// level-1 V combine (width 64->128), fully in-LDS: V21 = -W1 * R * W0
__global__ void k_vl1(float* sigma, const float* Dinv) {
  __shared__ float Rl[64 * TS], W0s[64 * TS], W1s[64 * TS], Ts[64 * TS];
  int b = blockIdx.x, t = threadIdx.x;
  int cls = b >> 3, i = b & 7;
  int t0 = 2 * i, t1 = 2 * i + 1;
  float* Sg = sigma + ((size_t)cls << 20);
  int tx = t & 15, ty = t >> 4;
  int r0 = ty * 4, c0 = tx * 4;
  const float* Dv0 = Dinv + ((size_t)(cls * 16 + t0)) * 4096;
  const float* Dv1 = Dinv + ((size_t)(cls * 16 + t1)) * 4096;
  for (int idx4 = t; idx4 < 1024; idx4 += 256) {
    int r = idx4 >> 4, c4 = (idx4 & 15) << 2;
    float4 vr = *(const float4*)&Sg[(size_t)(t0 * 64 + r) * DD + t1 * 64 + c4];
    Rl[r * TS + c4] = vr.x; Rl[r * TS + c4 + 1] = vr.y;
    Rl[r * TS + c4 + 2] = vr.z; Rl[r * TS + c4 + 3] = vr.w;
    float4 v0 = *(const float4*)&Dv0[r * 64 + c4];
    W0s[r * TS + c4] = v0.x; W0s[r * TS + c4 + 1] = v0.y;
    W0s[r * TS + c4 + 2] = v0.z; W0s[r * TS + c4 + 3] = v0.w;
    float4 v1 = *(const float4*)&Dv1[r * 64 + c4];
    W1s[r * TS + c4] = v1.x; W1s[r * TS + c4 + 1] = v1.y;
    W1s[r * TS + c4 + 2] = v1.z; W1s[r * TS + c4 + 3] = v1.w;
  }
  __syncthreads();
  float aT[4][4] = {};
#pragma unroll 8
  for (int p = 0; p < 64; p++) {
    float av[4], bv[4];
#pragma unroll
    for (int a = 0; a < 4; a++) av[a] = Rl[(r0 + a) * TS + p];
#pragma unroll
    for (int bq = 0; bq < 4; bq++) bv[bq] = W0s[p * TS + c0 + bq];
#pragma unroll
    for (int a = 0; a < 4; a++)
#pragma unroll
      for (int bq = 0; bq < 4; bq++) aT[a][bq] += av[a] * bv[bq];
  }
  __syncthreads();
#pragma unroll
  for (int a = 0; a < 4; a++)
#pragma unroll
    for (int bq = 0; bq < 4; bq++) Ts[(r0 + a) * TS + c0 + bq] = aT[a][bq];
  __syncthreads();
  float aV[4][4] = {};
#pragma unroll 8
  for (int p = 0; p < 64; p++) {
    float av[4], bv[4];
#pragma unroll
    for (int a = 0; a < 4; a++) av[a] = W1s[(r0 + a) * TS + p];
#pragma unroll
    for (int bq = 0; bq < 4; bq++) bv[bq] = Ts[p * TS + c0 + bq];
#pragma unroll
    for (int a = 0; a < 4; a++)
#pragma unroll
      for (int bq = 0; bq < 4; bq++) aV[a][bq] += av[a] * bv[bq];
  }
#pragma unroll
  for (int a = 0; a < 4; a++)
    *(float4*)&Sg[(size_t)(t0 * 64 + r0 + a) * DD + t1 * 64 + c0] =
        make_float4(-aV[a][0], -aV[a][1], -aV[a][2], -aV[a][3]);
}

// level-L launch A: T(a,b) = sum_m R21(a,m) * V11(m,b); T -> lower scratch
__global__ void k_vlA(float* sigma, const float* Dinv, int w) {
  __shared__ float Xs[64 * TS], Ys[64 * TS];
  int aa = blockIdx.x / w, bb = blockIdx.x % w;
  int base = blockIdx.y * 2 * w, cls = blockIdx.z;
  float* Sg = sigma + ((size_t)cls << 20);
  int t = threadIdx.x, tx = t & 15, ty = t >> 4;
  int r0 = ty * 4, c0 = tx * 4;
  float acc[4][4] = {};
  for (int m = bb; m < w; m++) {
    __syncthreads();
    for (int idx4 = t; idx4 < 1024; idx4 += 256) {
      int r = idx4 >> 4, c4 = (idx4 & 15) << 2;
      float4 v = *(const float4*)&Sg[(size_t)((base + m) * 64 + r) * DD + (base + w + aa) * 64 + c4];
      Xs[r * TS + c4] = v.x; Xs[r * TS + c4 + 1] = v.y;
      Xs[r * TS + c4 + 2] = v.z; Xs[r * TS + c4 + 3] = v.w;
    }
    if (m == bb) {
      const float* Dv = Dinv + ((size_t)(cls * 16 + base + bb)) * 4096;
      for (int idx4 = t; idx4 < 1024; idx4 += 256) {
        int r = idx4 >> 4, c4 = (idx4 & 15) << 2;
        float4 v = *(const float4*)&Dv[r * 64 + c4];
        Ys[r * TS + c4] = v.x; Ys[r * TS + c4 + 1] = v.y;
        Ys[r * TS + c4 + 2] = v.z; Ys[r * TS + c4 + 3] = v.w;
      }
    } else {
      for (int idx4 = t; idx4 < 1024; idx4 += 256) {
        int p = idx4 >> 4, c4 = (idx4 & 15) << 2;
        float4 v = *(const float4*)&Sg[(size_t)((base + bb) * 64 + p) * DD + (base + m) * 64 + c4];
        Ys[p * TS + c4] = v.x; Ys[p * TS + c4 + 1] = v.y;
        Ys[p * TS + c4 + 2] = v.z; Ys[p * TS + c4 + 3] = v.w;
      }
    }
    __syncthreads();
#pragma unroll 8
    for (int p = 0; p < 64; p++) {
      float av[4], bv[4];
#pragma unroll
      for (int a = 0; a < 4; a++) av[a] = Xs[(r0 + a) * TS + p];
#pragma unroll
      for (int bq = 0; bq < 4; bq++) bv[bq] = Ys[p * TS + c0 + bq];
#pragma unroll
      for (int a = 0; a < 4; a++)
#pragma unroll
        for (int bq = 0; bq < 4; bq++) acc[a][bq] += av[a] * bv[bq];
    }
  }
#pragma unroll
  for (int a = 0; a < 4; a++)
    *(float4*)&Sg[(size_t)((base + w + aa) * 64 + r0 + a) * DD + (base + bb) * 64 + c0] =
        make_float4(acc[a][0], acc[a][1], acc[a][2], acc[a][3]);
}

// level-L launch B: V21(a,b) = -sum_{m<=a} V22(a,m) * T(m,b); -> upper mirror
__global__ void k_vlB(float* sigma, const float* Dinv, int w) {
  __shared__ float Xs[64 * TS], Ys[64 * TS];
  int aa = blockIdx.x / w, bb = blockIdx.x % w;
  int base = blockIdx.y * 2 * w, cls = blockIdx.z;
  float* Sg = sigma + ((size_t)cls << 20);
  int t = threadIdx.x, tx = t & 15, ty = t >> 4;
  int r0 = ty * 4, c0 = tx * 4;
  float acc[4][4] = {};
  for (int m = 0; m <= aa; m++) {
    __syncthreads();
    if (m == aa) {
      const float* Dv = Dinv + ((size_t)(cls * 16 + base + w + aa)) * 4096;
      for (int idx4 = t; idx4 < 1024; idx4 += 256) {
        int r = idx4 >> 4, c4 = (idx4 & 15) << 2;
        float4 v = *(const float4*)&Dv[r * 64 + c4];
        Xs[r * TS + c4] = v.x; Xs[r * TS + c4 + 1] = v.y;
        Xs[r * TS + c4 + 2] = v.z; Xs[r * TS + c4 + 3] = v.w;
      }
    } else {
      for (int idx4 = t; idx4 < 1024; idx4 += 256) {
        int r = idx4 >> 4, c4 = (idx4 & 15) << 2;
        float4 v = *(const float4*)&Sg[(size_t)((base + w + m) * 64 + r) * DD + (base + w + aa) * 64 + c4];
        Xs[r * TS + c4] = v.x; Xs[r * TS + c4 + 1] = v.y;
        Xs[r * TS + c4 + 2] = v.z; Xs[r * TS + c4 + 3] = v.w;
      }
    }
    for (int idx4 = t; idx4 < 1024; idx4 += 256) {
      int p = idx4 >> 4, c4 = (idx4 & 15) << 2;
      float4 v = *(const float4*)&Sg[(size_t)((base + w + m) * 64 + p) * DD + (base + bb) * 64 + c4];
      Ys[p * TS + c4] = v.x; Ys[p * TS + c4 + 1] = v.y;
      Ys[p * TS + c4 + 2] = v.z; Ys[p * TS + c4 + 3] = v.w;
    }
    __syncthreads();
#pragma unroll 8
    for (int p = 0; p < 64; p++) {
      float av[4], bv[4];
#pragma unroll
      for (int a = 0; a < 4; a++) av[a] = Xs[(r0 + a) * TS + p];
#pragma unroll
      for (int bq = 0; bq < 4; bq++) bv[bq] = Ys[p * TS + c0 + bq];
#pragma unroll
      for (int a = 0; a < 4; a++)
#pragma unroll
        for (int bq = 0; bq < 4; bq++) acc[a][bq] += av[a] * bv[bq];
    }
  }
#pragma unroll
  for (int a = 0; a < 4; a++)
    *(float4*)&Sg[(size_t)((base + bb) * 64 + r0 + a) * DD + (base + w + aa) * 64 + c0] =
        make_float4(-acc[a][0], -acc[a][1], -acc[a][2], -acc[a][3]);
}

// 2176 blocks: packed-fp16 V-tile copy (half8 writes) + fused u-partial
__global__ void k_finalize(const float* sigma, const float* Dinv, const float* mu,
                           float* uarr, _Float16* UT) {
  __shared__ float U0[64 * TS];
  __shared__ float CS[4 * 64];
  int jp = blockIdx.x, t = threadIdx.x;
  int cls = jp / 136, tr = jp % 136;
  int nt_, kt_; tri_decode(tr, nt_, kt_);   // nt_ >= kt_
  const float* muc = mu + (size_t)cls * DD;
  _Float16* outp = UT + (size_t)cls * UT_CLS_STRIDE + (size_t)tr * 4096;
  const float* srcp;
  size_t row_stride;
  if (kt_ == nt_) {
    srcp = Dinv + ((size_t)(cls * 16 + nt_)) * 4096;
    row_stride = 64;
  } else {
    srcp = sigma + ((size_t)cls << 20) + (size_t)(kt_ * 64) * DD + nt_ * 64;
    row_stride = DD;
  }
  for (int i = 0; i < 2; i++) {
    int g8 = i * 256 + t;            // 512 groups of 8 halves
    int rr = g8 >> 3, c8 = (g8 & 7) << 3;
    float4 v0 = *(const float4*)&srcp[(size_t)rr * row_stride + c8];
    float4 v1 = *(const float4*)&srcp[(size_t)rr * row_stride + c8 + 4];
    half8 h;
    h[0] = (_Float16)v0.x; h[1] = (_Float16)v0.y; h[2] = (_Float16)v0.z; h[3] = (_Float16)v0.w;
    h[4] = (_Float16)v1.x; h[5] = (_Float16)v1.y; h[6] = (_Float16)v1.z; h[7] = (_Float16)v1.w;
    *(half8*)&outp[rr * 64 + c8] = h;
    U0[rr * TS + c8] = v0.x; U0[rr * TS + c8 + 1] = v0.y;
    U0[rr * TS + c8 + 2] = v0.z; U0[rr * TS + c8 + 3] = v0.w;
    U0[rr * TS + c8 + 4] = v1.x; U0[rr * TS + c8 + 5] = v1.y;
    U0[rr * TS + c8 + 6] = v1.z; U0[rr * TS + c8 + 7] = v1.w;
  }
  __syncthreads();
  int g = t >> 6, r = t & 63;
  float s = 0.f;
  for (int c = g * 16; c < g * 16 + 16; c++)
    s += U0[r * TS + c] * muc[kt_ * 64 + c];
  CS[g * 64 + r] = s;
  __syncthreads();
  if (g == 0)
    atomicAdd(&uarr[(size_t)cls * DD + nt_ * 64 + r],
              CS[r] + CS[64 + r] + CS[128 + r] + CS[192 + r]);
}

// ---------------- predict side ----------------
__global__ void k_xqdots(const float* Xq, const float* mu, float* xq2, float* xqmu,
                         _Float16* XqH) {
  __shared__ float xrow[DD];
  int m = blockIdx.x, t = threadIdx.x;
  for (int i = t; i < 256; i += 256)
    ((float4*)xrow)[i] = ((const float4*)(Xq + (size_t)m * DD))[i];
  __syncthreads();
  for (int i = t; i < 256; i += 256) {
    float4 v = ((const float4*)xrow)[i];
    half4 h = {(_Float16)v.x, (_Float16)v.y, (_Float16)v.z, (_Float16)v.w};
    *(half4*)&XqH[(size_t)m * DD + i * 4] = h;
  }
  int wave = t >> 6, lane = t & 63;
  for (int cc = 0; cc < 4; cc++) {
    int c = wave * 4 + cc;
    const float* muc = mu + (size_t)c * DD;
    float s = 0.f;
    for (int j = lane; j < DD; j += 64) s += xrow[j] * muc[j];
    for (int o = 32; o > 0; o >>= 1) s += __shfl_down(s, o, 64);
    if (lane == 0) xqmu[(size_t)m * 16 + c] = s;
  }
  if (wave == 0) {
    float s = 0.f;
    for (int j = lane; j < DD; j += 64) s += xrow[j] * xrow[j];
    for (int o = 32; o > 0; o >>= 1) s += __shfl_down(s, o, 64);
    if (lane == 0) xq2[m] = s;
  }
}

// R11: K-step 64 (one kt tile per LDS buffer, two 32-wide MFMA sub-steps).
// R10 counters showed gemmG is per-iteration-overhead bound (FETCH unchanged
// at 74MB when B-reuse doubled -> B already L2-resident; gains came from
// barrier amortization). Halves barriers + staging instructions per MFMA.
// LDS 55.3KB -> 2 blocks/CU = 16 waves (50% cap) > measured 33% occupancy.
// Fragment pattern unchanged (s2*32 reproduces the old k0 slicing exactly).
__global__ __launch_bounds__(512) void k_gemmG_mfma(const _Float16* XqH, const _Float16* UT,
                                                    const float* u, float* dout) {
  int mt = blockIdx.x, ct = 7 - (int)blockIdx.y, cls = blockIdx.z;
  const _Float16* Uc = UT + (size_t)cls * UT_CLS_STRIDE;
  __shared__ _Float16 As[256 * 72];
  __shared__ _Float16 Bs[128 * 72];
  int t = threadIdx.x;
  int wave = t >> 6, lane = t & 63;
  int wr = wave >> 1, wc = wave & 1;      // wr in [0,4): 256 rows; wc in {0,1}
  int quad = lane >> 4, l15 = lane & 15;
  int m0 = mt * 256, n0 = ct * 128, NT0 = ct * 2;
  floatx4 acc[4][4];
#pragma unroll
  for (int a = 0; a < 4; a++)
#pragma unroll
    for (int b = 0; b < 4; b++) acc[a][b] = (floatx4){0.f, 0.f, 0.f, 0.f};
  int kmax = (ct + 1) * 128;
  for (int kk = 0; kk < kmax; kk += 64) {
    __syncthreads();
    int kt = kk >> 6;
    // As: 256 rows x 64 halves = 2048 half8-groups, 4 iters of 512 threads
#pragma unroll
    for (int i = 0; i < 4; i++) {
      int lin = i * 512 + t;
      int r = lin >> 3, kg = (lin & 7) * 8;
      *(half8*)&As[r * 72 + kg] = *(const half8*)&XqH[(size_t)(m0 + r) * DD + kk + kg];
    }
    // Bs: 128 rows x 64 halves = 1024 groups, 2 iters
#pragma unroll
    for (int i = 0; i < 2; i++) {
      int lin = i * 512 + t;
      int nl = lin >> 3, kg = (lin & 7) * 8;
      int s = nl >> 6, np = nl & 63;
      int nt = NT0 + s;
      half8 v = {};
      if (kt <= nt)
        v = *(const half8*)&Uc[(size_t)(nt * (nt + 1) / 2 + kt) * 4096 + np * 64 + kg];
      *(half8*)&Bs[nl * 72 + kg] = v;
    }
    __syncthreads();
#pragma unroll
    for (int s2 = 0; s2 < 2; s2++) {
      half8 af[4], bf[4];
#pragma unroll
      for (int f = 0; f < 4; f++) {
        af[f] = *(const half8*)&As[(wr * 64 + f * 16 + l15) * 72 + s2 * 32 + quad * 8];
        bf[f] = *(const half8*)&Bs[(wc * 64 + f * 16 + l15) * 72 + s2 * 32 + quad * 8];
      }
#pragma unroll
      for (int fi = 0; fi < 4; fi++)
#pragma unroll
        for (int fj = 0; fj < 4; fj++)
          acc[fi][fj] = __builtin_amdgcn_mfma_f32_16x16x32_f16(af[fi], bf[fj], acc[fi][fj], 0, 0, 0);
    }
  }
  float uv[4];
#pragma unroll
  for (int fj = 0; fj < 4; fj++)
    uv[fj] = u[(size_t)cls * DD + n0 + wc * 64 + fj * 16 + l15];
#pragma unroll
  for (int fi = 0; fi < 4; fi++) {
#pragma unroll
    for (int r = 0; r < 4; r++) {
      float p = 0.f;
#pragma unroll
      for (int fj = 0; fj < 4; fj++) {
        float e = acc[fi][fj][r] - uv[fj];
        p += e * e;
      }
      p += __shfl_xor(p, 1, 64);
      p += __shfl_xor(p, 2, 64);
      p += __shfl_xor(p, 4, 64);
      p += __shfl_xor(p, 8, 64);
      if (l15 == 0) {
        int m = m0 + wr * 64 + fi * 16 + quad * 4 + r;
        atomicAdd(&dout[(size_t)m * 16 + cls], p);
      }
    }
  }
}

__global__ void k_logits(const float* xq2, const float* xqmu, const float* mu2,
                         float* dout) {
  size_t idx = (size_t)blockIdx.x * 256 + threadIdx.x;
  int m = (int)(idx >> 4), c = (int)(idx & 15);
  float q1 = dout[idx];
  float q2 = xq2[m] - 2.0f * xqmu[idx] + mu2[c];
  dout[idx] = -(0.9f * q1 + 0.1f * q2);
}

extern "C" void kernel_launch(void* const* d_in, const int* in_sizes, int n_in,
                              void* d_out, int out_size, void* d_ws, size_t ws_size,
                              hipStream_t stream) {
  (void)in_sizes; (void)n_in; (void)out_size; (void)ws_size;
  const float* X  = (const float*)d_in[0];
  const int*   y  = (const int*)d_in[1];
  const float* Xq = (const float*)d_in[2];
  const float* m  = (const float*)d_in[3];
  const float* kappa = (const float*)d_in[4];
  const float* nu = (const float*)d_in[5];
  const float* td = (const float*)d_in[6];
  const float* tl = (const float*)d_in[7];
  float* out = (float*)d_out;
  float* ws = (float*)d_ws;

  short* XTh   = (short*)(ws + OFF_XTH);
  short* XTl   = (short*)(ws + OFF_XTL);
  _Float16* UT = (_Float16*)ws;              // overlays XT planes (dead after syrk)
  float* baseb = ws + OFF_BASE;
  float* sigma = ws + OFF_SIGMA;
  _Float16* XqH = (_Float16*)sigma;          // overlays sigma (dead after finalize)
  float* Dinv  = ws + OFF_DINV;
  float* sums  = ws + OFF_SUMS;
  float* mu    = ws + OFF_MU;
  float* uarr  = ws + OFF_U;
  float* mu2   = ws + OFF_MU2;
  float* xq2   = ws + OFF_XQ2;
  float* xqmu  = ws + OFF_XQMU;
  float* kapnu = ws + OFF_KAPNU;
  float* cf    = ws + OFF_CF;
  float* beta  = ws + OFF_BETA;
  float* invs  = ws + OFF_INVS;
  int* ints      = (int*)(ws + OFF_INTS);
  int* counts    = ints;
  int* offsets   = ints + 16;
  int* cls_of_pt = ints + 32;
  int* order     = ints + 32 + PT_TILES;

  k_scalars<<<1, 256, 0, stream>>>(y, kappa, nu, kapnu, cf, beta, invs,
                                   counts, offsets, cls_of_pt, order,
                                   sums, uarr, out);
  k_binit<<<1024, 256, 0, stream>>>(m, kapnu, baseb);
  k_gatherT<<<dim3(PT_TILES, 16), 256, 0, stream>>>(X, order, cls_of_pt, XTh, XTl, sums);
  k_mumu2<<<16, 256, 0, stream>>>(sums, m, kapnu, cf, mu, mu2);
  k_base<<<dim3(136, 8), 256, 0, stream>>>(td, tl, baseb);
  k_syrk_mfma<<<16 * 36, 256, 0, stream>>>(XTh, XTl, baseb, mu, beta, invs,
                                           counts, offsets, sigma);
  k_diag0<<<16, 256, 0, stream>>>(sigma, Dinv);
  for (int k = 0; k < 15; k++) {
    int nb = 15 - k;
    int nt = nb * (nb + 1) / 2;
    if (k <= 7) {
      k_panel<<<dim3(nb, 16), 256, 0, stream>>>(sigma, Dinv, k);
      k_update<<<16 * nt, 256, 0, stream>>>(sigma, Dinv, k);
    } else {
      k_cholstep<<<16 * nt, 256, 0, stream>>>(sigma, Dinv, k);
    }
  }
  k_vl1<<<128, 256, 0, stream>>>(sigma, Dinv);
  for (int L = 2; L <= 4; L++) {
    int w = 1 << (L - 1);
    int ncomb = 8 >> (L - 1);
    k_vlA<<<dim3(w * w, ncomb, 16), 256, 0, stream>>>(sigma, Dinv, w);
    k_vlB<<<dim3(w * w, ncomb, 16), 256, 0, stream>>>(sigma, Dinv, w);
  }
  k_finalize<<<16 * 136, 256, 0, stream>>>(sigma, Dinv, mu, uarr, UT);
  k_xqdots<<<4096, 256, 0, stream>>>(Xq, mu, xq2, xqmu, XqH);
  k_gemmG_mfma<<<dim3(16, 8, 16), 512, 0, stream>>>(XqH, UT, uarr, out);
  k_logits<<<256, 256, 0, stream>>>(xq2, xqmu, mu2, out);
}